// Round 1
// baseline (1726.787 us; speedup 1.0000x reference)
//
#include <hip/hip_runtime.h>
#include <hip/hip_bf16.h>
#include <math.h>

#define D 2048
#define NH 16
#define NKV 4
#define HD 128
#define NE 16
#define NI 768
#define S 1024
#define EPS 1e-6f

// ---------------------------------------------------------------- utilities
__device__ __forceinline__ float wave_reduce_sum64(float v) {
    for (int off = 32; off; off >>= 1) v += __shfl_xor(v, off, 64);
    return v;
}

// ---------------------------------------------------------------- RMSNorm over D
__global__ void rmsnorm_kernel(const float* __restrict__ x, const float* __restrict__ w,
                               float* __restrict__ y) {
    int t = blockIdx.x;
    const float* xr = x + (size_t)t * D;
    float* yr = y + (size_t)t * D;
    float v[8];
    float ss = 0.f;
#pragma unroll
    for (int m = 0; m < 8; ++m) {
        v[m] = xr[threadIdx.x + 256 * m];
        ss += v[m] * v[m];
    }
    ss = wave_reduce_sum64(ss);
    __shared__ float wsum[4];
    if ((threadIdx.x & 63) == 0) wsum[threadIdx.x >> 6] = ss;
    __syncthreads();
    float tot = wsum[0] + wsum[1] + wsum[2] + wsum[3];
    float r = rsqrtf(tot / (float)D + EPS);
#pragma unroll
    for (int m = 0; m < 8; ++m) {
        int d = threadIdx.x + 256 * m;
        yr[d] = v[m] * r * w[d];
    }
}

// ---------------------------------------------------------------- generic C = alpha*A@W^T (+R)
// A: [M,K] lda, W: [N,K] ldw, C: [M,N] ldc. M%64==0, N%64==0, K%32==0.
__global__ __launch_bounds__(256) void gemm_bt_kernel(
    const float* __restrict__ A, int lda,
    const float* __restrict__ W, int ldw,
    float* __restrict__ C, int ldc,
    const float* __restrict__ R,
    int M, int N, int K, float alpha)
{
    __shared__ float As[64][33];
    __shared__ float Ws[64][33];
    int m0 = blockIdx.y * 64, n0 = blockIdx.x * 64;
    int tid = threadIdx.x;
    int srow = tid >> 2, scol = (tid & 3) * 8;
    int ty = tid >> 4, tx = tid & 15;
    float acc[4][4] = {};
    for (int k0 = 0; k0 < K; k0 += 32) {
        const float* ap = A + (size_t)(m0 + srow) * lda + k0 + scol;
        const float* wp = W + (size_t)(n0 + srow) * ldw + k0 + scol;
        float4 a0 = *(const float4*)ap;
        float4 a1 = *(const float4*)(ap + 4);
        float4 w0 = *(const float4*)wp;
        float4 w1 = *(const float4*)(wp + 4);
        __syncthreads();
        As[srow][scol + 0] = a0.x; As[srow][scol + 1] = a0.y; As[srow][scol + 2] = a0.z; As[srow][scol + 3] = a0.w;
        As[srow][scol + 4] = a1.x; As[srow][scol + 5] = a1.y; As[srow][scol + 6] = a1.z; As[srow][scol + 7] = a1.w;
        Ws[srow][scol + 0] = w0.x; Ws[srow][scol + 1] = w0.y; Ws[srow][scol + 2] = w0.z; Ws[srow][scol + 3] = w0.w;
        Ws[srow][scol + 4] = w1.x; Ws[srow][scol + 5] = w1.y; Ws[srow][scol + 6] = w1.z; Ws[srow][scol + 7] = w1.w;
        __syncthreads();
#pragma unroll
        for (int kk = 0; kk < 32; ++kk) {
            float a[4], b[4];
#pragma unroll
            for (int i = 0; i < 4; ++i) a[i] = As[ty * 4 + i][kk];
#pragma unroll
            for (int j = 0; j < 4; ++j) b[j] = Ws[tx * 4 + j][kk];
#pragma unroll
            for (int i = 0; i < 4; ++i)
#pragma unroll
                for (int j = 0; j < 4; ++j) acc[i][j] += a[i] * b[j];
        }
    }
#pragma unroll
    for (int i = 0; i < 4; ++i) {
#pragma unroll
        for (int j = 0; j < 4; ++j) {
            int r = m0 + ty * 4 + i, c = n0 + tx * 4 + j;
            float v = alpha * acc[i][j];
            if (R) v += R[(size_t)r * ldc + c];
            C[(size_t)r * ldc + c] = v;
        }
    }
}

// ---------------------------------------------------------------- per-head q/k RMSNorm + RoPE
// grid (S, NH+NKV), block 64. thread d handles dims d and d+64.
__global__ void qknorm_rope_kernel(float* __restrict__ q, float* __restrict__ k,
                                   const float* __restrict__ qn_w, const float* __restrict__ kn_w,
                                   const int* __restrict__ pos_ids)
{
    int t = blockIdx.x;
    int h = blockIdx.y;
    int d = threadIdx.x;
    float* base;
    const float* w;
    if (h < NH) { base = q + (size_t)t * D + h * HD;              w = qn_w; }
    else        { base = k + (size_t)t * (NKV * HD) + (h - NH) * HD; w = kn_w; }
    float x1 = base[d], x2 = base[d + 64];
    float ss = wave_reduce_sum64(x1 * x1 + x2 * x2);
    float r = rsqrtf(ss / (float)HD + EPS);
    float n1 = x1 * r * w[d];
    float n2 = x2 * r * w[d + 64];
    float pos = (float)pos_ids[t];
    float freq = powf(1000000.0f, -(float)d * (1.0f / 64.0f));
    float ang = pos * freq;
    float c, s;
    sincosf(ang, &s, &c);
    base[d]      = n1 * c - n2 * s;
    base[d + 64] = n2 * c + n1 * s;
}

// ---------------------------------------------------------------- flash attention (no mask, GQA)
// grid (S/32, NH), block 256. q:[S,2048] k,v:[S,512]
__global__ __launch_bounds__(256) void flash_attn_kernel(
    const float* __restrict__ q, const float* __restrict__ k, const float* __restrict__ v,
    float* __restrict__ o)
{
    int qt = blockIdx.x;
    int h = blockIdx.y;
    int kvh = h >> 2;
    const float scale = 0.08838834764831845f; // 128^-0.5
    __shared__ float qs[32][129];
    __shared__ float ks[32][129];
    __shared__ float vs[32][129];
    __shared__ float ss[32][33];
    int tid = threadIdx.x;
    int srow = tid >> 3, scol = (tid & 7) * 16;
    {
        const float* qp = q + (size_t)(qt * 32 + srow) * D + h * HD + scol;
#pragma unroll
        for (int u = 0; u < 16; u += 4) {
            float4 f = *(const float4*)(qp + u);
            qs[srow][scol + u + 0] = f.x; qs[srow][scol + u + 1] = f.y;
            qs[srow][scol + u + 2] = f.z; qs[srow][scol + u + 3] = f.w;
        }
    }
    float m = -1e30f, l = 0.f;
    float oacc[16] = {};
    int r = tid >> 3, g = tid & 7;
    for (int kt = 0; kt < S / 32; ++kt) {
        __syncthreads();
        const float* kp = k + (size_t)(kt * 32 + srow) * (NKV * HD) + kvh * HD + scol;
        const float* vp = v + (size_t)(kt * 32 + srow) * (NKV * HD) + kvh * HD + scol;
#pragma unroll
        for (int u = 0; u < 16; u += 4) {
            float4 f = *(const float4*)(kp + u);
            ks[srow][scol + u + 0] = f.x; ks[srow][scol + u + 1] = f.y;
            ks[srow][scol + u + 2] = f.z; ks[srow][scol + u + 3] = f.w;
            float4 gg = *(const float4*)(vp + u);
            vs[srow][scol + u + 0] = gg.x; vs[srow][scol + u + 1] = gg.y;
            vs[srow][scol + u + 2] = gg.z; vs[srow][scol + u + 3] = gg.w;
        }
        __syncthreads();
        float sc[4] = {0.f, 0.f, 0.f, 0.f};
        for (int d0 = 0; d0 < HD; ++d0) {
            float qv = qs[r][d0];
#pragma unroll
            for (int j = 0; j < 4; ++j) sc[j] += qv * ks[g + 8 * j][d0];
        }
#pragma unroll
        for (int j = 0; j < 4; ++j) sc[j] *= scale;
        float tmax = fmaxf(fmaxf(sc[0], sc[1]), fmaxf(sc[2], sc[3]));
        for (int off = 1; off < 8; off <<= 1) tmax = fmaxf(tmax, __shfl_xor(tmax, off, 64));
        float mnew = fmaxf(m, tmax);
        float corr = __expf(m - mnew);
        float p[4], psum = 0.f;
#pragma unroll
        for (int j = 0; j < 4; ++j) { p[j] = __expf(sc[j] - mnew); psum += p[j]; }
        for (int off = 1; off < 8; off <<= 1) psum += __shfl_xor(psum, off, 64);
        l = l * corr + psum;
        m = mnew;
#pragma unroll
        for (int jj = 0; jj < 16; ++jj) oacc[jj] *= corr;
#pragma unroll
        for (int j = 0; j < 4; ++j) ss[r][g + 8 * j] = p[j];
        __syncthreads();
#pragma unroll
        for (int kk = 0; kk < 32; ++kk) {
            float pv = ss[r][kk];
#pragma unroll
            for (int jj = 0; jj < 16; ++jj) oacc[jj] += pv * vs[kk][g + 8 * jj];
        }
    }
    float linv = 1.f / l;
    float* op = o + (size_t)(qt * 32 + r) * D + h * HD;
#pragma unroll
    for (int jj = 0; jj < 16; ++jj) op[g + 8 * jj] = oacc[jj] * linv;
}

// ---------------------------------------------------------------- MoE gate + expert lists
__global__ void gate_kernel(const float* __restrict__ x, const float* __restrict__ gw,
                            float* __restrict__ wbuf, int* __restrict__ cnt, int* __restrict__ elist)
{
    int t = blockIdx.x;
    int g = threadIdx.x >> 4, j = threadIdx.x & 15;
    const float* xr = x + (size_t)t * D;
    const float* gr = gw + (size_t)g * D;
    float p = 0.f;
    for (int m = 0; m < D / 16; ++m) p += xr[j + 16 * m] * gr[j + 16 * m];
    for (int off = 8; off; off >>= 1) p += __shfl_down(p, off, 64);
    __shared__ float lg[NE];
    if (j == 0) lg[g] = p;
    __syncthreads();
    if (threadIdx.x == 0) {
        float l0 = -1e30f; int i0 = 0;
        for (int e = 0; e < NE; ++e) if (lg[e] > l0) { l0 = lg[e]; i0 = e; }
        float l1 = -1e30f; int i1 = 0;
        for (int e = 0; e < NE; ++e) if (e != i0 && lg[e] > l1) { l1 = lg[e]; i1 = e; }
        float rr = expf(l1 - l0);
        wbuf[t * 2 + 0] = 1.f / (1.f + rr);
        wbuf[t * 2 + 1] = rr / (1.f + rr);
        int s0 = atomicAdd(&cnt[i0], 1); elist[i0 * S + s0] = t * 2;
        int s1 = atomicAdd(&cnt[i1], 1); elist[i1 * S + s1] = t * 2 + 1;
    }
}

// ---------------------------------------------------------------- MoE up/gate proj + SiLU*u
// grid (NI/64, S/64, NE). abuf[idx][i], idx = t*2+slot
__global__ __launch_bounds__(256) void moe_ffn1_kernel(
    const float* __restrict__ x, const float* __restrict__ Wg, const float* __restrict__ Wu,
    const int* __restrict__ cnt, const int* __restrict__ elist, float* __restrict__ abuf)
{
    int e = blockIdx.z;
    int me = cnt[e];
    int row0 = blockIdx.y * 64;
    if (row0 >= me) return;
    int n0 = blockIdx.x * 64;
    int vr = min(64, me - row0);
    __shared__ float As[64][33], Gs[64][33], Us[64][33];
    __shared__ int rowidx[64];
    int tid = threadIdx.x;
    if (tid < 64) rowidx[tid] = (tid < vr) ? elist[e * S + row0 + tid] : 0;
    __syncthreads();
    int srow = tid >> 2, scol = (tid & 3) * 8;
    int t_tok = rowidx[srow] >> 1;
    bool valid = srow < vr;
    int ty = tid >> 4, tx = tid & 15;
    float ag[4][4] = {}, au[4][4] = {};
    const float* wg_e = Wg + (size_t)e * NI * D;
    const float* wu_e = Wu + (size_t)e * NI * D;
    for (int k0 = 0; k0 < D; k0 += 32) {
        float4 a0, a1;
        if (valid) {
            const float* ap = x + (size_t)t_tok * D + k0 + scol;
            a0 = *(const float4*)ap; a1 = *(const float4*)(ap + 4);
        } else {
            a0 = make_float4(0.f, 0.f, 0.f, 0.f); a1 = a0;
        }
        const float* gp = wg_e + (size_t)(n0 + srow) * D + k0 + scol;
        const float* up = wu_e + (size_t)(n0 + srow) * D + k0 + scol;
        float4 g0 = *(const float4*)gp, g1 = *(const float4*)(gp + 4);
        float4 u0 = *(const float4*)up, u1 = *(const float4*)(up + 4);
        __syncthreads();
        As[srow][scol + 0] = a0.x; As[srow][scol + 1] = a0.y; As[srow][scol + 2] = a0.z; As[srow][scol + 3] = a0.w;
        As[srow][scol + 4] = a1.x; As[srow][scol + 5] = a1.y; As[srow][scol + 6] = a1.z; As[srow][scol + 7] = a1.w;
        Gs[srow][scol + 0] = g0.x; Gs[srow][scol + 1] = g0.y; Gs[srow][scol + 2] = g0.z; Gs[srow][scol + 3] = g0.w;
        Gs[srow][scol + 4] = g1.x; Gs[srow][scol + 5] = g1.y; Gs[srow][scol + 6] = g1.z; Gs[srow][scol + 7] = g1.w;
        Us[srow][scol + 0] = u0.x; Us[srow][scol + 1] = u0.y; Us[srow][scol + 2] = u0.z; Us[srow][scol + 3] = u0.w;
        Us[srow][scol + 4] = u1.x; Us[srow][scol + 5] = u1.y; Us[srow][scol + 6] = u1.z; Us[srow][scol + 7] = u1.w;
        __syncthreads();
#pragma unroll
        for (int kk = 0; kk < 32; ++kk) {
            float a[4], bg[4], bu[4];
#pragma unroll
            for (int i = 0; i < 4; ++i) a[i] = As[ty * 4 + i][kk];
#pragma unroll
            for (int j = 0; j < 4; ++j) { bg[j] = Gs[tx * 4 + j][kk]; bu[j] = Us[tx * 4 + j][kk]; }
#pragma unroll
            for (int i = 0; i < 4; ++i)
#pragma unroll
                for (int j = 0; j < 4; ++j) { ag[i][j] += a[i] * bg[j]; au[i][j] += a[i] * bu[j]; }
        }
    }
#pragma unroll
    for (int i = 0; i < 4; ++i) {
        int rr = ty * 4 + i;
        if (rr < vr) {
            int idx = rowidx[rr];
#pragma unroll
            for (int j = 0; j < 4; ++j) {
                float gg = ag[i][j], uu = au[i][j];
                float aa = gg / (1.f + expf(-gg)) * uu;
                abuf[(size_t)idx * NI + n0 + tx * 4 + j] = aa;
            }
        }
    }
}

// ---------------------------------------------------------------- MoE down proj
// grid (D/64, S/64, NE). ybuf[idx][d]
__global__ __launch_bounds__(256) void moe_ffn2_kernel(
    const float* __restrict__ abuf, const float* __restrict__ Wd,
    const int* __restrict__ cnt, const int* __restrict__ elist, float* __restrict__ ybuf)
{
    int e = blockIdx.z;
    int me = cnt[e];
    int row0 = blockIdx.y * 64;
    if (row0 >= me) return;
    int n0 = blockIdx.x * 64;
    int vr = min(64, me - row0);
    __shared__ float As[64][33], Ws[64][33];
    __shared__ int rowidx[64];
    int tid = threadIdx.x;
    if (tid < 64) rowidx[tid] = (tid < vr) ? elist[e * S + row0 + tid] : 0;
    __syncthreads();
    int srow = tid >> 2, scol = (tid & 3) * 8;
    int aidx = rowidx[srow];
    bool valid = srow < vr;
    int ty = tid >> 4, tx = tid & 15;
    float acc[4][4] = {};
    const float* wd_e = Wd + (size_t)e * D * NI;
    for (int k0 = 0; k0 < NI; k0 += 32) {
        float4 a0, a1;
        if (valid) {
            const float* ap = abuf + (size_t)aidx * NI + k0 + scol;
            a0 = *(const float4*)ap; a1 = *(const float4*)(ap + 4);
        } else {
            a0 = make_float4(0.f, 0.f, 0.f, 0.f); a1 = a0;
        }
        const float* wp = wd_e + (size_t)(n0 + srow) * NI + k0 + scol;
        float4 w0 = *(const float4*)wp, w1 = *(const float4*)(wp + 4);
        __syncthreads();
        As[srow][scol + 0] = a0.x; As[srow][scol + 1] = a0.y; As[srow][scol + 2] = a0.z; As[srow][scol + 3] = a0.w;
        As[srow][scol + 4] = a1.x; As[srow][scol + 5] = a1.y; As[srow][scol + 6] = a1.z; As[srow][scol + 7] = a1.w;
        Ws[srow][scol + 0] = w0.x; Ws[srow][scol + 1] = w0.y; Ws[srow][scol + 2] = w0.z; Ws[srow][scol + 3] = w0.w;
        Ws[srow][scol + 4] = w1.x; Ws[srow][scol + 5] = w1.y; Ws[srow][scol + 6] = w1.z; Ws[srow][scol + 7] = w1.w;
        __syncthreads();
#pragma unroll
        for (int kk = 0; kk < 32; ++kk) {
            float a[4], b[4];
#pragma unroll
            for (int i = 0; i < 4; ++i) a[i] = As[ty * 4 + i][kk];
#pragma unroll
            for (int j = 0; j < 4; ++j) b[j] = Ws[tx * 4 + j][kk];
#pragma unroll
            for (int i = 0; i < 4; ++i)
#pragma unroll
                for (int j = 0; j < 4; ++j) acc[i][j] += a[i] * b[j];
        }
    }
#pragma unroll
    for (int i = 0; i < 4; ++i) {
        int rr = ty * 4 + i;
        if (rr < vr) {
            int idx = rowidx[rr];
#pragma unroll
            for (int j = 0; j < 4; ++j)
                ybuf[(size_t)idx * D + n0 + tx * 4 + j] = acc[i][j];
        }
    }
}

// ---------------------------------------------------------------- final combine
__global__ void combine_kernel(const float* __restrict__ hattn, const float* __restrict__ wbuf,
                               const float* __restrict__ ybuf, float* __restrict__ out)
{
    int i = blockIdx.x * 256 + threadIdx.x;
    int t = i >> 11;
    int d = i & (D - 1);
    out[i] = hattn[i]
           + wbuf[t * 2 + 0] * ybuf[(size_t)(t * 2 + 0) * D + d]
           + wbuf[t * 2 + 1] * ybuf[(size_t)(t * 2 + 1) * D + d];
}

// ---------------------------------------------------------------- launch
extern "C" void kernel_launch(void* const* d_in, const int* in_sizes, int n_in,
                              void* d_out, int out_size, void* d_ws, size_t ws_size,
                              hipStream_t stream)
{
    const float* hidden = (const float*)d_in[0];
    const float* ln1 = (const float*)d_in[1];
    const float* ln2 = (const float*)d_in[2];
    const float* qn  = (const float*)d_in[3];
    const float* kn  = (const float*)d_in[4];
    const float* Wq  = (const float*)d_in[5];
    const float* Wk  = (const float*)d_in[6];
    const float* Wv  = (const float*)d_in[7];
    const float* Wo  = (const float*)d_in[8];
    const float* gw  = (const float*)d_in[9];
    const float* Wg  = (const float*)d_in[10];
    const float* Wu  = (const float*)d_in[11];
    const float* Wd  = (const float*)d_in[12];
    const int*   pos = (const int*)d_in[13];

    float* ws    = (float*)d_ws;
    float* h1    = ws;                    // 2097152
    float* qb    = h1 + 2097152;          // 2097152
    float* kb    = qb + 2097152;          // 524288
    float* vb    = kb + 524288;           // 524288
    float* attn  = vb + 524288;           // 2097152
    float* hattn = attn + 2097152;        // 2097152
    float* h2    = hattn + 2097152;       // 2097152
    float* abuf  = h2 + 2097152;          // 1572864
    float* ybuf  = abuf + 1572864;        // 4194304
    float* wbuf  = ybuf + 4194304;        // 2048
    int*   cnt   = (int*)(wbuf + 2048);   // 16
    int*   elist = cnt + 16;              // 16*1024
    float* out   = (float*)d_out;

    hipMemsetAsync(cnt, 0, NE * sizeof(int), stream);

    rmsnorm_kernel<<<S, 256, 0, stream>>>(hidden, ln1, h1);
    gemm_bt_kernel<<<dim3(32, 16), 256, 0, stream>>>(h1, D, Wq, D, qb, D, nullptr, S, 2048, D, 1.f);
    gemm_bt_kernel<<<dim3(8, 16), 256, 0, stream>>>(h1, D, Wk, D, kb, 512, nullptr, S, 512, D, 1.f);
    gemm_bt_kernel<<<dim3(8, 16), 256, 0, stream>>>(h1, D, Wv, D, vb, 512, nullptr, S, 512, D, 1.f);
    qknorm_rope_kernel<<<dim3(S, NH + NKV), 64, 0, stream>>>(qb, kb, qn, kn, pos);
    flash_attn_kernel<<<dim3(S / 32, NH), 256, 0, stream>>>(qb, kb, vb, attn);
    gemm_bt_kernel<<<dim3(32, 16), 256, 0, stream>>>(attn, D, Wo, D, hattn, D, hidden, S, D, D, 1.f);
    rmsnorm_kernel<<<S, 256, 0, stream>>>(hattn, ln2, h2);
    gate_kernel<<<S, 256, 0, stream>>>(h2, gw, wbuf, cnt, elist);
    moe_ffn1_kernel<<<dim3(NI / 64, 16, NE), 256, 0, stream>>>(h2, Wg, Wu, cnt, elist, abuf);
    moe_ffn2_kernel<<<dim3(D / 64, 16, NE), 256, 0, stream>>>(abuf, Wd, cnt, elist, ybuf);
    combine_kernel<<<dim3(S * D / 256), 256, 0, stream>>>(hattn, wbuf, ybuf, out);
}

// Round 2
// 998.834 us; speedup vs baseline: 1.7288x; 1.7288x over previous
//
#include <hip/hip_runtime.h>
#include <hip/hip_bf16.h>
#include <math.h>

#define D 2048
#define NH 16
#define NKV 4
#define HD 128
#define NE 16
#define NI 768
#define S 1024
#define EPS 1e-6f

typedef __attribute__((ext_vector_type(8))) short bf16x8;
typedef __attribute__((ext_vector_type(4))) float f32x4;

__device__ __forceinline__ float wave_reduce_sum64(float v) {
    for (int off = 32; off; off >>= 1) v += __shfl_xor(v, off, 64);
    return v;
}

__device__ __forceinline__ unsigned short f2bf(float f) {
    unsigned int x = __float_as_uint(f);
    x += 0x7FFFu + ((x >> 16) & 1u);   // round-to-nearest-even
    return (unsigned short)(x >> 16);
}

__device__ __forceinline__ bf16x8 pack8(const float4 a, const float4 b) {
    bf16x8 r;
    r[0] = (short)f2bf(a.x); r[1] = (short)f2bf(a.y);
    r[2] = (short)f2bf(a.z); r[3] = (short)f2bf(a.w);
    r[4] = (short)f2bf(b.x); r[5] = (short)f2bf(b.y);
    r[6] = (short)f2bf(b.z); r[7] = (short)f2bf(b.w);
    return r;
}

// ---------------------------------------------------------------- RMSNorm over D
__global__ void rmsnorm_kernel(const float* __restrict__ x, const float* __restrict__ w,
                               float* __restrict__ y) {
    int t = blockIdx.x;
    const float* xr = x + (size_t)t * D;
    float* yr = y + (size_t)t * D;
    float v[8];
    float ss = 0.f;
#pragma unroll
    for (int m = 0; m < 8; ++m) {
        v[m] = xr[threadIdx.x + 256 * m];
        ss += v[m] * v[m];
    }
    ss = wave_reduce_sum64(ss);
    __shared__ float wsum[4];
    if ((threadIdx.x & 63) == 0) wsum[threadIdx.x >> 6] = ss;
    __syncthreads();
    float tot = wsum[0] + wsum[1] + wsum[2] + wsum[3];
    float r = rsqrtf(tot / (float)D + EPS);
#pragma unroll
    for (int m = 0; m < 8; ++m) {
        int d = threadIdx.x + 256 * m;
        yr[d] = v[m] * r * w[d];
    }
}

// ---------------------------------------------------------------- unified MFMA GEMM
// C[row][n] = sum_k A[arow][k] * W[n][k]  (+R[row][n] dense mode)
// dense mode (cnt==null): rows = m0+i, M rows total (M%64==0).
// gather mode: expert e=blockIdx.z, me=cnt[e], idx=elist+e*S;
//   A row = idx[i]>>a_shift, C row = idx[i], W += e*N*K.
// BM=BN=BK=64, 256 threads = 4 waves (2x2), wave tile 32x32 via 2x2 16x16 frags.
__global__ __launch_bounds__(256) void mfma_gemm_kernel(
    const float* __restrict__ A, int lda, int a_shift,
    const float* __restrict__ W, int ldw,
    float* __restrict__ C, int ldc,
    const float* __restrict__ R,
    const int* __restrict__ cnt, const int* __restrict__ elist,
    int M, int N, int K)
{
    int e = blockIdx.z;
    int me = M;
    const int* idx = nullptr;
    if (cnt) {
        me = cnt[e];
        idx = elist + e * S;
        W += (size_t)e * N * K;
    }
    int m0 = blockIdx.y * 64;
    if (m0 >= me) return;
    int n0 = blockIdx.x * 64;

    __shared__ unsigned short As[64 * 64];
    __shared__ unsigned short Bs[64 * 64];
    __shared__ int ridx[64];

    int tid = threadIdx.x;
    if (cnt) {
        if (tid < 64) ridx[tid] = (m0 + tid < me) ? idx[m0 + tid] : -1;
        __syncthreads();
    }

    int srow = tid >> 2;        // staging row 0..63
    int scg  = tid & 3;         // 16-float column group
    int col0 = scg * 16;

    const float* arow = nullptr;
    if (cnt) {
        int rv = ridx[srow];
        if (rv >= 0) arow = A + (size_t)(rv >> a_shift) * lda;
    } else {
        arow = A + (size_t)(m0 + srow) * lda;
    }
    const float* wrow = W + (size_t)(n0 + srow) * ldw;

    // swizzled LDS write offsets (ushort units): row*64 + (granule ^ (row&7))*8
    int g0 = (scg * 2)     ^ (srow & 7);
    int g1 = (scg * 2 + 1) ^ (srow & 7);
    int w0 = srow * 64 + g0 * 8;
    int w1 = srow * 64 + g1 * 8;

    int wid = tid >> 6, lane = tid & 63;
    int wm = wid >> 1, wn = wid & 1;
    int l16 = lane & 15, lhi = lane >> 4;

    // frag read offsets: row = w*32 + f*16 + l16; granule = (kh*4+lhi) ^ (row&7)
    int ra[2][2], rb[2][2];
#pragma unroll
    for (int f = 0; f < 2; ++f) {
        int rowa = wm * 32 + f * 16 + l16;
        int rowb = wn * 32 + f * 16 + l16;
#pragma unroll
        for (int kh = 0; kh < 2; ++kh) {
            ra[f][kh] = rowa * 64 + (((kh * 4 + lhi) ^ (rowa & 7))) * 8;
            rb[f][kh] = rowb * 64 + (((kh * 4 + lhi) ^ (rowb & 7))) * 8;
        }
    }

    f32x4 acc[2][2] = {};

    for (int k0 = 0; k0 < K; k0 += 64) {
        float4 av[4], wv[4];
#pragma unroll
        for (int u = 0; u < 4; ++u) {
            if (arow) av[u] = *(const float4*)(arow + k0 + col0 + u * 4);
            else      av[u] = make_float4(0.f, 0.f, 0.f, 0.f);
            wv[u] = *(const float4*)(wrow + k0 + col0 + u * 4);
        }
        bf16x8 pa0 = pack8(av[0], av[1]);
        bf16x8 pa1 = pack8(av[2], av[3]);
        bf16x8 pw0 = pack8(wv[0], wv[1]);
        bf16x8 pw1 = pack8(wv[2], wv[3]);
        __syncthreads();
        *(bf16x8*)(As + w0) = pa0;
        *(bf16x8*)(As + w1) = pa1;
        *(bf16x8*)(Bs + w0) = pw0;
        *(bf16x8*)(Bs + w1) = pw1;
        __syncthreads();
#pragma unroll
        for (int kh = 0; kh < 2; ++kh) {
            bf16x8 af0 = *(const bf16x8*)(As + ra[0][kh]);
            bf16x8 af1 = *(const bf16x8*)(As + ra[1][kh]);
            bf16x8 bf0 = *(const bf16x8*)(Bs + rb[0][kh]);
            bf16x8 bf1 = *(const bf16x8*)(Bs + rb[1][kh]);
            acc[0][0] = __builtin_amdgcn_mfma_f32_16x16x32_bf16(af0, bf0, acc[0][0], 0, 0, 0);
            acc[0][1] = __builtin_amdgcn_mfma_f32_16x16x32_bf16(af0, bf1, acc[0][1], 0, 0, 0);
            acc[1][0] = __builtin_amdgcn_mfma_f32_16x16x32_bf16(af1, bf0, acc[1][0], 0, 0, 0);
            acc[1][1] = __builtin_amdgcn_mfma_f32_16x16x32_bf16(af1, bf1, acc[1][1], 0, 0, 0);
        }
    }

    // epilogue: C/D layout col = lane&15, row = (lane>>4)*4 + reg  [m89/m91]
#pragma unroll
    for (int mi = 0; mi < 2; ++mi) {
#pragma unroll
        for (int r = 0; r < 4; ++r) {
            int lrow = wm * 32 + mi * 16 + lhi * 4 + r;
            int grow;
            if (cnt) {
                int rv = ridx[lrow];
                if (rv < 0) continue;
                grow = rv;
            } else {
                grow = m0 + lrow;
            }
#pragma unroll
            for (int ni = 0; ni < 2; ++ni) {
                int gcol = n0 + wn * 32 + ni * 16 + l16;
                float v = acc[mi][ni][r];
                if (R) v += R[(size_t)grow * ldc + gcol];
                C[(size_t)grow * ldc + gcol] = v;
            }
        }
    }
}

// ---------------------------------------------------------------- per-head q/k RMSNorm + RoPE
__global__ void qknorm_rope_kernel(float* __restrict__ q, float* __restrict__ k,
                                   const float* __restrict__ qn_w, const float* __restrict__ kn_w,
                                   const int* __restrict__ pos_ids)
{
    int t = blockIdx.x;
    int h = blockIdx.y;
    int d = threadIdx.x;
    float* base;
    const float* w;
    if (h < NH) { base = q + (size_t)t * D + h * HD;                 w = qn_w; }
    else        { base = k + (size_t)t * (NKV * HD) + (h - NH) * HD; w = kn_w; }
    float x1 = base[d], x2 = base[d + 64];
    float ss = wave_reduce_sum64(x1 * x1 + x2 * x2);
    float r = rsqrtf(ss / (float)HD + EPS);
    float n1 = x1 * r * w[d];
    float n2 = x2 * r * w[d + 64];
    float pos = (float)pos_ids[t];
    float freq = powf(1000000.0f, -(float)d * (1.0f / 64.0f));
    float ang = pos * freq;
    float c, s;
    sincosf(ang, &s, &c);
    base[d]      = n1 * c - n2 * s;
    base[d + 64] = n2 * c + n1 * s;
}

// ---------------------------------------------------------------- flash attention (no mask, GQA)
__global__ __launch_bounds__(256) void flash_attn_kernel(
    const float* __restrict__ q, const float* __restrict__ k, const float* __restrict__ v,
    float* __restrict__ o)
{
    int qt = blockIdx.x;
    int h = blockIdx.y;
    int kvh = h >> 2;
    const float scale = 0.08838834764831845f; // 128^-0.5
    __shared__ float qs[32][129];
    __shared__ float ks[32][129];
    __shared__ float vs[32][129];
    __shared__ float ss[32][33];
    int tid = threadIdx.x;
    int srow = tid >> 3, scol = (tid & 7) * 16;
    {
        const float* qp = q + (size_t)(qt * 32 + srow) * D + h * HD + scol;
#pragma unroll
        for (int u = 0; u < 16; u += 4) {
            float4 f = *(const float4*)(qp + u);
            qs[srow][scol + u + 0] = f.x; qs[srow][scol + u + 1] = f.y;
            qs[srow][scol + u + 2] = f.z; qs[srow][scol + u + 3] = f.w;
        }
    }
    float m = -1e30f, l = 0.f;
    float oacc[16] = {};
    int r = tid >> 3, g = tid & 7;
    for (int kt = 0; kt < S / 32; ++kt) {
        __syncthreads();
        const float* kp = k + (size_t)(kt * 32 + srow) * (NKV * HD) + kvh * HD + scol;
        const float* vp = v + (size_t)(kt * 32 + srow) * (NKV * HD) + kvh * HD + scol;
#pragma unroll
        for (int u = 0; u < 16; u += 4) {
            float4 f = *(const float4*)(kp + u);
            ks[srow][scol + u + 0] = f.x; ks[srow][scol + u + 1] = f.y;
            ks[srow][scol + u + 2] = f.z; ks[srow][scol + u + 3] = f.w;
            float4 gg = *(const float4*)(vp + u);
            vs[srow][scol + u + 0] = gg.x; vs[srow][scol + u + 1] = gg.y;
            vs[srow][scol + u + 2] = gg.z; vs[srow][scol + u + 3] = gg.w;
        }
        __syncthreads();
        float sc[4] = {0.f, 0.f, 0.f, 0.f};
        for (int d0 = 0; d0 < HD; ++d0) {
            float qv = qs[r][d0];
#pragma unroll
            for (int j = 0; j < 4; ++j) sc[j] += qv * ks[g + 8 * j][d0];
        }
#pragma unroll
        for (int j = 0; j < 4; ++j) sc[j] *= scale;
        float tmax = fmaxf(fmaxf(sc[0], sc[1]), fmaxf(sc[2], sc[3]));
        for (int off = 1; off < 8; off <<= 1) tmax = fmaxf(tmax, __shfl_xor(tmax, off, 64));
        float mnew = fmaxf(m, tmax);
        float corr = __expf(m - mnew);
        float p[4], psum = 0.f;
#pragma unroll
        for (int j = 0; j < 4; ++j) { p[j] = __expf(sc[j] - mnew); psum += p[j]; }
        for (int off = 1; off < 8; off <<= 1) psum += __shfl_xor(psum, off, 64);
        l = l * corr + psum;
        m = mnew;
#pragma unroll
        for (int jj = 0; jj < 16; ++jj) oacc[jj] *= corr;
#pragma unroll
        for (int j = 0; j < 4; ++j) ss[r][g + 8 * j] = p[j];
        __syncthreads();
#pragma unroll
        for (int kk = 0; kk < 32; ++kk) {
            float pv = ss[r][kk];
#pragma unroll
            for (int jj = 0; jj < 16; ++jj) oacc[jj] += pv * vs[kk][g + 8 * jj];
        }
    }
    float linv = 1.f / l;
    float* op = o + (size_t)(qt * 32 + r) * D + h * HD;
#pragma unroll
    for (int jj = 0; jj < 16; ++jj) op[g + 8 * jj] = oacc[jj] * linv;
}

// ---------------------------------------------------------------- MoE gate + expert lists
__global__ void gate_kernel(const float* __restrict__ x, const float* __restrict__ gw,
                            float* __restrict__ wbuf, int* __restrict__ cnt, int* __restrict__ elist)
{
    int t = blockIdx.x;
    int g = threadIdx.x >> 4, j = threadIdx.x & 15;
    const float* xr = x + (size_t)t * D;
    const float* gr = gw + (size_t)g * D;
    float p = 0.f;
    for (int m = 0; m < D / 16; ++m) p += xr[j + 16 * m] * gr[j + 16 * m];
    for (int off = 8; off; off >>= 1) p += __shfl_down(p, off, 64);
    __shared__ float lg[NE];
    if (j == 0) lg[g] = p;
    __syncthreads();
    if (threadIdx.x == 0) {
        float l0 = -1e30f; int i0 = 0;
        for (int e = 0; e < NE; ++e) if (lg[e] > l0) { l0 = lg[e]; i0 = e; }
        float l1 = -1e30f; int i1 = 0;
        for (int e = 0; e < NE; ++e) if (e != i0 && lg[e] > l1) { l1 = lg[e]; i1 = e; }
        float rr = expf(l1 - l0);
        wbuf[t * 2 + 0] = 1.f / (1.f + rr);
        wbuf[t * 2 + 1] = rr / (1.f + rr);
        int s0 = atomicAdd(&cnt[i0], 1); elist[i0 * S + s0] = t * 2;
        int s1 = atomicAdd(&cnt[i1], 1); elist[i1 * S + s1] = t * 2 + 1;
    }
}

// ---------------------------------------------------------------- silu(g)*u
__global__ void silu_mul_kernel(const float* __restrict__ g, const float* __restrict__ u,
                                float* __restrict__ a)
{
    int i = blockIdx.x * 256 + threadIdx.x;
    float gg = g[i];
    a[i] = gg / (1.f + __expf(-gg)) * u[i];
}

// ---------------------------------------------------------------- final combine
__global__ void combine_kernel(const float* __restrict__ hattn, const float* __restrict__ wbuf,
                               const float* __restrict__ ybuf, float* __restrict__ out)
{
    int i = blockIdx.x * 256 + threadIdx.x;
    int t = i >> 11;
    int d = i & (D - 1);
    out[i] = hattn[i]
           + wbuf[t * 2 + 0] * ybuf[(size_t)(t * 2 + 0) * D + d]
           + wbuf[t * 2 + 1] * ybuf[(size_t)(t * 2 + 1) * D + d];
}

// ---------------------------------------------------------------- launch
extern "C" void kernel_launch(void* const* d_in, const int* in_sizes, int n_in,
                              void* d_out, int out_size, void* d_ws, size_t ws_size,
                              hipStream_t stream)
{
    const float* hidden = (const float*)d_in[0];
    const float* ln1 = (const float*)d_in[1];
    const float* ln2 = (const float*)d_in[2];
    const float* qn  = (const float*)d_in[3];
    const float* kn  = (const float*)d_in[4];
    const float* Wq  = (const float*)d_in[5];
    const float* Wk  = (const float*)d_in[6];
    const float* Wv  = (const float*)d_in[7];
    const float* Wo  = (const float*)d_in[8];
    const float* gw  = (const float*)d_in[9];
    const float* Wg  = (const float*)d_in[10];
    const float* Wu  = (const float*)d_in[11];
    const float* Wd  = (const float*)d_in[12];
    const int*   pos = (const int*)d_in[13];

    float* ws    = (float*)d_ws;
    float* h1    = ws;                    // 2M floats; later reused as gbuf (1.5M)
    float* qb    = h1 + 2097152;          // 2M; later reused as ubuf (1.5M)
    float* kb    = qb + 2097152;          // 0.5M
    float* vb    = kb + 524288;           // 0.5M
    float* attn  = vb + 524288;           // 2M; later reused as abuf (1.5M)
    float* hattn = attn + 2097152;        // 2M
    float* h2    = hattn + 2097152;       // 2M
    float* ybuf  = h2 + 2097152;          // 4M
    float* wbuf  = ybuf + 4194304;        // 2048
    int*   cnt   = (int*)(wbuf + 2048);   // 16
    int*   elist = cnt + 16;              // 16*1024
    float* gbuf  = h1;
    float* ubuf  = qb;
    float* abuf  = attn;
    float* out   = (float*)d_out;

    hipMemsetAsync(cnt, 0, NE * sizeof(int), stream);

    rmsnorm_kernel<<<S, 256, 0, stream>>>(hidden, ln1, h1);
    // QKV projections (bf16 MFMA)
    mfma_gemm_kernel<<<dim3(32, 16, 1), 256, 0, stream>>>(h1, D, 0, Wq, D, qb, 2048, nullptr, nullptr, nullptr, S, 2048, D);
    mfma_gemm_kernel<<<dim3(8, 16, 1), 256, 0, stream>>>(h1, D, 0, Wk, D, kb, 512, nullptr, nullptr, nullptr, S, 512, D);
    mfma_gemm_kernel<<<dim3(8, 16, 1), 256, 0, stream>>>(h1, D, 0, Wv, D, vb, 512, nullptr, nullptr, nullptr, S, 512, D);
    qknorm_rope_kernel<<<dim3(S, NH + NKV), 64, 0, stream>>>(qb, kb, qn, kn, pos);
    flash_attn_kernel<<<dim3(S / 32, NH), 256, 0, stream>>>(qb, kb, vb, attn);
    // O projection + residual
    mfma_gemm_kernel<<<dim3(32, 16, 1), 256, 0, stream>>>(attn, D, 0, Wo, D, hattn, D, hidden, nullptr, nullptr, S, 2048, D);
    rmsnorm_kernel<<<S, 256, 0, stream>>>(hattn, ln2, h2);
    gate_kernel<<<S, 256, 0, stream>>>(h2, gw, wbuf, cnt, elist);
    // MoE expert GEMMs (gathered)
    mfma_gemm_kernel<<<dim3(NI / 64, 16, NE), 256, 0, stream>>>(h2, D, 1, Wg, D, gbuf, NI, nullptr, cnt, elist, 0, NI, D);
    mfma_gemm_kernel<<<dim3(NI / 64, 16, NE), 256, 0, stream>>>(h2, D, 1, Wu, D, ubuf, NI, nullptr, cnt, elist, 0, NI, D);
    silu_mul_kernel<<<dim3(2 * S * NI / 256), 256, 0, stream>>>(gbuf, ubuf, abuf);
    mfma_gemm_kernel<<<dim3(D / 64, 16, NE), 256, 0, stream>>>(abuf, NI, 0, Wd, NI, ybuf, D, nullptr, cnt, elist, 0, D, NI);
    combine_kernel<<<dim3(S * D / 256), 256, 0, stream>>>(hattn, wbuf, ybuf, out);
}

// Round 3
// 702.497 us; speedup vs baseline: 2.4581x; 1.4218x over previous
//
#include <hip/hip_runtime.h>
#include <hip/hip_bf16.h>
#include <math.h>

#define D 2048
#define NH 16
#define NKV 4
#define HD 128
#define NE 16
#define NI 768
#define S 1024
#define EPS 1e-6f

typedef __attribute__((ext_vector_type(8))) short bf16x8;
typedef __attribute__((ext_vector_type(4))) float f32x4;

__device__ __forceinline__ float wave_reduce_sum64(float v) {
    for (int off = 32; off; off >>= 1) v += __shfl_xor(v, off, 64);
    return v;
}

__device__ __forceinline__ unsigned short f2bf(float f) {
    unsigned int x = __float_as_uint(f);
    x += 0x7FFFu + ((x >> 16) & 1u);   // round-to-nearest-even
    return (unsigned short)(x >> 16);
}

__device__ __forceinline__ bf16x8 pack8(const float4 a, const float4 b) {
    bf16x8 r;
    r[0] = (short)f2bf(a.x); r[1] = (short)f2bf(a.y);
    r[2] = (short)f2bf(a.z); r[3] = (short)f2bf(a.w);
    r[4] = (short)f2bf(b.x); r[5] = (short)f2bf(b.y);
    r[6] = (short)f2bf(b.z); r[7] = (short)f2bf(b.w);
    return r;
}

// ---------------------------------------------------------------- RMSNorm over D
__global__ void rmsnorm_kernel(const float* __restrict__ x, const float* __restrict__ w,
                               float* __restrict__ y) {
    int t = blockIdx.x;
    const float* xr = x + (size_t)t * D;
    float* yr = y + (size_t)t * D;
    float v[8];
    float ss = 0.f;
#pragma unroll
    for (int m = 0; m < 8; ++m) {
        v[m] = xr[threadIdx.x + 256 * m];
        ss += v[m] * v[m];
    }
    ss = wave_reduce_sum64(ss);
    __shared__ float wsum[4];
    if ((threadIdx.x & 63) == 0) wsum[threadIdx.x >> 6] = ss;
    __syncthreads();
    float tot = wsum[0] + wsum[1] + wsum[2] + wsum[3];
    float r = rsqrtf(tot / (float)D + EPS);
#pragma unroll
    for (int m = 0; m < 8; ++m) {
        int d = threadIdx.x + 256 * m;
        yr[d] = v[m] * r * w[d];
    }
}

// ---------------------------------------------------------------- unified MFMA GEMM
__global__ __launch_bounds__(256) void mfma_gemm_kernel(
    const float* __restrict__ A, int lda, int a_shift,
    const float* __restrict__ W, int ldw,
    float* __restrict__ C, int ldc,
    const float* __restrict__ R,
    const int* __restrict__ cnt, const int* __restrict__ elist,
    int M, int N, int K)
{
    int e = blockIdx.z;
    int me = M;
    const int* idx = nullptr;
    if (cnt) {
        me = cnt[e];
        idx = elist + e * S;
        W += (size_t)e * N * K;
    }
    int m0 = blockIdx.y * 64;
    if (m0 >= me) return;
    int n0 = blockIdx.x * 64;

    __shared__ unsigned short As[64 * 64];
    __shared__ unsigned short Bs[64 * 64];
    __shared__ int ridx[64];

    int tid = threadIdx.x;
    if (cnt) {
        if (tid < 64) ridx[tid] = (m0 + tid < me) ? idx[m0 + tid] : -1;
        __syncthreads();
    }

    int srow = tid >> 2;
    int scg  = tid & 3;
    int col0 = scg * 16;

    const float* arow = nullptr;
    if (cnt) {
        int rv = ridx[srow];
        if (rv >= 0) arow = A + (size_t)(rv >> a_shift) * lda;
    } else {
        arow = A + (size_t)(m0 + srow) * lda;
    }
    const float* wrow = W + (size_t)(n0 + srow) * ldw;

    int g0 = (scg * 2)     ^ (srow & 7);
    int g1 = (scg * 2 + 1) ^ (srow & 7);
    int w0 = srow * 64 + g0 * 8;
    int w1 = srow * 64 + g1 * 8;

    int wid = tid >> 6, lane = tid & 63;
    int wm = wid >> 1, wn = wid & 1;
    int l16 = lane & 15, lhi = lane >> 4;

    int ra[2][2], rb[2][2];
#pragma unroll
    for (int f = 0; f < 2; ++f) {
        int rowa = wm * 32 + f * 16 + l16;
        int rowb = wn * 32 + f * 16 + l16;
#pragma unroll
        for (int kh = 0; kh < 2; ++kh) {
            ra[f][kh] = rowa * 64 + (((kh * 4 + lhi) ^ (rowa & 7))) * 8;
            rb[f][kh] = rowb * 64 + (((kh * 4 + lhi) ^ (rowb & 7))) * 8;
        }
    }

    f32x4 acc[2][2] = {};

    for (int k0 = 0; k0 < K; k0 += 64) {
        float4 av[4], wv[4];
#pragma unroll
        for (int u = 0; u < 4; ++u) {
            if (arow) av[u] = *(const float4*)(arow + k0 + col0 + u * 4);
            else      av[u] = make_float4(0.f, 0.f, 0.f, 0.f);
            wv[u] = *(const float4*)(wrow + k0 + col0 + u * 4);
        }
        bf16x8 pa0 = pack8(av[0], av[1]);
        bf16x8 pa1 = pack8(av[2], av[3]);
        bf16x8 pw0 = pack8(wv[0], wv[1]);
        bf16x8 pw1 = pack8(wv[2], wv[3]);
        __syncthreads();
        *(bf16x8*)(As + w0) = pa0;
        *(bf16x8*)(As + w1) = pa1;
        *(bf16x8*)(Bs + w0) = pw0;
        *(bf16x8*)(Bs + w1) = pw1;
        __syncthreads();
#pragma unroll
        for (int kh = 0; kh < 2; ++kh) {
            bf16x8 af0 = *(const bf16x8*)(As + ra[0][kh]);
            bf16x8 af1 = *(const bf16x8*)(As + ra[1][kh]);
            bf16x8 bf0 = *(const bf16x8*)(Bs + rb[0][kh]);
            bf16x8 bf1 = *(const bf16x8*)(Bs + rb[1][kh]);
            acc[0][0] = __builtin_amdgcn_mfma_f32_16x16x32_bf16(af0, bf0, acc[0][0], 0, 0, 0);
            acc[0][1] = __builtin_amdgcn_mfma_f32_16x16x32_bf16(af0, bf1, acc[0][1], 0, 0, 0);
            acc[1][0] = __builtin_amdgcn_mfma_f32_16x16x32_bf16(af1, bf0, acc[1][0], 0, 0, 0);
            acc[1][1] = __builtin_amdgcn_mfma_f32_16x16x32_bf16(af1, bf1, acc[1][1], 0, 0, 0);
        }
    }

#pragma unroll
    for (int mi = 0; mi < 2; ++mi) {
#pragma unroll
        for (int r = 0; r < 4; ++r) {
            int lrow = wm * 32 + mi * 16 + lhi * 4 + r;
            int grow;
            if (cnt) {
                int rv = ridx[lrow];
                if (rv < 0) continue;
                grow = rv;
            } else {
                grow = m0 + lrow;
            }
#pragma unroll
            for (int ni = 0; ni < 2; ++ni) {
                int gcol = n0 + wn * 32 + ni * 16 + l16;
                float v = acc[mi][ni][r];
                if (R) v += R[(size_t)grow * ldc + gcol];
                C[(size_t)grow * ldc + gcol] = v;
            }
        }
    }
}

// ---------------------------------------------------------------- q/k RMSNorm + RoPE -> bf16
// grid (S, NH+NKV), block 64. q-scale (HD^-0.5) folded into q output.
__global__ void qkrope_bf16_kernel(const float* __restrict__ q, const float* __restrict__ k,
                                   const float* __restrict__ qn_w, const float* __restrict__ kn_w,
                                   const int* __restrict__ pos_ids,
                                   unsigned short* __restrict__ qbh, unsigned short* __restrict__ kbh)
{
    int t = blockIdx.x;
    int h = blockIdx.y;
    int d = threadIdx.x;
    const float* base;
    const float* w;
    unsigned short* ob;
    float scale;
    if (h < NH) {
        base = q + (size_t)t * D + h * HD; w = qn_w;
        ob = qbh + (size_t)t * D + h * HD; scale = 0.08838834764831845f;
    } else {
        base = k + (size_t)t * (NKV * HD) + (h - NH) * HD; w = kn_w;
        ob = kbh + (size_t)t * (NKV * HD) + (h - NH) * HD; scale = 1.0f;
    }
    float x1 = base[d], x2 = base[d + 64];
    float ss = wave_reduce_sum64(x1 * x1 + x2 * x2);
    float r = rsqrtf(ss / (float)HD + EPS);
    float n1 = x1 * r * w[d];
    float n2 = x2 * r * w[d + 64];
    float pos = (float)pos_ids[t];
    float freq = powf(1000000.0f, -(float)d * (1.0f / 64.0f));
    float ang = pos * freq;
    float c, s;
    sincosf(ang, &s, &c);
    ob[d]      = f2bf((n1 * c - n2 * s) * scale);
    ob[d + 64] = f2bf((n2 * c + n1 * s) * scale);
}

// ---------------------------------------------------------------- V -> bf16 V^T [KV][HD][S]
// grid (S/64, HD/64, NKV), block 256
__global__ void vtrans_kernel(const float* __restrict__ vb, unsigned short* __restrict__ vbt)
{
    __shared__ unsigned short tile[64][65];
    int s0 = blockIdx.x * 64, d0 = blockIdx.y * 64, kvh = blockIdx.z;
    int tid = threadIdx.x;
    {
        int i = tid >> 2;            // s index
        int j4 = (tid & 3) * 16;     // d chunk
        const float* src = vb + (size_t)(s0 + i) * (NKV * HD) + kvh * HD + d0 + j4;
#pragma unroll
        for (int u = 0; u < 4; ++u) {
            float4 f = *(const float4*)(src + u * 4);
            tile[i][j4 + u * 4 + 0] = f2bf(f.x);
            tile[i][j4 + u * 4 + 1] = f2bf(f.y);
            tile[i][j4 + u * 4 + 2] = f2bf(f.z);
            tile[i][j4 + u * 4 + 3] = f2bf(f.w);
        }
    }
    __syncthreads();
    {
        int j = tid >> 2;            // d index
        int i4 = (tid & 3) * 16;     // s chunk
        bf16x8 o0, o1;
#pragma unroll
        for (int u = 0; u < 8; ++u) {
            o0[u] = (short)tile[i4 + u][j];
            o1[u] = (short)tile[i4 + 8 + u][j];
        }
        unsigned short* dst = vbt + ((size_t)kvh * HD + d0 + j) * S + s0 + i4;
        *(bf16x8*)(dst) = o0;
        *(bf16x8*)(dst + 8) = o1;
    }
}

// ---------------------------------------------------------------- MFMA flash attention
// grid (S/64, NH), block 256 = 4 waves; wave w owns q-rows [w*16, w*16+16).
__global__ __launch_bounds__(256) void flash_attn_mfma_kernel(
    const unsigned short* __restrict__ qbh, const unsigned short* __restrict__ kbh,
    const unsigned short* __restrict__ vbt, float* __restrict__ o)
{
    int qt = blockIdx.x;
    int h  = blockIdx.y;
    int kvh = h >> 2;

    __shared__ unsigned short Qs[64 * 128];   // [qrow][d], granule^(row&7) swizzle (16 granules)
    __shared__ unsigned short Ks[64 * 128];   // [kvrow][d], same swizzle
    __shared__ unsigned short Vs[128 * 64];   // V^T tile [d][kv], granule^(row&7) (8 granules)
    __shared__ unsigned short Ps[4][16 * 72]; // per-wave P [qrel][kv], pad 72

    int tid = threadIdx.x;
    int wid = tid >> 6, lane = tid & 63;
    int l16 = lane & 15, lhi = lane >> 4;

    // ---- stage Q once
    {
        int r = tid >> 2;
        int gb = (tid & 3) * 4;
        const unsigned short* src = qbh + (size_t)(qt * 64 + r) * D + h * HD;
#pragma unroll
        for (int u = 0; u < 4; ++u) {
            int g = gb + u;
            bf16x8 val = *(const bf16x8*)(src + g * 8);
            *(bf16x8*)(Qs + r * 128 + (g ^ (r & 7)) * 8) = val;
        }
    }

    // Q A-frag offsets
    int qrow = wid * 16 + l16;
    int qoff[4];
#pragma unroll
    for (int kh = 0; kh < 4; ++kh)
        qoff[kh] = qrow * 128 + (((kh * 4 + lhi) ^ (qrow & 7))) * 8;

    float mreg[4], lreg[4];
#pragma unroll
    for (int r = 0; r < 4; ++r) { mreg[r] = -3.0e38f; lreg[r] = 0.f; }
    f32x4 oacc[8] = {};

    for (int kt = 0; kt < S / 64; ++kt) {
        __syncthreads();
        // stage K tile [64][128]
        {
            int r = tid >> 2;
            int gb = (tid & 3) * 4;
            const unsigned short* src = kbh + (size_t)(kt * 64 + r) * (NKV * HD) + kvh * HD;
#pragma unroll
            for (int u = 0; u < 4; ++u) {
                int g = gb + u;
                bf16x8 val = *(const bf16x8*)(src + g * 8);
                *(bf16x8*)(Ks + r * 128 + (g ^ (r & 7)) * 8) = val;
            }
        }
        // stage V^T tile [128][64]
        {
            int r = tid >> 1;
            int gb = (tid & 1) * 4;
            const unsigned short* src = vbt + ((size_t)kvh * HD + r) * S + kt * 64;
#pragma unroll
            for (int u = 0; u < 4; ++u) {
                int g = gb + u;
                bf16x8 val = *(const bf16x8*)(src + g * 8);
                *(bf16x8*)(Vs + r * 64 + (g ^ (r & 7)) * 8) = val;
            }
        }
        __syncthreads();

        // ---- QK^T: sc[nf] = 16x16 tile, rows q (lhi*4+r), cols kv (nf*16+l16)
        bf16x8 qa[4];
#pragma unroll
        for (int kh = 0; kh < 4; ++kh) qa[kh] = *(const bf16x8*)(Qs + qoff[kh]);
        f32x4 sc[4] = {};
#pragma unroll
        for (int nf = 0; nf < 4; ++nf) {
            int krow = nf * 16 + l16;
#pragma unroll
            for (int kh = 0; kh < 4; ++kh) {
                bf16x8 kf = *(const bf16x8*)(Ks + krow * 128 + (((kh * 4 + lhi) ^ (krow & 7))) * 8);
                sc[nf] = __builtin_amdgcn_mfma_f32_16x16x32_bf16(qa[kh], kf, sc[nf], 0, 0, 0);
            }
        }

        // ---- online softmax (rows = lhi*4+r, reduce across l16 group + nf)
        float corr[4];
#pragma unroll
        for (int r = 0; r < 4; ++r) {
            float tmax = fmaxf(fmaxf(sc[0][r], sc[1][r]), fmaxf(sc[2][r], sc[3][r]));
            tmax = fmaxf(tmax, __shfl_xor(tmax, 1, 64));
            tmax = fmaxf(tmax, __shfl_xor(tmax, 2, 64));
            tmax = fmaxf(tmax, __shfl_xor(tmax, 4, 64));
            tmax = fmaxf(tmax, __shfl_xor(tmax, 8, 64));
            float mn = fmaxf(mreg[r], tmax);
            corr[r] = __expf(mreg[r] - mn);
            mreg[r] = mn;
            float psum = 0.f;
#pragma unroll
            for (int nf = 0; nf < 4; ++nf) {
                float p = __expf(sc[nf][r] - mn);
                sc[nf][r] = p;
                psum += p;
            }
            psum += __shfl_xor(psum, 1, 64);
            psum += __shfl_xor(psum, 2, 64);
            psum += __shfl_xor(psum, 4, 64);
            psum += __shfl_xor(psum, 8, 64);
            lreg[r] = lreg[r] * corr[r] + psum;
        }
#pragma unroll
        for (int fb = 0; fb < 8; ++fb)
#pragma unroll
            for (int r = 0; r < 4; ++r) oacc[fb][r] *= corr[r];

        // ---- write P to per-wave LDS (bf16), then read as A-frags (same wave, no barrier)
#pragma unroll
        for (int nf = 0; nf < 4; ++nf)
#pragma unroll
            for (int r = 0; r < 4; ++r)
                Ps[wid][(lhi * 4 + r) * 72 + nf * 16 + l16] = f2bf(sc[nf][r]);

        bf16x8 pa[2];
#pragma unroll
        for (int k2 = 0; k2 < 2; ++k2)
            pa[k2] = *(const bf16x8*)(&Ps[wid][l16 * 72 + k2 * 32 + lhi * 8]);

        // ---- PV: oacc[fb] += P[16x64] @ V[64x16(fb)]
#pragma unroll
        for (int fb = 0; fb < 8; ++fb) {
            int vrow = fb * 16 + l16;
#pragma unroll
            for (int k2 = 0; k2 < 2; ++k2) {
                bf16x8 vf = *(const bf16x8*)(Vs + vrow * 64 + (((k2 * 4 + lhi) ^ (vrow & 7))) * 8);
                oacc[fb] = __builtin_amdgcn_mfma_f32_16x16x32_bf16(pa[k2], vf, oacc[fb], 0, 0, 0);
            }
        }
    }

    // ---- epilogue
    float linv[4];
#pragma unroll
    for (int r = 0; r < 4; ++r) linv[r] = 1.f / lreg[r];
#pragma unroll
    for (int fb = 0; fb < 8; ++fb) {
#pragma unroll
        for (int r = 0; r < 4; ++r) {
            int row = qt * 64 + wid * 16 + lhi * 4 + r;
            o[(size_t)row * D + h * HD + fb * 16 + l16] = oacc[fb][r] * linv[r];
        }
    }
}

// ---------------------------------------------------------------- MoE gate + expert lists
__global__ void gate_kernel(const float* __restrict__ x, const float* __restrict__ gw,
                            float* __restrict__ wbuf, int* __restrict__ cnt, int* __restrict__ elist)
{
    int t = blockIdx.x;
    int g = threadIdx.x >> 4, j = threadIdx.x & 15;
    const float* xr = x + (size_t)t * D;
    const float* gr = gw + (size_t)g * D;
    float p = 0.f;
    for (int m = 0; m < D / 16; ++m) p += xr[j + 16 * m] * gr[j + 16 * m];
    for (int off = 8; off; off >>= 1) p += __shfl_down(p, off, 64);
    __shared__ float lg[NE];
    if (j == 0) lg[g] = p;
    __syncthreads();
    if (threadIdx.x == 0) {
        float l0 = -1e30f; int i0 = 0;
        for (int e = 0; e < NE; ++e) if (lg[e] > l0) { l0 = lg[e]; i0 = e; }
        float l1 = -1e30f; int i1 = 0;
        for (int e = 0; e < NE; ++e) if (e != i0 && lg[e] > l1) { l1 = lg[e]; i1 = e; }
        float rr = expf(l1 - l0);
        wbuf[t * 2 + 0] = 1.f / (1.f + rr);
        wbuf[t * 2 + 1] = rr / (1.f + rr);
        int s0 = atomicAdd(&cnt[i0], 1); elist[i0 * S + s0] = t * 2;
        int s1 = atomicAdd(&cnt[i1], 1); elist[i1 * S + s1] = t * 2 + 1;
    }
}

// ---------------------------------------------------------------- silu(g)*u
__global__ void silu_mul_kernel(const float* __restrict__ g, const float* __restrict__ u,
                                float* __restrict__ a)
{
    int i = blockIdx.x * 256 + threadIdx.x;
    float gg = g[i];
    a[i] = gg / (1.f + __expf(-gg)) * u[i];
}

// ---------------------------------------------------------------- final combine
__global__ void combine_kernel(const float* __restrict__ hattn, const float* __restrict__ wbuf,
                               const float* __restrict__ ybuf, float* __restrict__ out)
{
    int i = blockIdx.x * 256 + threadIdx.x;
    int t = i >> 11;
    int d = i & (D - 1);
    out[i] = hattn[i]
           + wbuf[t * 2 + 0] * ybuf[(size_t)(t * 2 + 0) * D + d]
           + wbuf[t * 2 + 1] * ybuf[(size_t)(t * 2 + 1) * D + d];
}

// ---------------------------------------------------------------- launch
extern "C" void kernel_launch(void* const* d_in, const int* in_sizes, int n_in,
                              void* d_out, int out_size, void* d_ws, size_t ws_size,
                              hipStream_t stream)
{
    const float* hidden = (const float*)d_in[0];
    const float* ln1 = (const float*)d_in[1];
    const float* ln2 = (const float*)d_in[2];
    const float* qn  = (const float*)d_in[3];
    const float* kn  = (const float*)d_in[4];
    const float* Wq  = (const float*)d_in[5];
    const float* Wk  = (const float*)d_in[6];
    const float* Wv  = (const float*)d_in[7];
    const float* Wo  = (const float*)d_in[8];
    const float* gw  = (const float*)d_in[9];
    const float* Wg  = (const float*)d_in[10];
    const float* Wu  = (const float*)d_in[11];
    const float* Wd  = (const float*)d_in[12];
    const int*   pos = (const int*)d_in[13];

    float* ws    = (float*)d_ws;
    float* h1    = ws;                    // 2M floats; overlays: qbh/kbh/vbt (bf16), later gbuf
    float* qb    = h1 + 2097152;          // 2M; later ubuf
    float* kb    = qb + 2097152;          // 0.5M
    float* vb    = kb + 524288;           // 0.5M
    float* attn  = vb + 524288;           // 2M; later abuf
    float* hattn = attn + 2097152;        // 2M
    float* h2    = hattn + 2097152;       // 2M
    float* ybuf  = h2 + 2097152;          // 4M
    float* wbuf  = ybuf + 4194304;        // 2048
    int*   cnt   = (int*)(wbuf + 2048);   // 16
    int*   elist = cnt + 16;              // 16*1024

    unsigned short* qbh = (unsigned short*)h1;                 // 2M bf16 (1M floats)
    unsigned short* kbh = (unsigned short*)(h1 + 1048576);     // 512K bf16
    unsigned short* vbt = (unsigned short*)(h1 + 1310720);     // 512K bf16
    float* gbuf  = h1;
    float* ubuf  = qb;
    float* abuf  = attn;
    float* out   = (float*)d_out;

    hipMemsetAsync(cnt, 0, NE * sizeof(int), stream);

    rmsnorm_kernel<<<S, 256, 0, stream>>>(hidden, ln1, h1);
    mfma_gemm_kernel<<<dim3(32, 16, 1), 256, 0, stream>>>(h1, D, 0, Wq, D, qb, 2048, nullptr, nullptr, nullptr, S, 2048, D);
    mfma_gemm_kernel<<<dim3(8, 16, 1), 256, 0, stream>>>(h1, D, 0, Wk, D, kb, 512, nullptr, nullptr, nullptr, S, 512, D);
    mfma_gemm_kernel<<<dim3(8, 16, 1), 256, 0, stream>>>(h1, D, 0, Wv, D, vb, 512, nullptr, nullptr, nullptr, S, 512, D);
    // h1 is dead from here; bf16 q/k/vT overlay it
    qkrope_bf16_kernel<<<dim3(S, NH + NKV), 64, 0, stream>>>(qb, kb, qn, kn, pos, qbh, kbh);
    vtrans_kernel<<<dim3(S / 64, HD / 64, NKV), 256, 0, stream>>>(vb, vbt);
    flash_attn_mfma_kernel<<<dim3(S / 64, NH), 256, 0, stream>>>(qbh, kbh, vbt, attn);
    mfma_gemm_kernel<<<dim3(32, 16, 1), 256, 0, stream>>>(attn, D, 0, Wo, D, hattn, D, hidden, nullptr, nullptr, S, 2048, D);
    rmsnorm_kernel<<<S, 256, 0, stream>>>(hattn, ln2, h2);
    gate_kernel<<<S, 256, 0, stream>>>(h2, gw, wbuf, cnt, elist);
    mfma_gemm_kernel<<<dim3(NI / 64, 16, NE), 256, 0, stream>>>(h2, D, 1, Wg, D, gbuf, NI, nullptr, cnt, elist, 0, NI, D);
    mfma_gemm_kernel<<<dim3(NI / 64, 16, NE), 256, 0, stream>>>(h2, D, 1, Wu, D, ubuf, NI, nullptr, cnt, elist, 0, NI, D);
    silu_mul_kernel<<<dim3(2 * S * NI / 256), 256, 0, stream>>>(gbuf, ubuf, abuf);
    mfma_gemm_kernel<<<dim3(D / 64, 16, NE), 256, 0, stream>>>(abuf, NI, 0, Wd, NI, ybuf, D, nullptr, cnt, elist, 0, D, NI);
    combine_kernel<<<dim3(S * D / 256), 256, 0, stream>>>(hattn, wbuf, ybuf, out);
}

// Round 4
// 460.414 us; speedup vs baseline: 3.7505x; 1.5258x over previous
//
#include <hip/hip_runtime.h>
#include <hip/hip_bf16.h>
#include <math.h>

#define D 2048
#define NH 16
#define NKV 4
#define HD 128
#define NE 16
#define NI 768
#define S 1024
#define EPS 1e-6f

typedef __attribute__((ext_vector_type(8))) short bf16x8;
typedef __attribute__((ext_vector_type(4))) float f32x4;

__device__ __forceinline__ float wave_reduce_sum64(float v) {
    for (int off = 32; off; off >>= 1) v += __shfl_xor(v, off, 64);
    return v;
}

__device__ __forceinline__ unsigned short f2bf(float f) {
    unsigned int x = __float_as_uint(f);
    x += 0x7FFFu + ((x >> 16) & 1u);   // round-to-nearest-even
    return (unsigned short)(x >> 16);
}

__device__ __forceinline__ bf16x8 pack8(const float4 a, const float4 b) {
    bf16x8 r;
    r[0] = (short)f2bf(a.x); r[1] = (short)f2bf(a.y);
    r[2] = (short)f2bf(a.z); r[3] = (short)f2bf(a.w);
    r[4] = (short)f2bf(b.x); r[5] = (short)f2bf(b.y);
    r[6] = (short)f2bf(b.z); r[7] = (short)f2bf(b.w);
    return r;
}

// ---------------------------------------------------------------- RMSNorm over D
__global__ void rmsnorm_kernel(const float* __restrict__ x, const float* __restrict__ w,
                               float* __restrict__ y) {
    int t = blockIdx.x;
    const float* xr = x + (size_t)t * D;
    float* yr = y + (size_t)t * D;
    float v[8];
    float ss = 0.f;
#pragma unroll
    for (int m = 0; m < 8; ++m) {
        v[m] = xr[threadIdx.x + 256 * m];
        ss += v[m] * v[m];
    }
    ss = wave_reduce_sum64(ss);
    __shared__ float wsum[4];
    if ((threadIdx.x & 63) == 0) wsum[threadIdx.x >> 6] = ss;
    __syncthreads();
    float tot = wsum[0] + wsum[1] + wsum[2] + wsum[3];
    float r = rsqrtf(tot / (float)D + EPS);
#pragma unroll
    for (int m = 0; m < 8; ++m) {
        int d = threadIdx.x + 256 * m;
        yr[d] = v[m] * r * w[d];
    }
}

// ---------------------------------------------------------------- dense MFMA GEMM (prefetched)
// C = A@W^T (+R); optional duplicate write to C2. BM=BN=BK=64.
__global__ __launch_bounds__(256) void mfma_gemm_kernel(
    const float* __restrict__ A, int lda,
    const float* __restrict__ W, int ldw,
    float* __restrict__ C, int ldc,
    const float* __restrict__ R, float* __restrict__ C2,
    int M, int N, int K)
{
    int m0 = blockIdx.y * 64;
    int n0 = blockIdx.x * 64;

    __shared__ unsigned short As[64 * 64];
    __shared__ unsigned short Bs[64 * 64];

    int tid = threadIdx.x;
    int srow = tid >> 2;
    int scol = (tid & 3) * 16;

    const float* ap = A + (size_t)(m0 + srow) * lda + scol;
    const float* wp = W + (size_t)(n0 + srow) * ldw + scol;

    int wlo[2];
#pragma unroll
    for (int u = 0; u < 2; ++u) {
        int g = (tid & 3) * 2 + u;
        wlo[u] = srow * 64 + (g ^ (srow & 7)) * 8;
    }

    int wid = tid >> 6, lane = tid & 63;
    int wm = wid >> 1, wn = wid & 1;
    int l16 = lane & 15, lhi = lane >> 4;

    int ra[2][2], rb[2][2];
#pragma unroll
    for (int f = 0; f < 2; ++f) {
        int rowa = wm * 32 + f * 16 + l16;
        int rowb = wn * 32 + f * 16 + l16;
#pragma unroll
        for (int kh = 0; kh < 2; ++kh) {
            ra[f][kh] = rowa * 64 + (((kh * 4 + lhi) ^ (rowa & 7))) * 8;
            rb[f][kh] = rowb * 64 + (((kh * 4 + lhi) ^ (rowb & 7))) * 8;
        }
    }

    f32x4 acc[2][2] = {};
    float4 av[4], wv[4];

    auto ldt = [&](int k0) {
#pragma unroll
        for (int u = 0; u < 4; ++u) {
            av[u] = *(const float4*)(ap + k0 + u * 4);
            wv[u] = *(const float4*)(wp + k0 + u * 4);
        }
    };

    ldt(0);
    for (int k0 = 0; k0 < K; k0 += 64) {
        bf16x8 pa0 = pack8(av[0], av[1]);
        bf16x8 pa1 = pack8(av[2], av[3]);
        bf16x8 pw0 = pack8(wv[0], wv[1]);
        bf16x8 pw1 = pack8(wv[2], wv[3]);
        __syncthreads();
        *(bf16x8*)(As + wlo[0]) = pa0;
        *(bf16x8*)(As + wlo[1]) = pa1;
        *(bf16x8*)(Bs + wlo[0]) = pw0;
        *(bf16x8*)(Bs + wlo[1]) = pw1;
        __syncthreads();
        if (k0 + 64 < K) ldt(k0 + 64);
#pragma unroll
        for (int kh = 0; kh < 2; ++kh) {
            bf16x8 af0 = *(const bf16x8*)(As + ra[0][kh]);
            bf16x8 af1 = *(const bf16x8*)(As + ra[1][kh]);
            bf16x8 bf0 = *(const bf16x8*)(Bs + rb[0][kh]);
            bf16x8 bf1 = *(const bf16x8*)(Bs + rb[1][kh]);
            acc[0][0] = __builtin_amdgcn_mfma_f32_16x16x32_bf16(af0, bf0, acc[0][0], 0, 0, 0);
            acc[0][1] = __builtin_amdgcn_mfma_f32_16x16x32_bf16(af0, bf1, acc[0][1], 0, 0, 0);
            acc[1][0] = __builtin_amdgcn_mfma_f32_16x16x32_bf16(af1, bf0, acc[1][0], 0, 0, 0);
            acc[1][1] = __builtin_amdgcn_mfma_f32_16x16x32_bf16(af1, bf1, acc[1][1], 0, 0, 0);
        }
    }

#pragma unroll
    for (int mi = 0; mi < 2; ++mi) {
#pragma unroll
        for (int r = 0; r < 4; ++r) {
            int grow = m0 + wm * 32 + mi * 16 + lhi * 4 + r;
#pragma unroll
            for (int ni = 0; ni < 2; ++ni) {
                int gcol = n0 + wn * 32 + ni * 16 + l16;
                float v = acc[mi][ni][r];
                if (R) v += R[(size_t)grow * ldc + gcol];
                C[(size_t)grow * ldc + gcol] = v;
                if (C2) C2[(size_t)grow * ldc + gcol] = v;
            }
        }
    }
}

// ---------------------------------------------------------------- fused MoE up+gate (gathered)
// BM=128, BN=64, BK=64, prefetched. abuf[slot][i] = silu(g)*u in bf16.
__global__ __launch_bounds__(256) void moe_mlp_kernel(
    const float* __restrict__ x, const float* __restrict__ Wg, const float* __restrict__ Wu,
    const int* __restrict__ cnt, const int* __restrict__ elist,
    unsigned short* __restrict__ abuf)
{
    int e = blockIdx.z;
    int me = cnt[e];
    int m0 = blockIdx.y * 128;
    if (m0 >= me) return;
    int n0 = blockIdx.x * 64;

    __shared__ unsigned short As[128 * 64];
    __shared__ unsigned short Gs[64 * 64];
    __shared__ unsigned short Us[64 * 64];
    __shared__ int ridx[128];

    int tid = threadIdx.x;
    const int* idx = elist + e * S;
    if (tid < 128) ridx[tid] = (m0 + tid < me) ? idx[m0 + tid] : -1;
    __syncthreads();

    int arow_i = tid >> 1;
    int ahalf = (tid & 1) * 32;
    int rva = ridx[arow_i];
    const float* arow = (rva >= 0) ? (x + (size_t)(rva >> 1) * D + ahalf) : nullptr;

    int brow = tid >> 2;
    int bcol = (tid & 3) * 16;
    const float* gp = Wg + ((size_t)e * NI + n0 + brow) * D + bcol;
    const float* up = Wu + ((size_t)e * NI + n0 + brow) * D + bcol;

    int wa[4], wb[2];
#pragma unroll
    for (int u = 0; u < 4; ++u) {
        int g = (tid & 1) * 4 + u;
        wa[u] = arow_i * 64 + (g ^ (arow_i & 7)) * 8;
    }
#pragma unroll
    for (int u = 0; u < 2; ++u) {
        int g = (tid & 3) * 2 + u;
        wb[u] = brow * 64 + (g ^ (brow & 7)) * 8;
    }

    int wid = tid >> 6, lane = tid & 63;
    int l16 = lane & 15, lhi = lane >> 4;

    int raoff[2][2], rboff[4][2];
#pragma unroll
    for (int mf = 0; mf < 2; ++mf) {
        int rowa = wid * 32 + mf * 16 + l16;
#pragma unroll
        for (int kh = 0; kh < 2; ++kh)
            raoff[mf][kh] = rowa * 64 + (((kh * 4 + lhi) ^ (rowa & 7))) * 8;
    }
#pragma unroll
    for (int nf = 0; nf < 4; ++nf) {
        int rowb = nf * 16 + l16;
#pragma unroll
        for (int kh = 0; kh < 2; ++kh)
            rboff[nf][kh] = rowb * 64 + (((kh * 4 + lhi) ^ (rowb & 7))) * 8;
    }

    f32x4 accg[2][4] = {}, accu[2][4] = {};
    float4 av[8], gv[4], uv[4];

    auto ldt = [&](int k0) {
        if (arow) {
#pragma unroll
            for (int u = 0; u < 8; ++u) av[u] = *(const float4*)(arow + k0 + u * 4);
        } else {
#pragma unroll
            for (int u = 0; u < 8; ++u) av[u] = make_float4(0.f, 0.f, 0.f, 0.f);
        }
#pragma unroll
        for (int u = 0; u < 4; ++u) {
            gv[u] = *(const float4*)(gp + k0 + u * 4);
            uv[u] = *(const float4*)(up + k0 + u * 4);
        }
    };

    ldt(0);
    for (int k0 = 0; k0 < D; k0 += 64) {
        bf16x8 pa[4], pg[2], pu[2];
#pragma unroll
        for (int u = 0; u < 4; ++u) pa[u] = pack8(av[2 * u], av[2 * u + 1]);
#pragma unroll
        for (int u = 0; u < 2; ++u) {
            pg[u] = pack8(gv[2 * u], gv[2 * u + 1]);
            pu[u] = pack8(uv[2 * u], uv[2 * u + 1]);
        }
        __syncthreads();
#pragma unroll
        for (int u = 0; u < 4; ++u) *(bf16x8*)(As + wa[u]) = pa[u];
#pragma unroll
        for (int u = 0; u < 2; ++u) {
            *(bf16x8*)(Gs + wb[u]) = pg[u];
            *(bf16x8*)(Us + wb[u]) = pu[u];
        }
        __syncthreads();
        if (k0 + 64 < D) ldt(k0 + 64);
#pragma unroll
        for (int kh = 0; kh < 2; ++kh) {
            bf16x8 a0 = *(const bf16x8*)(As + raoff[0][kh]);
            bf16x8 a1 = *(const bf16x8*)(As + raoff[1][kh]);
#pragma unroll
            for (int nf = 0; nf < 4; ++nf) {
                bf16x8 bg = *(const bf16x8*)(Gs + rboff[nf][kh]);
                bf16x8 bu = *(const bf16x8*)(Us + rboff[nf][kh]);
                accg[0][nf] = __builtin_amdgcn_mfma_f32_16x16x32_bf16(a0, bg, accg[0][nf], 0, 0, 0);
                accg[1][nf] = __builtin_amdgcn_mfma_f32_16x16x32_bf16(a1, bg, accg[1][nf], 0, 0, 0);
                accu[0][nf] = __builtin_amdgcn_mfma_f32_16x16x32_bf16(a0, bu, accu[0][nf], 0, 0, 0);
                accu[1][nf] = __builtin_amdgcn_mfma_f32_16x16x32_bf16(a1, bu, accu[1][nf], 0, 0, 0);
            }
        }
    }

#pragma unroll
    for (int mf = 0; mf < 2; ++mf) {
#pragma unroll
        for (int r = 0; r < 4; ++r) {
            int lrow = wid * 32 + mf * 16 + lhi * 4 + r;
            int rv = ridx[lrow];
            if (rv < 0) continue;
            unsigned short* orow = abuf + (size_t)rv * NI + n0;
#pragma unroll
            for (int nf = 0; nf < 4; ++nf) {
                float g = accg[mf][nf][r];
                float u = accu[mf][nf][r];
                float a = g / (1.f + __expf(-g)) * u;
                orow[nf * 16 + l16] = f2bf(a);
            }
        }
    }
}

// ---------------------------------------------------------------- MoE down proj + combine
// A = abuf bf16 [slot][NI], W = Wd fp32. out += wbuf[slot] * (A@Wd^T) via atomics.
__global__ __launch_bounds__(256) void moe_down_kernel(
    const unsigned short* __restrict__ abuf, const float* __restrict__ Wd,
    const int* __restrict__ cnt, const int* __restrict__ elist,
    const float* __restrict__ wbuf, float* __restrict__ out)
{
    int e = blockIdx.z;
    int me = cnt[e];
    int m0 = blockIdx.y * 128;
    if (m0 >= me) return;
    int n0 = blockIdx.x * 64;

    __shared__ unsigned short As[128 * 64];
    __shared__ unsigned short Bs[64 * 64];
    __shared__ int ridx[128];

    int tid = threadIdx.x;
    const int* idx = elist + e * S;
    if (tid < 128) ridx[tid] = (m0 + tid < me) ? idx[m0 + tid] : -1;
    __syncthreads();

    int arow_i = tid >> 1;
    int ahalf = (tid & 1) * 32;
    int rva = ridx[arow_i];
    const unsigned short* arow = (rva >= 0) ? (abuf + (size_t)rva * NI + ahalf) : nullptr;

    int brow = tid >> 2;
    int bcol = (tid & 3) * 16;
    const float* wp = Wd + ((size_t)e * D + n0 + brow) * NI + bcol;

    int wa[4], wb[2];
#pragma unroll
    for (int u = 0; u < 4; ++u) {
        int g = (tid & 1) * 4 + u;
        wa[u] = arow_i * 64 + (g ^ (arow_i & 7)) * 8;
    }
#pragma unroll
    for (int u = 0; u < 2; ++u) {
        int g = (tid & 3) * 2 + u;
        wb[u] = brow * 64 + (g ^ (brow & 7)) * 8;
    }

    int wid = tid >> 6, lane = tid & 63;
    int l16 = lane & 15, lhi = lane >> 4;

    int raoff[2][2], rboff[4][2];
#pragma unroll
    for (int mf = 0; mf < 2; ++mf) {
        int rowa = wid * 32 + mf * 16 + l16;
#pragma unroll
        for (int kh = 0; kh < 2; ++kh)
            raoff[mf][kh] = rowa * 64 + (((kh * 4 + lhi) ^ (rowa & 7))) * 8;
    }
#pragma unroll
    for (int nf = 0; nf < 4; ++nf) {
        int rowb = nf * 16 + l16;
#pragma unroll
        for (int kh = 0; kh < 2; ++kh)
            rboff[nf][kh] = rowb * 64 + (((kh * 4 + lhi) ^ (rowb & 7))) * 8;
    }

    f32x4 acc[2][4] = {};
    bf16x8 av[4];
    float4 wv[4];

    auto ldt = [&](int k0) {
        if (arow) {
#pragma unroll
            for (int u = 0; u < 4; ++u) av[u] = *(const bf16x8*)(arow + k0 + u * 8);
        } else {
            bf16x8 z = {};
#pragma unroll
            for (int u = 0; u < 4; ++u) av[u] = z;
        }
#pragma unroll
        for (int u = 0; u < 4; ++u) wv[u] = *(const float4*)(wp + k0 + u * 4);
    };

    ldt(0);
    for (int k0 = 0; k0 < NI; k0 += 64) {
        bf16x8 pw0 = pack8(wv[0], wv[1]);
        bf16x8 pw1 = pack8(wv[2], wv[3]);
        bf16x8 a0s = av[0], a1s = av[1], a2s = av[2], a3s = av[3];
        __syncthreads();
        *(bf16x8*)(As + wa[0]) = a0s;
        *(bf16x8*)(As + wa[1]) = a1s;
        *(bf16x8*)(As + wa[2]) = a2s;
        *(bf16x8*)(As + wa[3]) = a3s;
        *(bf16x8*)(Bs + wb[0]) = pw0;
        *(bf16x8*)(Bs + wb[1]) = pw1;
        __syncthreads();
        if (k0 + 64 < NI) ldt(k0 + 64);
#pragma unroll
        for (int kh = 0; kh < 2; ++kh) {
            bf16x8 a0 = *(const bf16x8*)(As + raoff[0][kh]);
            bf16x8 a1 = *(const bf16x8*)(As + raoff[1][kh]);
#pragma unroll
            for (int nf = 0; nf < 4; ++nf) {
                bf16x8 b = *(const bf16x8*)(Bs + rboff[nf][kh]);
                acc[0][nf] = __builtin_amdgcn_mfma_f32_16x16x32_bf16(a0, b, acc[0][nf], 0, 0, 0);
                acc[1][nf] = __builtin_amdgcn_mfma_f32_16x16x32_bf16(a1, b, acc[1][nf], 0, 0, 0);
            }
        }
    }

#pragma unroll
    for (int mf = 0; mf < 2; ++mf) {
#pragma unroll
        for (int r = 0; r < 4; ++r) {
            int lrow = wid * 32 + mf * 16 + lhi * 4 + r;
            int rv = ridx[lrow];
            if (rv < 0) continue;
            float w = wbuf[rv];
            float* orow = out + (size_t)(rv >> 1) * D + n0;
#pragma unroll
            for (int nf = 0; nf < 4; ++nf)
                atomicAdd(orow + nf * 16 + l16, w * acc[mf][nf][r]);
        }
    }
}

// ---------------------------------------------------------------- q/k RMSNorm + RoPE -> bf16
__global__ void qkrope_bf16_kernel(const float* __restrict__ q, const float* __restrict__ k,
                                   const float* __restrict__ qn_w, const float* __restrict__ kn_w,
                                   const int* __restrict__ pos_ids,
                                   unsigned short* __restrict__ qbh, unsigned short* __restrict__ kbh)
{
    int t = blockIdx.x;
    int h = blockIdx.y;
    int d = threadIdx.x;
    const float* base;
    const float* w;
    unsigned short* ob;
    float scale;
    if (h < NH) {
        base = q + (size_t)t * D + h * HD; w = qn_w;
        ob = qbh + (size_t)t * D + h * HD; scale = 0.08838834764831845f;
    } else {
        base = k + (size_t)t * (NKV * HD) + (h - NH) * HD; w = kn_w;
        ob = kbh + (size_t)t * (NKV * HD) + (h - NH) * HD; scale = 1.0f;
    }
    float x1 = base[d], x2 = base[d + 64];
    float ss = wave_reduce_sum64(x1 * x1 + x2 * x2);
    float r = rsqrtf(ss / (float)HD + EPS);
    float n1 = x1 * r * w[d];
    float n2 = x2 * r * w[d + 64];
    float pos = (float)pos_ids[t];
    float freq = powf(1000000.0f, -(float)d * (1.0f / 64.0f));
    float ang = pos * freq;
    float c, s;
    sincosf(ang, &s, &c);
    ob[d]      = f2bf((n1 * c - n2 * s) * scale);
    ob[d + 64] = f2bf((n2 * c + n1 * s) * scale);
}

// ---------------------------------------------------------------- V -> bf16 V^T [KV][HD][S]
__global__ void vtrans_kernel(const float* __restrict__ vb, unsigned short* __restrict__ vbt)
{
    __shared__ unsigned short tile[64][65];
    int s0 = blockIdx.x * 64, d0 = blockIdx.y * 64, kvh = blockIdx.z;
    int tid = threadIdx.x;
    {
        int i = tid >> 2;
        int j4 = (tid & 3) * 16;
        const float* src = vb + (size_t)(s0 + i) * (NKV * HD) + kvh * HD + d0 + j4;
#pragma unroll
        for (int u = 0; u < 4; ++u) {
            float4 f = *(const float4*)(src + u * 4);
            tile[i][j4 + u * 4 + 0] = f2bf(f.x);
            tile[i][j4 + u * 4 + 1] = f2bf(f.y);
            tile[i][j4 + u * 4 + 2] = f2bf(f.z);
            tile[i][j4 + u * 4 + 3] = f2bf(f.w);
        }
    }
    __syncthreads();
    {
        int j = tid >> 2;
        int i4 = (tid & 3) * 16;
        bf16x8 o0, o1;
#pragma unroll
        for (int u = 0; u < 8; ++u) {
            o0[u] = (short)tile[i4 + u][j];
            o1[u] = (short)tile[i4 + 8 + u][j];
        }
        unsigned short* dst = vbt + ((size_t)kvh * HD + d0 + j) * S + s0 + i4;
        *(bf16x8*)(dst) = o0;
        *(bf16x8*)(dst + 8) = o1;
    }
}

// ---------------------------------------------------------------- MFMA flash attention
__global__ __launch_bounds__(256) void flash_attn_mfma_kernel(
    const unsigned short* __restrict__ qbh, const unsigned short* __restrict__ kbh,
    const unsigned short* __restrict__ vbt, float* __restrict__ o)
{
    int qt = blockIdx.x;
    int h  = blockIdx.y;
    int kvh = h >> 2;

    __shared__ unsigned short Qs[64 * 128];
    __shared__ unsigned short Ks[64 * 128];
    __shared__ unsigned short Vs[128 * 64];
    __shared__ unsigned short Ps[4][16 * 72];

    int tid = threadIdx.x;
    int wid = tid >> 6, lane = tid & 63;
    int l16 = lane & 15, lhi = lane >> 4;

    {
        int r = tid >> 2;
        int gb = (tid & 3) * 4;
        const unsigned short* src = qbh + (size_t)(qt * 64 + r) * D + h * HD;
#pragma unroll
        for (int u = 0; u < 4; ++u) {
            int g = gb + u;
            bf16x8 val = *(const bf16x8*)(src + g * 8);
            *(bf16x8*)(Qs + r * 128 + (g ^ (r & 7)) * 8) = val;
        }
    }

    int qrow = wid * 16 + l16;
    int qoff[4];
#pragma unroll
    for (int kh = 0; kh < 4; ++kh)
        qoff[kh] = qrow * 128 + (((kh * 4 + lhi) ^ (qrow & 7))) * 8;

    float mreg[4], lreg[4];
#pragma unroll
    for (int r = 0; r < 4; ++r) { mreg[r] = -3.0e38f; lreg[r] = 0.f; }
    f32x4 oacc[8] = {};

    for (int kt = 0; kt < S / 64; ++kt) {
        __syncthreads();
        {
            int r = tid >> 2;
            int gb = (tid & 3) * 4;
            const unsigned short* src = kbh + (size_t)(kt * 64 + r) * (NKV * HD) + kvh * HD;
#pragma unroll
            for (int u = 0; u < 4; ++u) {
                int g = gb + u;
                bf16x8 val = *(const bf16x8*)(src + g * 8);
                *(bf16x8*)(Ks + r * 128 + (g ^ (r & 7)) * 8) = val;
            }
        }
        {
            int r = tid >> 1;
            int gb = (tid & 1) * 4;
            const unsigned short* src = vbt + ((size_t)kvh * HD + r) * S + kt * 64;
#pragma unroll
            for (int u = 0; u < 4; ++u) {
                int g = gb + u;
                bf16x8 val = *(const bf16x8*)(src + g * 8);
                *(bf16x8*)(Vs + r * 64 + (g ^ (r & 7)) * 8) = val;
            }
        }
        __syncthreads();

        bf16x8 qa[4];
#pragma unroll
        for (int kh = 0; kh < 4; ++kh) qa[kh] = *(const bf16x8*)(Qs + qoff[kh]);
        f32x4 sc[4] = {};
#pragma unroll
        for (int nf = 0; nf < 4; ++nf) {
            int krow = nf * 16 + l16;
#pragma unroll
            for (int kh = 0; kh < 4; ++kh) {
                bf16x8 kf = *(const bf16x8*)(Ks + krow * 128 + (((kh * 4 + lhi) ^ (krow & 7))) * 8);
                sc[nf] = __builtin_amdgcn_mfma_f32_16x16x32_bf16(qa[kh], kf, sc[nf], 0, 0, 0);
            }
        }

        float corr[4];
#pragma unroll
        for (int r = 0; r < 4; ++r) {
            float tmax = fmaxf(fmaxf(sc[0][r], sc[1][r]), fmaxf(sc[2][r], sc[3][r]));
            tmax = fmaxf(tmax, __shfl_xor(tmax, 1, 64));
            tmax = fmaxf(tmax, __shfl_xor(tmax, 2, 64));
            tmax = fmaxf(tmax, __shfl_xor(tmax, 4, 64));
            tmax = fmaxf(tmax, __shfl_xor(tmax, 8, 64));
            float mn = fmaxf(mreg[r], tmax);
            corr[r] = __expf(mreg[r] - mn);
            mreg[r] = mn;
            float psum = 0.f;
#pragma unroll
            for (int nf = 0; nf < 4; ++nf) {
                float p = __expf(sc[nf][r] - mn);
                sc[nf][r] = p;
                psum += p;
            }
            psum += __shfl_xor(psum, 1, 64);
            psum += __shfl_xor(psum, 2, 64);
            psum += __shfl_xor(psum, 4, 64);
            psum += __shfl_xor(psum, 8, 64);
            lreg[r] = lreg[r] * corr[r] + psum;
        }
#pragma unroll
        for (int fb = 0; fb < 8; ++fb)
#pragma unroll
            for (int r = 0; r < 4; ++r) oacc[fb][r] *= corr[r];

#pragma unroll
        for (int nf = 0; nf < 4; ++nf)
#pragma unroll
            for (int r = 0; r < 4; ++r)
                Ps[wid][(lhi * 4 + r) * 72 + nf * 16 + l16] = f2bf(sc[nf][r]);

        bf16x8 pa[2];
#pragma unroll
        for (int k2 = 0; k2 < 2; ++k2)
            pa[k2] = *(const bf16x8*)(&Ps[wid][l16 * 72 + k2 * 32 + lhi * 8]);

#pragma unroll
        for (int fb = 0; fb < 8; ++fb) {
            int vrow = fb * 16 + l16;
#pragma unroll
            for (int k2 = 0; k2 < 2; ++k2) {
                bf16x8 vf = *(const bf16x8*)(Vs + vrow * 64 + (((k2 * 4 + lhi) ^ (vrow & 7))) * 8);
                oacc[fb] = __builtin_amdgcn_mfma_f32_16x16x32_bf16(pa[k2], vf, oacc[fb], 0, 0, 0);
            }
        }
    }

    float linv[4];
#pragma unroll
    for (int r = 0; r < 4; ++r) linv[r] = 1.f / lreg[r];
#pragma unroll
    for (int fb = 0; fb < 8; ++fb) {
#pragma unroll
        for (int r = 0; r < 4; ++r) {
            int row = qt * 64 + wid * 16 + lhi * 4 + r;
            o[(size_t)row * D + h * HD + fb * 16 + l16] = oacc[fb][r] * linv[r];
        }
    }
}

// ---------------------------------------------------------------- MoE gate + expert lists
__global__ void gate_kernel(const float* __restrict__ x, const float* __restrict__ gw,
                            float* __restrict__ wbuf, int* __restrict__ cnt, int* __restrict__ elist)
{
    int t = blockIdx.x;
    int g = threadIdx.x >> 4, j = threadIdx.x & 15;
    const float* xr = x + (size_t)t * D;
    const float* gr = gw + (size_t)g * D;
    float p = 0.f;
    for (int m = 0; m < D / 16; ++m) p += xr[j + 16 * m] * gr[j + 16 * m];
    for (int off = 8; off; off >>= 1) p += __shfl_down(p, off, 64);
    __shared__ float lg[NE];
    if (j == 0) lg[g] = p;
    __syncthreads();
    if (threadIdx.x == 0) {
        float l0 = -1e30f; int i0 = 0;
        for (int e = 0; e < NE; ++e) if (lg[e] > l0) { l0 = lg[e]; i0 = e; }
        float l1 = -1e30f; int i1 = 0;
        for (int e = 0; e < NE; ++e) if (e != i0 && lg[e] > l1) { l1 = lg[e]; i1 = e; }
        float rr = expf(l1 - l0);
        wbuf[t * 2 + 0] = 1.f / (1.f + rr);
        wbuf[t * 2 + 1] = rr / (1.f + rr);
        int s0 = atomicAdd(&cnt[i0], 1); elist[i0 * S + s0] = t * 2;
        int s1 = atomicAdd(&cnt[i1], 1); elist[i1 * S + s1] = t * 2 + 1;
    }
}

// ---------------------------------------------------------------- launch
extern "C" void kernel_launch(void* const* d_in, const int* in_sizes, int n_in,
                              void* d_out, int out_size, void* d_ws, size_t ws_size,
                              hipStream_t stream)
{
    const float* hidden = (const float*)d_in[0];
    const float* ln1 = (const float*)d_in[1];
    const float* ln2 = (const float*)d_in[2];
    const float* qn  = (const float*)d_in[3];
    const float* kn  = (const float*)d_in[4];
    const float* Wq  = (const float*)d_in[5];
    const float* Wk  = (const float*)d_in[6];
    const float* Wv  = (const float*)d_in[7];
    const float* Wo  = (const float*)d_in[8];
    const float* gw  = (const float*)d_in[9];
    const float* Wg  = (const float*)d_in[10];
    const float* Wu  = (const float*)d_in[11];
    const float* Wd  = (const float*)d_in[12];
    const int*   pos = (const int*)d_in[13];

    float* ws    = (float*)d_ws;
    float* h1    = ws;                    // 2M floats; overlays qbh/kbh/vbt bf16
    float* qb    = h1 + 2097152;          // 2M
    float* kb    = qb + 2097152;          // 0.5M
    float* vb    = kb + 524288;           // 0.5M
    float* attn  = vb + 524288;           // 2M; overlays abuf bf16 (0.75M floats)
    float* hattn = attn + 2097152;        // 2M
    float* h2    = hattn + 2097152;       // 2M
    float* wbuf  = h2 + 2097152;          // 2048
    int*   cnt   = (int*)(wbuf + 2048);   // 16
    int*   elist = cnt + 16;              // 16*1024

    unsigned short* qbh = (unsigned short*)h1;                 // S*D bf16
    unsigned short* kbh = (unsigned short*)(h1 + 1048576);     // S*512 bf16
    unsigned short* vbt = (unsigned short*)(h1 + 1310720);     // 512*S bf16
    unsigned short* abuf = (unsigned short*)attn;              // 2048*NI bf16
    float* out   = (float*)d_out;

    hipMemsetAsync(cnt, 0, NE * sizeof(int), stream);

    rmsnorm_kernel<<<S, 256, 0, stream>>>(hidden, ln1, h1);
    mfma_gemm_kernel<<<dim3(32, 16, 1), 256, 0, stream>>>(h1, D, Wq, D, qb, 2048, nullptr, nullptr, S, 2048, D);
    mfma_gemm_kernel<<<dim3(8, 16, 1), 256, 0, stream>>>(h1, D, Wk, D, kb, 512, nullptr, nullptr, S, 512, D);
    mfma_gemm_kernel<<<dim3(8, 16, 1), 256, 0, stream>>>(h1, D, Wv, D, vb, 512, nullptr, nullptr, S, 512, D);
    // h1 dead; bf16 overlays
    qkrope_bf16_kernel<<<dim3(S, NH + NKV), 64, 0, stream>>>(qb, kb, qn, kn, pos, qbh, kbh);
    vtrans_kernel<<<dim3(S / 64, HD / 64, NKV), 256, 0, stream>>>(vb, vbt);
    flash_attn_mfma_kernel<<<dim3(S / 64, NH), 256, 0, stream>>>(qbh, kbh, vbt, attn);
    // O projection + residual; also writes out (= hattn) for MoE atomic accumulation
    mfma_gemm_kernel<<<dim3(32, 16, 1), 256, 0, stream>>>(attn, D, Wo, D, hattn, D, hidden, out, S, 2048, D);
    rmsnorm_kernel<<<S, 256, 0, stream>>>(hattn, ln2, h2);
    gate_kernel<<<S, 256, 0, stream>>>(h2, gw, wbuf, cnt, elist);
    // attn buffer dead; abuf overlays
    moe_mlp_kernel<<<dim3(NI / 64, 8, NE), 256, 0, stream>>>(h2, Wg, Wu, cnt, elist, abuf);
    moe_down_kernel<<<dim3(D / 64, 8, NE), 256, 0, stream>>>(abuf, Wd, cnt, elist, wbuf, out);
}

// Round 5
// 451.660 us; speedup vs baseline: 3.8232x; 1.0194x over previous
//
#include <hip/hip_runtime.h>
#include <hip/hip_bf16.h>
#include <math.h>

#define D 2048
#define NH 16
#define NKV 4
#define HD 128
#define NE 16
#define NI 768
#define S 1024
#define EPS 1e-6f

typedef __attribute__((ext_vector_type(8))) short bf16x8;
typedef __attribute__((ext_vector_type(4))) float f32x4;

__device__ __forceinline__ float wave_reduce_sum64(float v) {
    for (int off = 32; off; off >>= 1) v += __shfl_xor(v, off, 64);
    return v;
}

__device__ __forceinline__ unsigned short f2bf(float f) {
    unsigned int x = __float_as_uint(f);
    x += 0x7FFFu + ((x >> 16) & 1u);   // round-to-nearest-even
    return (unsigned short)(x >> 16);
}

__device__ __forceinline__ bf16x8 pack8(const float4 a, const float4 b) {
    bf16x8 r;
    r[0] = (short)f2bf(a.x); r[1] = (short)f2bf(a.y);
    r[2] = (short)f2bf(a.z); r[3] = (short)f2bf(a.w);
    r[4] = (short)f2bf(b.x); r[5] = (short)f2bf(b.y);
    r[6] = (short)f2bf(b.z); r[7] = (short)f2bf(b.w);
    return r;
}

// ---------------------------------------------------------------- RMSNorm over D
__global__ void rmsnorm_kernel(const float* __restrict__ x, const float* __restrict__ w,
                               float* __restrict__ y) {
    int t = blockIdx.x;
    const float* xr = x + (size_t)t * D;
    float* yr = y + (size_t)t * D;
    float v[8];
    float ss = 0.f;
#pragma unroll
    for (int m = 0; m < 8; ++m) {
        v[m] = xr[threadIdx.x + 256 * m];
        ss += v[m] * v[m];
    }
    ss = wave_reduce_sum64(ss);
    __shared__ float wsum[4];
    if ((threadIdx.x & 63) == 0) wsum[threadIdx.x >> 6] = ss;
    __syncthreads();
    float tot = wsum[0] + wsum[1] + wsum[2] + wsum[3];
    float r = rsqrtf(tot / (float)D + EPS);
#pragma unroll
    for (int m = 0; m < 8; ++m) {
        int d = threadIdx.x + 256 * m;
        yr[d] = v[m] * r * w[d];
    }
}

// ---------------------------------------------------------------- dense MFMA GEMM (prefetched)
// C = A@W^T (+R); optional duplicate write to C2. BM=BN=BK=64.
__global__ __launch_bounds__(256) void mfma_gemm_kernel(
    const float* __restrict__ A, int lda,
    const float* __restrict__ W, int ldw,
    float* __restrict__ C, int ldc,
    const float* __restrict__ R, float* __restrict__ C2,
    int M, int N, int K)
{
    int m0 = blockIdx.y * 64;
    int n0 = blockIdx.x * 64;

    __shared__ unsigned short As[64 * 64];
    __shared__ unsigned short Bs[64 * 64];

    int tid = threadIdx.x;
    int srow = tid >> 2;
    int scol = (tid & 3) * 16;

    const float* ap = A + (size_t)(m0 + srow) * lda + scol;
    const float* wp = W + (size_t)(n0 + srow) * ldw + scol;

    int wlo[2];
#pragma unroll
    for (int u = 0; u < 2; ++u) {
        int g = (tid & 3) * 2 + u;
        wlo[u] = srow * 64 + (g ^ (srow & 7)) * 8;
    }

    int wid = tid >> 6, lane = tid & 63;
    int wm = wid >> 1, wn = wid & 1;
    int l16 = lane & 15, lhi = lane >> 4;

    int ra[2][2], rb[2][2];
#pragma unroll
    for (int f = 0; f < 2; ++f) {
        int rowa = wm * 32 + f * 16 + l16;
        int rowb = wn * 32 + f * 16 + l16;
#pragma unroll
        for (int kh = 0; kh < 2; ++kh) {
            ra[f][kh] = rowa * 64 + (((kh * 4 + lhi) ^ (rowa & 7))) * 8;
            rb[f][kh] = rowb * 64 + (((kh * 4 + lhi) ^ (rowb & 7))) * 8;
        }
    }

    f32x4 acc[2][2] = {};
    float4 av[4], wv[4];

    auto ldt = [&](int k0) {
#pragma unroll
        for (int u = 0; u < 4; ++u) {
            av[u] = *(const float4*)(ap + k0 + u * 4);
            wv[u] = *(const float4*)(wp + k0 + u * 4);
        }
    };

    ldt(0);
    for (int k0 = 0; k0 < K; k0 += 64) {
        bf16x8 pa0 = pack8(av[0], av[1]);
        bf16x8 pa1 = pack8(av[2], av[3]);
        bf16x8 pw0 = pack8(wv[0], wv[1]);
        bf16x8 pw1 = pack8(wv[2], wv[3]);
        __syncthreads();
        *(bf16x8*)(As + wlo[0]) = pa0;
        *(bf16x8*)(As + wlo[1]) = pa1;
        *(bf16x8*)(Bs + wlo[0]) = pw0;
        *(bf16x8*)(Bs + wlo[1]) = pw1;
        __syncthreads();
        if (k0 + 64 < K) ldt(k0 + 64);
#pragma unroll
        for (int kh = 0; kh < 2; ++kh) {
            bf16x8 af0 = *(const bf16x8*)(As + ra[0][kh]);
            bf16x8 af1 = *(const bf16x8*)(As + ra[1][kh]);
            bf16x8 bf0 = *(const bf16x8*)(Bs + rb[0][kh]);
            bf16x8 bf1 = *(const bf16x8*)(Bs + rb[1][kh]);
            acc[0][0] = __builtin_amdgcn_mfma_f32_16x16x32_bf16(af0, bf0, acc[0][0], 0, 0, 0);
            acc[0][1] = __builtin_amdgcn_mfma_f32_16x16x32_bf16(af0, bf1, acc[0][1], 0, 0, 0);
            acc[1][0] = __builtin_amdgcn_mfma_f32_16x16x32_bf16(af1, bf0, acc[1][0], 0, 0, 0);
            acc[1][1] = __builtin_amdgcn_mfma_f32_16x16x32_bf16(af1, bf1, acc[1][1], 0, 0, 0);
        }
    }

#pragma unroll
    for (int mi = 0; mi < 2; ++mi) {
#pragma unroll
        for (int r = 0; r < 4; ++r) {
            int grow = m0 + wm * 32 + mi * 16 + lhi * 4 + r;
#pragma unroll
            for (int ni = 0; ni < 2; ++ni) {
                int gcol = n0 + wn * 32 + ni * 16 + l16;
                float v = acc[mi][ni][r];
                if (R) v += R[(size_t)grow * ldc + gcol];
                C[(size_t)grow * ldc + gcol] = v;
                if (C2) C2[(size_t)grow * ldc + gcol] = v;
            }
        }
    }
}

// ---------------------------------------------------------------- fused QKV GEMM
// N = 3072: cols 0..2047 = Wq, 2048..2559 = Wk, 2560..3071 = Wv. C ldc = 3072.
__global__ __launch_bounds__(256) void qkv_gemm_kernel(
    const float* __restrict__ A,
    const float* __restrict__ Wq, const float* __restrict__ Wk, const float* __restrict__ Wv,
    float* __restrict__ C)
{
    int m0 = blockIdx.y * 64;
    int n0 = blockIdx.x * 64;

    const float* W;
    int wr0;
    if (n0 < 2048)      { W = Wq; wr0 = n0; }
    else if (n0 < 2560) { W = Wk; wr0 = n0 - 2048; }
    else                { W = Wv; wr0 = n0 - 2560; }

    __shared__ unsigned short As[64 * 64];
    __shared__ unsigned short Bs[64 * 64];

    int tid = threadIdx.x;
    int srow = tid >> 2;
    int scol = (tid & 3) * 16;

    const float* ap = A + (size_t)(m0 + srow) * D + scol;
    const float* wp = W + (size_t)(wr0 + srow) * D + scol;

    int wlo[2];
#pragma unroll
    for (int u = 0; u < 2; ++u) {
        int g = (tid & 3) * 2 + u;
        wlo[u] = srow * 64 + (g ^ (srow & 7)) * 8;
    }

    int wid = tid >> 6, lane = tid & 63;
    int wm = wid >> 1, wn = wid & 1;
    int l16 = lane & 15, lhi = lane >> 4;

    int ra[2][2], rb[2][2];
#pragma unroll
    for (int f = 0; f < 2; ++f) {
        int rowa = wm * 32 + f * 16 + l16;
        int rowb = wn * 32 + f * 16 + l16;
#pragma unroll
        for (int kh = 0; kh < 2; ++kh) {
            ra[f][kh] = rowa * 64 + (((kh * 4 + lhi) ^ (rowa & 7))) * 8;
            rb[f][kh] = rowb * 64 + (((kh * 4 + lhi) ^ (rowb & 7))) * 8;
        }
    }

    f32x4 acc[2][2] = {};
    float4 av[4], wv[4];

    auto ldt = [&](int k0) {
#pragma unroll
        for (int u = 0; u < 4; ++u) {
            av[u] = *(const float4*)(ap + k0 + u * 4);
            wv[u] = *(const float4*)(wp + k0 + u * 4);
        }
    };

    ldt(0);
    for (int k0 = 0; k0 < D; k0 += 64) {
        bf16x8 pa0 = pack8(av[0], av[1]);
        bf16x8 pa1 = pack8(av[2], av[3]);
        bf16x8 pw0 = pack8(wv[0], wv[1]);
        bf16x8 pw1 = pack8(wv[2], wv[3]);
        __syncthreads();
        *(bf16x8*)(As + wlo[0]) = pa0;
        *(bf16x8*)(As + wlo[1]) = pa1;
        *(bf16x8*)(Bs + wlo[0]) = pw0;
        *(bf16x8*)(Bs + wlo[1]) = pw1;
        __syncthreads();
        if (k0 + 64 < D) ldt(k0 + 64);
#pragma unroll
        for (int kh = 0; kh < 2; ++kh) {
            bf16x8 af0 = *(const bf16x8*)(As + ra[0][kh]);
            bf16x8 af1 = *(const bf16x8*)(As + ra[1][kh]);
            bf16x8 bf0 = *(const bf16x8*)(Bs + rb[0][kh]);
            bf16x8 bf1 = *(const bf16x8*)(Bs + rb[1][kh]);
            acc[0][0] = __builtin_amdgcn_mfma_f32_16x16x32_bf16(af0, bf0, acc[0][0], 0, 0, 0);
            acc[0][1] = __builtin_amdgcn_mfma_f32_16x16x32_bf16(af0, bf1, acc[0][1], 0, 0, 0);
            acc[1][0] = __builtin_amdgcn_mfma_f32_16x16x32_bf16(af1, bf0, acc[1][0], 0, 0, 0);
            acc[1][1] = __builtin_amdgcn_mfma_f32_16x16x32_bf16(af1, bf1, acc[1][1], 0, 0, 0);
        }
    }

#pragma unroll
    for (int mi = 0; mi < 2; ++mi) {
#pragma unroll
        for (int r = 0; r < 4; ++r) {
            int grow = m0 + wm * 32 + mi * 16 + lhi * 4 + r;
#pragma unroll
            for (int ni = 0; ni < 2; ++ni) {
                int gcol = n0 + wn * 32 + ni * 16 + l16;
                C[(size_t)grow * 3072 + gcol] = acc[mi][ni][r];
            }
        }
    }
}

// ---------------------------------------------------------------- fused MoE up+gate (gathered)
// BM=128, BN=16, BK=64. grid (NI/16, 8, NE). abuf[slot][i] = silu(g)*u bf16.
__global__ __launch_bounds__(256) void moe_mlp_kernel(
    const float* __restrict__ x, const float* __restrict__ Wg, const float* __restrict__ Wu,
    const int* __restrict__ cnt, const int* __restrict__ elist,
    unsigned short* __restrict__ abuf)
{
    int e = blockIdx.z;
    int me = cnt[e];
    int m0 = blockIdx.y * 128;
    if (m0 >= me) return;
    int n0 = blockIdx.x * 16;

    __shared__ unsigned short As[128 * 64];
    __shared__ unsigned short Gs[16 * 64];
    __shared__ unsigned short Us[16 * 64];
    __shared__ int ridx[128];

    int tid = threadIdx.x;
    const int* idx = elist + e * S;
    if (tid < 128) ridx[tid] = (m0 + tid < me) ? idx[m0 + tid] : -1;
    __syncthreads();

    // A staging: thread pair per row, 32-float halves
    int arow_i = tid >> 1;
    int ahalf = (tid & 1) * 32;
    int rva = ridx[arow_i];
    const float* arow = (rva >= 0) ? (x + (size_t)(rva >> 1) * D + ahalf) : nullptr;
    int wa[4];
#pragma unroll
    for (int u = 0; u < 4; ++u) {
        int g = (tid & 1) * 4 + u;
        wa[u] = arow_i * 64 + (g ^ (arow_i & 7)) * 8;
    }

    // B staging: threads 0-127 -> Wg, 128-255 -> Wu; 8 floats/thread
    int tl = tid & 127;
    int bwrow = tl >> 3;
    int bg8 = tl & 7;
    const float* bp = ((tid < 128) ? Wg : Wu) + ((size_t)e * NI + n0 + bwrow) * D + bg8 * 8;
    unsigned short* bs = (tid < 128) ? Gs : Us;
    int wbo = bwrow * 64 + (bg8 ^ (bwrow & 7)) * 8;

    int wid = tid >> 6, lane = tid & 63;
    int l16 = lane & 15, lhi = lane >> 4;

    int raoff[2][2], rboff[2];
#pragma unroll
    for (int mf = 0; mf < 2; ++mf) {
        int rowa = wid * 32 + mf * 16 + l16;
#pragma unroll
        for (int kh = 0; kh < 2; ++kh)
            raoff[mf][kh] = rowa * 64 + (((kh * 4 + lhi) ^ (rowa & 7))) * 8;
    }
#pragma unroll
    for (int kh = 0; kh < 2; ++kh)
        rboff[kh] = l16 * 64 + (((kh * 4 + lhi) ^ (l16 & 7))) * 8;

    f32x4 accg[2] = {}, accu[2] = {};
    float4 av[8], bv[2];

    auto ldt = [&](int k0) {
        if (arow) {
#pragma unroll
            for (int u = 0; u < 8; ++u) av[u] = *(const float4*)(arow + k0 + u * 4);
        } else {
#pragma unroll
            for (int u = 0; u < 8; ++u) av[u] = make_float4(0.f, 0.f, 0.f, 0.f);
        }
        bv[0] = *(const float4*)(bp + k0);
        bv[1] = *(const float4*)(bp + k0 + 4);
    };

    ldt(0);
    for (int k0 = 0; k0 < D; k0 += 64) {
        bf16x8 pa[4];
#pragma unroll
        for (int u = 0; u < 4; ++u) pa[u] = pack8(av[2 * u], av[2 * u + 1]);
        bf16x8 pb = pack8(bv[0], bv[1]);
        __syncthreads();
#pragma unroll
        for (int u = 0; u < 4; ++u) *(bf16x8*)(As + wa[u]) = pa[u];
        *(bf16x8*)(bs + wbo) = pb;
        __syncthreads();
        if (k0 + 64 < D) ldt(k0 + 64);
#pragma unroll
        for (int kh = 0; kh < 2; ++kh) {
            bf16x8 a0 = *(const bf16x8*)(As + raoff[0][kh]);
            bf16x8 a1 = *(const bf16x8*)(As + raoff[1][kh]);
            bf16x8 bgf = *(const bf16x8*)(Gs + rboff[kh]);
            bf16x8 buf = *(const bf16x8*)(Us + rboff[kh]);
            accg[0] = __builtin_amdgcn_mfma_f32_16x16x32_bf16(a0, bgf, accg[0], 0, 0, 0);
            accg[1] = __builtin_amdgcn_mfma_f32_16x16x32_bf16(a1, bgf, accg[1], 0, 0, 0);
            accu[0] = __builtin_amdgcn_mfma_f32_16x16x32_bf16(a0, buf, accu[0], 0, 0, 0);
            accu[1] = __builtin_amdgcn_mfma_f32_16x16x32_bf16(a1, buf, accu[1], 0, 0, 0);
        }
    }

#pragma unroll
    for (int mf = 0; mf < 2; ++mf) {
#pragma unroll
        for (int r = 0; r < 4; ++r) {
            int lrow = wid * 32 + mf * 16 + lhi * 4 + r;
            int rv = ridx[lrow];
            if (rv < 0) continue;
            float g = accg[mf][r];
            float u = accu[mf][r];
            float a = g / (1.f + __expf(-g)) * u;
            abuf[(size_t)rv * NI + n0 + l16] = f2bf(a);
        }
    }
}

// ---------------------------------------------------------------- MoE down proj + combine
// BM=128, BN=16. grid (D/16, 8, NE). out += wbuf[slot] * (abuf@Wd^T) via atomics.
__global__ __launch_bounds__(256) void moe_down_kernel(
    const unsigned short* __restrict__ abuf, const float* __restrict__ Wd,
    const int* __restrict__ cnt, const int* __restrict__ elist,
    const float* __restrict__ wbuf, float* __restrict__ out)
{
    int e = blockIdx.z;
    int me = cnt[e];
    int m0 = blockIdx.y * 128;
    if (m0 >= me) return;
    int n0 = blockIdx.x * 16;

    __shared__ unsigned short As[128 * 64];
    __shared__ unsigned short Bs[16 * 64];
    __shared__ int ridx[128];

    int tid = threadIdx.x;
    const int* idx = elist + e * S;
    if (tid < 128) ridx[tid] = (m0 + tid < me) ? idx[m0 + tid] : -1;
    __syncthreads();

    int arow_i = tid >> 1;
    int ahalf = (tid & 1) * 32;
    int rva = ridx[arow_i];
    const unsigned short* arow = (rva >= 0) ? (abuf + (size_t)rva * NI + ahalf) : nullptr;
    int wa[4];
#pragma unroll
    for (int u = 0; u < 4; ++u) {
        int g = (tid & 1) * 4 + u;
        wa[u] = arow_i * 64 + (g ^ (arow_i & 7)) * 8;
    }

    int tl = tid & 127;
    int bwrow = tl >> 3;
    int bg8 = tl & 7;
    const float* bp = Wd + ((size_t)e * D + n0 + bwrow) * NI + bg8 * 8;
    int wbo = bwrow * 64 + (bg8 ^ (bwrow & 7)) * 8;
    bool doB = tid < 128;

    int wid = tid >> 6, lane = tid & 63;
    int l16 = lane & 15, lhi = lane >> 4;

    int raoff[2][2], rboff[2];
#pragma unroll
    for (int mf = 0; mf < 2; ++mf) {
        int rowa = wid * 32 + mf * 16 + l16;
#pragma unroll
        for (int kh = 0; kh < 2; ++kh)
            raoff[mf][kh] = rowa * 64 + (((kh * 4 + lhi) ^ (rowa & 7))) * 8;
    }
#pragma unroll
    for (int kh = 0; kh < 2; ++kh)
        rboff[kh] = l16 * 64 + (((kh * 4 + lhi) ^ (l16 & 7))) * 8;

    f32x4 acc[2] = {};
    bf16x8 av[4];
    float4 bv[2];

    auto ldt = [&](int k0) {
        if (arow) {
#pragma unroll
            for (int u = 0; u < 4; ++u) av[u] = *(const bf16x8*)(arow + k0 + u * 8);
        } else {
            bf16x8 z = {};
#pragma unroll
            for (int u = 0; u < 4; ++u) av[u] = z;
        }
        if (doB) {
            bv[0] = *(const float4*)(bp + k0);
            bv[1] = *(const float4*)(bp + k0 + 4);
        }
    };

    ldt(0);
    for (int k0 = 0; k0 < NI; k0 += 64) {
        bf16x8 a0s = av[0], a1s = av[1], a2s = av[2], a3s = av[3];
        bf16x8 pb = pack8(bv[0], bv[1]);
        __syncthreads();
        *(bf16x8*)(As + wa[0]) = a0s;
        *(bf16x8*)(As + wa[1]) = a1s;
        *(bf16x8*)(As + wa[2]) = a2s;
        *(bf16x8*)(As + wa[3]) = a3s;
        if (doB) *(bf16x8*)(Bs + wbo) = pb;
        __syncthreads();
        if (k0 + 64 < NI) ldt(k0 + 64);
#pragma unroll
        for (int kh = 0; kh < 2; ++kh) {
            bf16x8 a0 = *(const bf16x8*)(As + raoff[0][kh]);
            bf16x8 a1 = *(const bf16x8*)(As + raoff[1][kh]);
            bf16x8 b = *(const bf16x8*)(Bs + rboff[kh]);
            acc[0] = __builtin_amdgcn_mfma_f32_16x16x32_bf16(a0, b, acc[0], 0, 0, 0);
            acc[1] = __builtin_amdgcn_mfma_f32_16x16x32_bf16(a1, b, acc[1], 0, 0, 0);
        }
    }

#pragma unroll
    for (int mf = 0; mf < 2; ++mf) {
#pragma unroll
        for (int r = 0; r < 4; ++r) {
            int lrow = wid * 32 + mf * 16 + lhi * 4 + r;
            int rv = ridx[lrow];
            if (rv < 0) continue;
            float w = wbuf[rv];
            atomicAdd(out + (size_t)(rv >> 1) * D + n0 + l16, w * acc[mf][r]);
        }
    }
}

// ---------------------------------------------------------------- q/k RMSNorm + RoPE -> bf16
// reads from qkvb (ldc 3072): q cols 0.., k cols 2048..
__global__ void qkrope_bf16_kernel(const float* __restrict__ qkvb,
                                   const float* __restrict__ qn_w, const float* __restrict__ kn_w,
                                   const int* __restrict__ pos_ids,
                                   unsigned short* __restrict__ qbh, unsigned short* __restrict__ kbh)
{
    int t = blockIdx.x;
    int h = blockIdx.y;
    int d = threadIdx.x;
    const float* base;
    const float* w;
    unsigned short* ob;
    float scale;
    if (h < NH) {
        base = qkvb + (size_t)t * 3072 + h * HD; w = qn_w;
        ob = qbh + (size_t)t * D + h * HD; scale = 0.08838834764831845f;
    } else {
        base = qkvb + (size_t)t * 3072 + 2048 + (h - NH) * HD; w = kn_w;
        ob = kbh + (size_t)t * (NKV * HD) + (h - NH) * HD; scale = 1.0f;
    }
    float x1 = base[d], x2 = base[d + 64];
    float ss = wave_reduce_sum64(x1 * x1 + x2 * x2);
    float r = rsqrtf(ss / (float)HD + EPS);
    float n1 = x1 * r * w[d];
    float n2 = x2 * r * w[d + 64];
    float pos = (float)pos_ids[t];
    float freq = powf(1000000.0f, -(float)d * (1.0f / 64.0f));
    float ang = pos * freq;
    float c, s;
    sincosf(ang, &s, &c);
    ob[d]      = f2bf((n1 * c - n2 * s) * scale);
    ob[d + 64] = f2bf((n2 * c + n1 * s) * scale);
}

// ---------------------------------------------------------------- V -> bf16 V^T [KV][HD][S]
// reads from qkvb cols 2560..
__global__ void vtrans_kernel(const float* __restrict__ qkvb, unsigned short* __restrict__ vbt)
{
    __shared__ unsigned short tile[64][65];
    int s0 = blockIdx.x * 64, d0 = blockIdx.y * 64, kvh = blockIdx.z;
    int tid = threadIdx.x;
    {
        int i = tid >> 2;
        int j4 = (tid & 3) * 16;
        const float* src = qkvb + (size_t)(s0 + i) * 3072 + 2560 + kvh * HD + d0 + j4;
#pragma unroll
        for (int u = 0; u < 4; ++u) {
            float4 f = *(const float4*)(src + u * 4);
            tile[i][j4 + u * 4 + 0] = f2bf(f.x);
            tile[i][j4 + u * 4 + 1] = f2bf(f.y);
            tile[i][j4 + u * 4 + 2] = f2bf(f.z);
            tile[i][j4 + u * 4 + 3] = f2bf(f.w);
        }
    }
    __syncthreads();
    {
        int j = tid >> 2;
        int i4 = (tid & 3) * 16;
        bf16x8 o0, o1;
#pragma unroll
        for (int u = 0; u < 8; ++u) {
            o0[u] = (short)tile[i4 + u][j];
            o1[u] = (short)tile[i4 + 8 + u][j];
        }
        unsigned short* dst = vbt + ((size_t)kvh * HD + d0 + j) * S + s0 + i4;
        *(bf16x8*)(dst) = o0;
        *(bf16x8*)(dst + 8) = o1;
    }
}

// ---------------------------------------------------------------- MFMA flash attention
__global__ __launch_bounds__(256) void flash_attn_mfma_kernel(
    const unsigned short* __restrict__ qbh, const unsigned short* __restrict__ kbh,
    const unsigned short* __restrict__ vbt, float* __restrict__ o)
{
    int qt = blockIdx.x;
    int h  = blockIdx.y;
    int kvh = h >> 2;

    __shared__ unsigned short Qs[64 * 128];
    __shared__ unsigned short Ks[64 * 128];
    __shared__ unsigned short Vs[128 * 64];
    __shared__ unsigned short Ps[4][16 * 72];

    int tid = threadIdx.x;
    int wid = tid >> 6, lane = tid & 63;
    int l16 = lane & 15, lhi = lane >> 4;

    {
        int r = tid >> 2;
        int gb = (tid & 3) * 4;
        const unsigned short* src = qbh + (size_t)(qt * 64 + r) * D + h * HD;
#pragma unroll
        for (int u = 0; u < 4; ++u) {
            int g = gb + u;
            bf16x8 val = *(const bf16x8*)(src + g * 8);
            *(bf16x8*)(Qs + r * 128 + (g ^ (r & 7)) * 8) = val;
        }
    }

    int qrow = wid * 16 + l16;
    int qoff[4];
#pragma unroll
    for (int kh = 0; kh < 4; ++kh)
        qoff[kh] = qrow * 128 + (((kh * 4 + lhi) ^ (qrow & 7))) * 8;

    float mreg[4], lreg[4];
#pragma unroll
    for (int r = 0; r < 4; ++r) { mreg[r] = -3.0e38f; lreg[r] = 0.f; }
    f32x4 oacc[8] = {};

    for (int kt = 0; kt < S / 64; ++kt) {
        __syncthreads();
        {
            int r = tid >> 2;
            int gb = (tid & 3) * 4;
            const unsigned short* src = kbh + (size_t)(kt * 64 + r) * (NKV * HD) + kvh * HD;
#pragma unroll
            for (int u = 0; u < 4; ++u) {
                int g = gb + u;
                bf16x8 val = *(const bf16x8*)(src + g * 8);
                *(bf16x8*)(Ks + r * 128 + (g ^ (r & 7)) * 8) = val;
            }
        }
        {
            int r = tid >> 1;
            int gb = (tid & 1) * 4;
            const unsigned short* src = vbt + ((size_t)kvh * HD + r) * S + kt * 64;
#pragma unroll
            for (int u = 0; u < 4; ++u) {
                int g = gb + u;
                bf16x8 val = *(const bf16x8*)(src + g * 8);
                *(bf16x8*)(Vs + r * 64 + (g ^ (r & 7)) * 8) = val;
            }
        }
        __syncthreads();

        bf16x8 qa[4];
#pragma unroll
        for (int kh = 0; kh < 4; ++kh) qa[kh] = *(const bf16x8*)(Qs + qoff[kh]);
        f32x4 sc[4] = {};
#pragma unroll
        for (int nf = 0; nf < 4; ++nf) {
            int krow = nf * 16 + l16;
#pragma unroll
            for (int kh = 0; kh < 4; ++kh) {
                bf16x8 kf = *(const bf16x8*)(Ks + krow * 128 + (((kh * 4 + lhi) ^ (krow & 7))) * 8);
                sc[nf] = __builtin_amdgcn_mfma_f32_16x16x32_bf16(qa[kh], kf, sc[nf], 0, 0, 0);
            }
        }

        float corr[4];
#pragma unroll
        for (int r = 0; r < 4; ++r) {
            float tmax = fmaxf(fmaxf(sc[0][r], sc[1][r]), fmaxf(sc[2][r], sc[3][r]));
            tmax = fmaxf(tmax, __shfl_xor(tmax, 1, 64));
            tmax = fmaxf(tmax, __shfl_xor(tmax, 2, 64));
            tmax = fmaxf(tmax, __shfl_xor(tmax, 4, 64));
            tmax = fmaxf(tmax, __shfl_xor(tmax, 8, 64));
            float mn = fmaxf(mreg[r], tmax);
            corr[r] = __expf(mreg[r] - mn);
            mreg[r] = mn;
            float psum = 0.f;
#pragma unroll
            for (int nf = 0; nf < 4; ++nf) {
                float p = __expf(sc[nf][r] - mn);
                sc[nf][r] = p;
                psum += p;
            }
            psum += __shfl_xor(psum, 1, 64);
            psum += __shfl_xor(psum, 2, 64);
            psum += __shfl_xor(psum, 4, 64);
            psum += __shfl_xor(psum, 8, 64);
            lreg[r] = lreg[r] * corr[r] + psum;
        }
#pragma unroll
        for (int fb = 0; fb < 8; ++fb)
#pragma unroll
            for (int r = 0; r < 4; ++r) oacc[fb][r] *= corr[r];

#pragma unroll
        for (int nf = 0; nf < 4; ++nf)
#pragma unroll
            for (int r = 0; r < 4; ++r)
                Ps[wid][(lhi * 4 + r) * 72 + nf * 16 + l16] = f2bf(sc[nf][r]);

        bf16x8 pa[2];
#pragma unroll
        for (int k2 = 0; k2 < 2; ++k2)
            pa[k2] = *(const bf16x8*)(&Ps[wid][l16 * 72 + k2 * 32 + lhi * 8]);

#pragma unroll
        for (int fb = 0; fb < 8; ++fb) {
            int vrow = fb * 16 + l16;
#pragma unroll
            for (int k2 = 0; k2 < 2; ++k2) {
                bf16x8 vf = *(const bf16x8*)(Vs + vrow * 64 + (((k2 * 4 + lhi) ^ (vrow & 7))) * 8);
                oacc[fb] = __builtin_amdgcn_mfma_f32_16x16x32_bf16(pa[k2], vf, oacc[fb], 0, 0, 0);
            }
        }
    }

    float linv[4];
#pragma unroll
    for (int r = 0; r < 4; ++r) linv[r] = 1.f / lreg[r];
#pragma unroll
    for (int fb = 0; fb < 8; ++fb) {
#pragma unroll
        for (int r = 0; r < 4; ++r) {
            int row = qt * 64 + wid * 16 + lhi * 4 + r;
            o[(size_t)row * D + h * HD + fb * 16 + l16] = oacc[fb][r] * linv[r];
        }
    }
}

// ---------------------------------------------------------------- MoE gate + expert lists
__global__ void gate_kernel(const float* __restrict__ x, const float* __restrict__ gw,
                            float* __restrict__ wbuf, int* __restrict__ cnt, int* __restrict__ elist)
{
    int t = blockIdx.x;
    int g = threadIdx.x >> 4, j = threadIdx.x & 15;
    const float* xr = x + (size_t)t * D;
    const float* gr = gw + (size_t)g * D;
    float p = 0.f;
    for (int m = 0; m < D / 16; ++m) p += xr[j + 16 * m] * gr[j + 16 * m];
    for (int off = 8; off; off >>= 1) p += __shfl_down(p, off, 64);
    __shared__ float lg[NE];
    if (j == 0) lg[g] = p;
    __syncthreads();
    if (threadIdx.x == 0) {
        float l0 = -1e30f; int i0 = 0;
        for (int e = 0; e < NE; ++e) if (lg[e] > l0) { l0 = lg[e]; i0 = e; }
        float l1 = -1e30f; int i1 = 0;
        for (int e = 0; e < NE; ++e) if (e != i0 && lg[e] > l1) { l1 = lg[e]; i1 = e; }
        float rr = expf(l1 - l0);
        wbuf[t * 2 + 0] = 1.f / (1.f + rr);
        wbuf[t * 2 + 1] = rr / (1.f + rr);
        int s0 = atomicAdd(&cnt[i0], 1); elist[i0 * S + s0] = t * 2;
        int s1 = atomicAdd(&cnt[i1], 1); elist[i1 * S + s1] = t * 2 + 1;
    }
}

// ---------------------------------------------------------------- launch
extern "C" void kernel_launch(void* const* d_in, const int* in_sizes, int n_in,
                              void* d_out, int out_size, void* d_ws, size_t ws_size,
                              hipStream_t stream)
{
    const float* hidden = (const float*)d_in[0];
    const float* ln1 = (const float*)d_in[1];
    const float* ln2 = (const float*)d_in[2];
    const float* qn  = (const float*)d_in[3];
    const float* kn  = (const float*)d_in[4];
    const float* Wq  = (const float*)d_in[5];
    const float* Wk  = (const float*)d_in[6];
    const float* Wv  = (const float*)d_in[7];
    const float* Wo  = (const float*)d_in[8];
    const float* gw  = (const float*)d_in[9];
    const float* Wg  = (const float*)d_in[10];
    const float* Wu  = (const float*)d_in[11];
    const float* Wd  = (const float*)d_in[12];
    const int*   pos = (const int*)d_in[13];

    float* ws    = (float*)d_ws;
    float* h1    = ws;                    // 2M floats; overlays qbh/kbh/vbt bf16
    float* qkvb  = h1 + 2097152;          // S*3072 = 3.15M floats
    float* attn  = qkvb + 3145728;        // 2M; overlays abuf bf16
    float* hattn = attn + 2097152;        // 2M
    float* h2    = hattn + 2097152;       // 2M
    float* wbuf  = h2 + 2097152;          // 2048
    int*   cnt   = (int*)(wbuf + 2048);   // 16
    int*   elist = cnt + 16;              // 16*1024

    unsigned short* qbh = (unsigned short*)h1;                 // S*D bf16
    unsigned short* kbh = (unsigned short*)(h1 + 1048576);     // S*512 bf16
    unsigned short* vbt = (unsigned short*)(h1 + 1310720);     // 512*S bf16
    unsigned short* abuf = (unsigned short*)attn;              // 2048*NI bf16
    float* out   = (float*)d_out;

    hipMemsetAsync(cnt, 0, NE * sizeof(int), stream);

    rmsnorm_kernel<<<S, 256, 0, stream>>>(hidden, ln1, h1);
    qkv_gemm_kernel<<<dim3(48, 16), 256, 0, stream>>>(h1, Wq, Wk, Wv, qkvb);
    // h1 dead; bf16 overlays
    qkrope_bf16_kernel<<<dim3(S, NH + NKV), 64, 0, stream>>>(qkvb, qn, kn, pos, qbh, kbh);
    vtrans_kernel<<<dim3(S / 64, HD / 64, NKV), 256, 0, stream>>>(qkvb, vbt);
    flash_attn_mfma_kernel<<<dim3(S / 64, NH), 256, 0, stream>>>(qbh, kbh, vbt, attn);
    // O projection + residual; also writes out (= hattn) for MoE atomic accumulation
    mfma_gemm_kernel<<<dim3(32, 16), 256, 0, stream>>>(attn, D, Wo, D, hattn, D, hidden, out, S, 2048, D);
    rmsnorm_kernel<<<S, 256, 0, stream>>>(hattn, ln2, h2);
    gate_kernel<<<S, 256, 0, stream>>>(h2, gw, wbuf, cnt, elist);
    // attn buffer dead; abuf overlays
    moe_mlp_kernel<<<dim3(NI / 16, 8, NE), 256, 0, stream>>>(h2, Wg, Wu, cnt, elist, abuf);
    moe_down_kernel<<<dim3(D / 16, 8, NE), 256, 0, stream>>>(abuf, Wd, cnt, elist, wbuf, out);
}

// Round 6
// 342.258 us; speedup vs baseline: 5.0453x; 1.3196x over previous
//
#include <hip/hip_runtime.h>
#include <hip/hip_bf16.h>
#include <math.h>

#define D 2048
#define NH 16
#define NKV 4
#define HD 128
#define NE 16
#define NI 768
#define S 1024
#define EPS 1e-6f

typedef __attribute__((ext_vector_type(8))) short bf16x8;
typedef __attribute__((ext_vector_type(4))) float f32x4;

__device__ __forceinline__ float wave_reduce_sum64(float v) {
    for (int off = 32; off; off >>= 1) v += __shfl_xor(v, off, 64);
    return v;
}

__device__ __forceinline__ unsigned short f2bf(float f) {
    unsigned int x = __float_as_uint(f);
    x += 0x7FFFu + ((x >> 16) & 1u);   // round-to-nearest-even
    return (unsigned short)(x >> 16);
}

__device__ __forceinline__ bf16x8 pack8(const float4 a, const float4 b) {
    bf16x8 r;
    r[0] = (short)f2bf(a.x); r[1] = (short)f2bf(a.y);
    r[2] = (short)f2bf(a.z); r[3] = (short)f2bf(a.w);
    r[4] = (short)f2bf(b.x); r[5] = (short)f2bf(b.y);
    r[6] = (short)f2bf(b.z); r[7] = (short)f2bf(b.w);
    return r;
}

// ---------------------------------------------------------------- RMSNorm over D (+ optional bf16 copy)
__global__ void rmsnorm_kernel(const float* __restrict__ x, const float* __restrict__ w,
                               float* __restrict__ y, unsigned short* __restrict__ yb) {
    int t = blockIdx.x;
    const float* xr = x + (size_t)t * D;
    float* yr = y + (size_t)t * D;
    float v[8];
    float ss = 0.f;
#pragma unroll
    for (int m = 0; m < 8; ++m) {
        v[m] = xr[threadIdx.x + 256 * m];
        ss += v[m] * v[m];
    }
    ss = wave_reduce_sum64(ss);
    __shared__ float wsum[4];
    if ((threadIdx.x & 63) == 0) wsum[threadIdx.x >> 6] = ss;
    __syncthreads();
    float tot = wsum[0] + wsum[1] + wsum[2] + wsum[3];
    float r = rsqrtf(tot / (float)D + EPS);
#pragma unroll
    for (int m = 0; m < 8; ++m) {
        int d = threadIdx.x + 256 * m;
        float val = v[m] * r * w[d];
        yr[d] = val;
        if (yb) yb[(size_t)t * D + d] = f2bf(val);
    }
}

// ---------------------------------------------------------------- dense MFMA GEMM (prefetched)
// C = A@W^T (+R); optional duplicate write to C2. BM=BN=BK=64.
__global__ __launch_bounds__(256) void mfma_gemm_kernel(
    const float* __restrict__ A, int lda,
    const float* __restrict__ W, int ldw,
    float* __restrict__ C, int ldc,
    const float* __restrict__ R, float* __restrict__ C2,
    int M, int N, int K)
{
    int m0 = blockIdx.y * 64;
    int n0 = blockIdx.x * 64;

    __shared__ unsigned short As[64 * 64];
    __shared__ unsigned short Bs[64 * 64];

    int tid = threadIdx.x;
    int srow = tid >> 2;
    int scol = (tid & 3) * 16;

    const float* ap = A + (size_t)(m0 + srow) * lda + scol;
    const float* wp = W + (size_t)(n0 + srow) * ldw + scol;

    int wlo[2];
#pragma unroll
    for (int u = 0; u < 2; ++u) {
        int g = (tid & 3) * 2 + u;
        wlo[u] = srow * 64 + (g ^ (srow & 7)) * 8;
    }

    int wid = tid >> 6, lane = tid & 63;
    int wm = wid >> 1, wn = wid & 1;
    int l16 = lane & 15, lhi = lane >> 4;

    int ra[2][2], rb[2][2];
#pragma unroll
    for (int f = 0; f < 2; ++f) {
        int rowa = wm * 32 + f * 16 + l16;
        int rowb = wn * 32 + f * 16 + l16;
#pragma unroll
        for (int kh = 0; kh < 2; ++kh) {
            ra[f][kh] = rowa * 64 + (((kh * 4 + lhi) ^ (rowa & 7))) * 8;
            rb[f][kh] = rowb * 64 + (((kh * 4 + lhi) ^ (rowb & 7))) * 8;
        }
    }

    f32x4 acc[2][2] = {};
    float4 av[4], wv[4];

    auto ldt = [&](int k0) {
#pragma unroll
        for (int u = 0; u < 4; ++u) {
            av[u] = *(const float4*)(ap + k0 + u * 4);
            wv[u] = *(const float4*)(wp + k0 + u * 4);
        }
    };

    ldt(0);
    for (int k0 = 0; k0 < K; k0 += 64) {
        bf16x8 pa0 = pack8(av[0], av[1]);
        bf16x8 pa1 = pack8(av[2], av[3]);
        bf16x8 pw0 = pack8(wv[0], wv[1]);
        bf16x8 pw1 = pack8(wv[2], wv[3]);
        __syncthreads();
        *(bf16x8*)(As + wlo[0]) = pa0;
        *(bf16x8*)(As + wlo[1]) = pa1;
        *(bf16x8*)(Bs + wlo[0]) = pw0;
        *(bf16x8*)(Bs + wlo[1]) = pw1;
        __syncthreads();
        if (k0 + 64 < K) ldt(k0 + 64);
#pragma unroll
        for (int kh = 0; kh < 2; ++kh) {
            bf16x8 af0 = *(const bf16x8*)(As + ra[0][kh]);
            bf16x8 af1 = *(const bf16x8*)(As + ra[1][kh]);
            bf16x8 bf0 = *(const bf16x8*)(Bs + rb[0][kh]);
            bf16x8 bf1 = *(const bf16x8*)(Bs + rb[1][kh]);
            acc[0][0] = __builtin_amdgcn_mfma_f32_16x16x32_bf16(af0, bf0, acc[0][0], 0, 0, 0);
            acc[0][1] = __builtin_amdgcn_mfma_f32_16x16x32_bf16(af0, bf1, acc[0][1], 0, 0, 0);
            acc[1][0] = __builtin_amdgcn_mfma_f32_16x16x32_bf16(af1, bf0, acc[1][0], 0, 0, 0);
            acc[1][1] = __builtin_amdgcn_mfma_f32_16x16x32_bf16(af1, bf1, acc[1][1], 0, 0, 0);
        }
    }

#pragma unroll
    for (int mi = 0; mi < 2; ++mi) {
#pragma unroll
        for (int r = 0; r < 4; ++r) {
            int grow = m0 + wm * 32 + mi * 16 + lhi * 4 + r;
#pragma unroll
            for (int ni = 0; ni < 2; ++ni) {
                int gcol = n0 + wn * 32 + ni * 16 + l16;
                float v = acc[mi][ni][r];
                if (R) v += R[(size_t)grow * ldc + gcol];
                C[(size_t)grow * ldc + gcol] = v;
                if (C2) C2[(size_t)grow * ldc + gcol] = v;
            }
        }
    }
}

// ---------------------------------------------------------------- fused QKV GEMM
// N = 3072: cols 0..2047 = Wq, 2048..2559 = Wk, 2560..3071 = Wv. C ldc = 3072.
__global__ __launch_bounds__(256) void qkv_gemm_kernel(
    const float* __restrict__ A,
    const float* __restrict__ Wq, const float* __restrict__ Wk, const float* __restrict__ Wv,
    float* __restrict__ C)
{
    int m0 = blockIdx.y * 64;
    int n0 = blockIdx.x * 64;

    const float* W;
    int wr0;
    if (n0 < 2048)      { W = Wq; wr0 = n0; }
    else if (n0 < 2560) { W = Wk; wr0 = n0 - 2048; }
    else                { W = Wv; wr0 = n0 - 2560; }

    __shared__ unsigned short As[64 * 64];
    __shared__ unsigned short Bs[64 * 64];

    int tid = threadIdx.x;
    int srow = tid >> 2;
    int scol = (tid & 3) * 16;

    const float* ap = A + (size_t)(m0 + srow) * D + scol;
    const float* wp = W + (size_t)(wr0 + srow) * D + scol;

    int wlo[2];
#pragma unroll
    for (int u = 0; u < 2; ++u) {
        int g = (tid & 3) * 2 + u;
        wlo[u] = srow * 64 + (g ^ (srow & 7)) * 8;
    }

    int wid = tid >> 6, lane = tid & 63;
    int wm = wid >> 1, wn = wid & 1;
    int l16 = lane & 15, lhi = lane >> 4;

    int ra[2][2], rb[2][2];
#pragma unroll
    for (int f = 0; f < 2; ++f) {
        int rowa = wm * 32 + f * 16 + l16;
        int rowb = wn * 32 + f * 16 + l16;
#pragma unroll
        for (int kh = 0; kh < 2; ++kh) {
            ra[f][kh] = rowa * 64 + (((kh * 4 + lhi) ^ (rowa & 7))) * 8;
            rb[f][kh] = rowb * 64 + (((kh * 4 + lhi) ^ (rowb & 7))) * 8;
        }
    }

    f32x4 acc[2][2] = {};
    float4 av[4], wv[4];

    auto ldt = [&](int k0) {
#pragma unroll
        for (int u = 0; u < 4; ++u) {
            av[u] = *(const float4*)(ap + k0 + u * 4);
            wv[u] = *(const float4*)(wp + k0 + u * 4);
        }
    };

    ldt(0);
    for (int k0 = 0; k0 < D; k0 += 64) {
        bf16x8 pa0 = pack8(av[0], av[1]);
        bf16x8 pa1 = pack8(av[2], av[3]);
        bf16x8 pw0 = pack8(wv[0], wv[1]);
        bf16x8 pw1 = pack8(wv[2], wv[3]);
        __syncthreads();
        *(bf16x8*)(As + wlo[0]) = pa0;
        *(bf16x8*)(As + wlo[1]) = pa1;
        *(bf16x8*)(Bs + wlo[0]) = pw0;
        *(bf16x8*)(Bs + wlo[1]) = pw1;
        __syncthreads();
        if (k0 + 64 < D) ldt(k0 + 64);
#pragma unroll
        for (int kh = 0; kh < 2; ++kh) {
            bf16x8 af0 = *(const bf16x8*)(As + ra[0][kh]);
            bf16x8 af1 = *(const bf16x8*)(As + ra[1][kh]);
            bf16x8 bf0 = *(const bf16x8*)(Bs + rb[0][kh]);
            bf16x8 bf1 = *(const bf16x8*)(Bs + rb[1][kh]);
            acc[0][0] = __builtin_amdgcn_mfma_f32_16x16x32_bf16(af0, bf0, acc[0][0], 0, 0, 0);
            acc[0][1] = __builtin_amdgcn_mfma_f32_16x16x32_bf16(af0, bf1, acc[0][1], 0, 0, 0);
            acc[1][0] = __builtin_amdgcn_mfma_f32_16x16x32_bf16(af1, bf0, acc[1][0], 0, 0, 0);
            acc[1][1] = __builtin_amdgcn_mfma_f32_16x16x32_bf16(af1, bf1, acc[1][1], 0, 0, 0);
        }
    }

#pragma unroll
    for (int mi = 0; mi < 2; ++mi) {
#pragma unroll
        for (int r = 0; r < 4; ++r) {
            int grow = m0 + wm * 32 + mi * 16 + lhi * 4 + r;
#pragma unroll
            for (int ni = 0; ni < 2; ++ni) {
                int gcol = n0 + wn * 32 + ni * 16 + l16;
                C[(size_t)grow * 3072 + gcol] = acc[mi][ni][r];
            }
        }
    }
}

// ---------------------------------------------------------------- fused MoE up+gate (gathered)
// BM=64, BN=16, BK=64. grid (NI/16, 16, NE). A = h2b (bf16). abuf[slot][i] = silu(g)*u bf16.
__global__ __launch_bounds__(256) void moe_mlp_kernel(
    const unsigned short* __restrict__ h2b,
    const float* __restrict__ Wg, const float* __restrict__ Wu,
    const int* __restrict__ cnt, const int* __restrict__ elist,
    unsigned short* __restrict__ abuf)
{
    int e = blockIdx.z;
    int me = cnt[e];
    int m0 = blockIdx.y * 64;
    if (m0 >= me) return;
    int n0 = blockIdx.x * 16;

    __shared__ unsigned short As[64 * 64];
    __shared__ unsigned short Gs[16 * 64];
    __shared__ unsigned short Us[16 * 64];
    __shared__ int ridx[64];

    int tid = threadIdx.x;
    const int* idx = elist + e * S;
    if (tid < 64) ridx[tid] = (m0 + tid < me) ? idx[m0 + tid] : -1;
    __syncthreads();

    // A staging: bf16, thread t -> row t>>2, 16 elems at (t&3)*16
    int arow_i = tid >> 2;
    int acolg = (tid & 3) * 16;
    int rva = ridx[arow_i];
    const unsigned short* arow = (rva >= 0) ? (h2b + (size_t)(rva >> 1) * D + acolg) : nullptr;
    int wa[2];
#pragma unroll
    for (int u = 0; u < 2; ++u) {
        int g = (tid & 3) * 2 + u;
        wa[u] = arow_i * 64 + (g ^ (arow_i & 7)) * 8;
    }

    // B staging: threads 0-127 -> Wg, 128-255 -> Wu; 8 floats/thread
    int tl = tid & 127;
    int bwrow = tl >> 3;
    int bg8 = tl & 7;
    const float* bp = ((tid < 128) ? Wg : Wu) + ((size_t)e * NI + n0 + bwrow) * D + bg8 * 8;
    unsigned short* bs = (tid < 128) ? Gs : Us;
    int wbo = bwrow * 64 + (bg8 ^ (bwrow & 7)) * 8;

    int wid = tid >> 6, lane = tid & 63;
    int l16 = lane & 15, lhi = lane >> 4;

    int raoff[2], rboff[2];
    {
        int rowa = wid * 16 + l16;
#pragma unroll
        for (int kh = 0; kh < 2; ++kh) {
            raoff[kh] = rowa * 64 + (((kh * 4 + lhi) ^ (rowa & 7))) * 8;
            rboff[kh] = l16 * 64 + (((kh * 4 + lhi) ^ (l16 & 7))) * 8;
        }
    }

    f32x4 accg = {}, accu = {};
    bf16x8 av[2];
    float4 bv[2];

    auto ldt = [&](int k0) {
        if (arow) {
            av[0] = *(const bf16x8*)(arow + k0);
            av[1] = *(const bf16x8*)(arow + k0 + 8);
        } else {
            bf16x8 z = {};
            av[0] = z; av[1] = z;
        }
        bv[0] = *(const float4*)(bp + k0);
        bv[1] = *(const float4*)(bp + k0 + 4);
    };

    ldt(0);
    for (int k0 = 0; k0 < D; k0 += 64) {
        bf16x8 a0s = av[0], a1s = av[1];
        bf16x8 pb = pack8(bv[0], bv[1]);
        __syncthreads();
        *(bf16x8*)(As + wa[0]) = a0s;
        *(bf16x8*)(As + wa[1]) = a1s;
        *(bf16x8*)(bs + wbo) = pb;
        __syncthreads();
        if (k0 + 64 < D) ldt(k0 + 64);
#pragma unroll
        for (int kh = 0; kh < 2; ++kh) {
            bf16x8 a = *(const bf16x8*)(As + raoff[kh]);
            bf16x8 bgf = *(const bf16x8*)(Gs + rboff[kh]);
            bf16x8 buf = *(const bf16x8*)(Us + rboff[kh]);
            accg = __builtin_amdgcn_mfma_f32_16x16x32_bf16(a, bgf, accg, 0, 0, 0);
            accu = __builtin_amdgcn_mfma_f32_16x16x32_bf16(a, buf, accu, 0, 0, 0);
        }
    }

#pragma unroll
    for (int r = 0; r < 4; ++r) {
        int lrow = wid * 16 + lhi * 4 + r;
        int rv = ridx[lrow];
        if (rv < 0) continue;
        float g = accg[r];
        float u = accu[r];
        float a = g / (1.f + __expf(-g)) * u;
        abuf[(size_t)rv * NI + n0 + l16] = f2bf(a);
    }
}

// ---------------------------------------------------------------- MoE down proj + combine
// BM=64, BN=16. grid (D/16, 16, NE). out += wbuf[slot] * (abuf@Wd^T) via atomics.
__global__ __launch_bounds__(256) void moe_down_kernel(
    const unsigned short* __restrict__ abuf, const float* __restrict__ Wd,
    const int* __restrict__ cnt, const int* __restrict__ elist,
    const float* __restrict__ wbuf, float* __restrict__ out)
{
    int e = blockIdx.z;
    int me = cnt[e];
    int m0 = blockIdx.y * 64;
    if (m0 >= me) return;
    int n0 = blockIdx.x * 16;

    __shared__ unsigned short As[64 * 64];
    __shared__ unsigned short Bs[16 * 64];
    __shared__ int ridx[64];

    int tid = threadIdx.x;
    const int* idx = elist + e * S;
    if (tid < 64) ridx[tid] = (m0 + tid < me) ? idx[m0 + tid] : -1;
    __syncthreads();

    int arow_i = tid >> 2;
    int acolg = (tid & 3) * 16;
    int rva = ridx[arow_i];
    const unsigned short* arow = (rva >= 0) ? (abuf + (size_t)rva * NI + acolg) : nullptr;
    int wa[2];
#pragma unroll
    for (int u = 0; u < 2; ++u) {
        int g = (tid & 3) * 2 + u;
        wa[u] = arow_i * 64 + (g ^ (arow_i & 7)) * 8;
    }

    int tl = tid & 127;
    int bwrow = tl >> 3;
    int bg8 = tl & 7;
    const float* bp = Wd + ((size_t)e * D + n0 + bwrow) * NI + bg8 * 8;
    int wbo = bwrow * 64 + (bg8 ^ (bwrow & 7)) * 8;
    bool doB = tid < 128;

    int wid = tid >> 6, lane = tid & 63;
    int l16 = lane & 15, lhi = lane >> 4;

    int raoff[2], rboff[2];
    {
        int rowa = wid * 16 + l16;
#pragma unroll
        for (int kh = 0; kh < 2; ++kh) {
            raoff[kh] = rowa * 64 + (((kh * 4 + lhi) ^ (rowa & 7))) * 8;
            rboff[kh] = l16 * 64 + (((kh * 4 + lhi) ^ (l16 & 7))) * 8;
        }
    }

    f32x4 acc = {};
    bf16x8 av[2];
    float4 bv[2];

    auto ldt = [&](int k0) {
        if (arow) {
            av[0] = *(const bf16x8*)(arow + k0);
            av[1] = *(const bf16x8*)(arow + k0 + 8);
        } else {
            bf16x8 z = {};
            av[0] = z; av[1] = z;
        }
        if (doB) {
            bv[0] = *(const float4*)(bp + k0);
            bv[1] = *(const float4*)(bp + k0 + 4);
        }
    };

    ldt(0);
    for (int k0 = 0; k0 < NI; k0 += 64) {
        bf16x8 a0s = av[0], a1s = av[1];
        bf16x8 pb = pack8(bv[0], bv[1]);
        __syncthreads();
        *(bf16x8*)(As + wa[0]) = a0s;
        *(bf16x8*)(As + wa[1]) = a1s;
        if (doB) *(bf16x8*)(Bs + wbo) = pb;
        __syncthreads();
        if (k0 + 64 < NI) ldt(k0 + 64);
#pragma unroll
        for (int kh = 0; kh < 2; ++kh) {
            bf16x8 a = *(const bf16x8*)(As + raoff[kh]);
            bf16x8 b = *(const bf16x8*)(Bs + rboff[kh]);
            acc = __builtin_amdgcn_mfma_f32_16x16x32_bf16(a, b, acc, 0, 0, 0);
        }
    }

#pragma unroll
    for (int r = 0; r < 4; ++r) {
        int lrow = wid * 16 + lhi * 4 + r;
        int rv = ridx[lrow];
        if (rv < 0) continue;
        float w = wbuf[rv];
        atomicAdd(out + (size_t)(rv >> 1) * D + n0 + l16, w * acc[r]);
    }
}

// ---------------------------------------------------------------- q/k RMSNorm + RoPE -> bf16
// reads from qkvb (ldc 3072): q cols 0.., k cols 2048..
__global__ void qkrope_bf16_kernel(const float* __restrict__ qkvb,
                                   const float* __restrict__ qn_w, const float* __restrict__ kn_w,
                                   const int* __restrict__ pos_ids,
                                   unsigned short* __restrict__ qbh, unsigned short* __restrict__ kbh)
{
    int t = blockIdx.x;
    int h = blockIdx.y;
    int d = threadIdx.x;
    const float* base;
    const float* w;
    unsigned short* ob;
    float scale;
    if (h < NH) {
        base = qkvb + (size_t)t * 3072 + h * HD; w = qn_w;
        ob = qbh + (size_t)t * D + h * HD; scale = 0.08838834764831845f;
    } else {
        base = qkvb + (size_t)t * 3072 + 2048 + (h - NH) * HD; w = kn_w;
        ob = kbh + (size_t)t * (NKV * HD) + (h - NH) * HD; scale = 1.0f;
    }
    float x1 = base[d], x2 = base[d + 64];
    float ss = wave_reduce_sum64(x1 * x1 + x2 * x2);
    float r = rsqrtf(ss / (float)HD + EPS);
    float n1 = x1 * r * w[d];
    float n2 = x2 * r * w[d + 64];
    float pos = (float)pos_ids[t];
    float freq = powf(1000000.0f, -(float)d * (1.0f / 64.0f));
    float ang = pos * freq;
    float c, s;
    sincosf(ang, &s, &c);
    ob[d]      = f2bf((n1 * c - n2 * s) * scale);
    ob[d + 64] = f2bf((n2 * c + n1 * s) * scale);
}

// ---------------------------------------------------------------- V -> bf16 V^T [KV][HD][S]
// reads from qkvb cols 2560..
__global__ void vtrans_kernel(const float* __restrict__ qkvb, unsigned short* __restrict__ vbt)
{
    __shared__ unsigned short tile[64][65];
    int s0 = blockIdx.x * 64, d0 = blockIdx.y * 64, kvh = blockIdx.z;
    int tid = threadIdx.x;
    {
        int i = tid >> 2;
        int j4 = (tid & 3) * 16;
        const float* src = qkvb + (size_t)(s0 + i) * 3072 + 2560 + kvh * HD + d0 + j4;
#pragma unroll
        for (int u = 0; u < 4; ++u) {
            float4 f = *(const float4*)(src + u * 4);
            tile[i][j4 + u * 4 + 0] = f2bf(f.x);
            tile[i][j4 + u * 4 + 1] = f2bf(f.y);
            tile[i][j4 + u * 4 + 2] = f2bf(f.z);
            tile[i][j4 + u * 4 + 3] = f2bf(f.w);
        }
    }
    __syncthreads();
    {
        int j = tid >> 2;
        int i4 = (tid & 3) * 16;
        bf16x8 o0, o1;
#pragma unroll
        for (int u = 0; u < 8; ++u) {
            o0[u] = (short)tile[i4 + u][j];
            o1[u] = (short)tile[i4 + 8 + u][j];
        }
        unsigned short* dst = vbt + ((size_t)kvh * HD + d0 + j) * S + s0 + i4;
        *(bf16x8*)(dst) = o0;
        *(bf16x8*)(dst + 8) = o1;
    }
}

// ---------------------------------------------------------------- MFMA flash attention
__global__ __launch_bounds__(256) void flash_attn_mfma_kernel(
    const unsigned short* __restrict__ qbh, const unsigned short* __restrict__ kbh,
    const unsigned short* __restrict__ vbt, float* __restrict__ o)
{
    int qt = blockIdx.x;
    int h  = blockIdx.y;
    int kvh = h >> 2;

    __shared__ unsigned short Qs[64 * 128];
    __shared__ unsigned short Ks[64 * 128];
    __shared__ unsigned short Vs[128 * 64];
    __shared__ unsigned short Ps[4][16 * 72];

    int tid = threadIdx.x;
    int wid = tid >> 6, lane = tid & 63;
    int l16 = lane & 15, lhi = lane >> 4;

    {
        int r = tid >> 2;
        int gb = (tid & 3) * 4;
        const unsigned short* src = qbh + (size_t)(qt * 64 + r) * D + h * HD;
#pragma unroll
        for (int u = 0; u < 4; ++u) {
            int g = gb + u;
            bf16x8 val = *(const bf16x8*)(src + g * 8);
            *(bf16x8*)(Qs + r * 128 + (g ^ (r & 7)) * 8) = val;
        }
    }

    int qrow = wid * 16 + l16;
    int qoff[4];
#pragma unroll
    for (int kh = 0; kh < 4; ++kh)
        qoff[kh] = qrow * 128 + (((kh * 4 + lhi) ^ (qrow & 7))) * 8;

    float mreg[4], lreg[4];
#pragma unroll
    for (int r = 0; r < 4; ++r) { mreg[r] = -3.0e38f; lreg[r] = 0.f; }
    f32x4 oacc[8] = {};

    for (int kt = 0; kt < S / 64; ++kt) {
        __syncthreads();
        {
            int r = tid >> 2;
            int gb = (tid & 3) * 4;
            const unsigned short* src = kbh + (size_t)(kt * 64 + r) * (NKV * HD) + kvh * HD;
#pragma unroll
            for (int u = 0; u < 4; ++u) {
                int g = gb + u;
                bf16x8 val = *(const bf16x8*)(src + g * 8);
                *(bf16x8*)(Ks + r * 128 + (g ^ (r & 7)) * 8) = val;
            }
        }
        {
            int r = tid >> 1;
            int gb = (tid & 1) * 4;
            const unsigned short* src = vbt + ((size_t)kvh * HD + r) * S + kt * 64;
#pragma unroll
            for (int u = 0; u < 4; ++u) {
                int g = gb + u;
                bf16x8 val = *(const bf16x8*)(src + g * 8);
                *(bf16x8*)(Vs + r * 64 + (g ^ (r & 7)) * 8) = val;
            }
        }
        __syncthreads();

        bf16x8 qa[4];
#pragma unroll
        for (int kh = 0; kh < 4; ++kh) qa[kh] = *(const bf16x8*)(Qs + qoff[kh]);
        f32x4 sc[4] = {};
#pragma unroll
        for (int nf = 0; nf < 4; ++nf) {
            int krow = nf * 16 + l16;
#pragma unroll
            for (int kh = 0; kh < 4; ++kh) {
                bf16x8 kf = *(const bf16x8*)(Ks + krow * 128 + (((kh * 4 + lhi) ^ (krow & 7))) * 8);
                sc[nf] = __builtin_amdgcn_mfma_f32_16x16x32_bf16(qa[kh], kf, sc[nf], 0, 0, 0);
            }
        }

        float corr[4];
#pragma unroll
        for (int r = 0; r < 4; ++r) {
            float tmax = fmaxf(fmaxf(sc[0][r], sc[1][r]), fmaxf(sc[2][r], sc[3][r]));
            tmax = fmaxf(tmax, __shfl_xor(tmax, 1, 64));
            tmax = fmaxf(tmax, __shfl_xor(tmax, 2, 64));
            tmax = fmaxf(tmax, __shfl_xor(tmax, 4, 64));
            tmax = fmaxf(tmax, __shfl_xor(tmax, 8, 64));
            float mn = fmaxf(mreg[r], tmax);
            corr[r] = __expf(mreg[r] - mn);
            mreg[r] = mn;
            float psum = 0.f;
#pragma unroll
            for (int nf = 0; nf < 4; ++nf) {
                float p = __expf(sc[nf][r] - mn);
                sc[nf][r] = p;
                psum += p;
            }
            psum += __shfl_xor(psum, 1, 64);
            psum += __shfl_xor(psum, 2, 64);
            psum += __shfl_xor(psum, 4, 64);
            psum += __shfl_xor(psum, 8, 64);
            lreg[r] = lreg[r] * corr[r] + psum;
        }
#pragma unroll
        for (int fb = 0; fb < 8; ++fb)
#pragma unroll
            for (int r = 0; r < 4; ++r) oacc[fb][r] *= corr[r];

#pragma unroll
        for (int nf = 0; nf < 4; ++nf)
#pragma unroll
            for (int r = 0; r < 4; ++r)
                Ps[wid][(lhi * 4 + r) * 72 + nf * 16 + l16] = f2bf(sc[nf][r]);

        bf16x8 pa[2];
#pragma unroll
        for (int k2 = 0; k2 < 2; ++k2)
            pa[k2] = *(const bf16x8*)(&Ps[wid][l16 * 72 + k2 * 32 + lhi * 8]);

#pragma unroll
        for (int fb = 0; fb < 8; ++fb) {
            int vrow = fb * 16 + l16;
#pragma unroll
            for (int k2 = 0; k2 < 2; ++k2) {
                bf16x8 vf = *(const bf16x8*)(Vs + vrow * 64 + (((k2 * 4 + lhi) ^ (vrow & 7))) * 8);
                oacc[fb] = __builtin_amdgcn_mfma_f32_16x16x32_bf16(pa[k2], vf, oacc[fb], 0, 0, 0);
            }
        }
    }

    float linv[4];
#pragma unroll
    for (int r = 0; r < 4; ++r) linv[r] = 1.f / lreg[r];
#pragma unroll
    for (int fb = 0; fb < 8; ++fb) {
#pragma unroll
        for (int r = 0; r < 4; ++r) {
            int row = qt * 64 + wid * 16 + lhi * 4 + r;
            o[(size_t)row * D + h * HD + fb * 16 + l16] = oacc[fb][r] * linv[r];
        }
    }
}

// ---------------------------------------------------------------- MoE gate + expert lists
__global__ void gate_kernel(const float* __restrict__ x, const float* __restrict__ gw,
                            float* __restrict__ wbuf, int* __restrict__ cnt, int* __restrict__ elist)
{
    int t = blockIdx.x;
    int g = threadIdx.x >> 4, j = threadIdx.x & 15;
    const float* xr = x + (size_t)t * D;
    const float* gr = gw + (size_t)g * D;
    float p = 0.f;
    for (int m = 0; m < D / 16; ++m) p += xr[j + 16 * m] * gr[j + 16 * m];
    for (int off = 8; off; off >>= 1) p += __shfl_down(p, off, 64);
    __shared__ float lg[NE];
    if (j == 0) lg[g] = p;
    __syncthreads();
    if (threadIdx.x == 0) {
        float l0 = -1e30f; int i0 = 0;
        for (int e = 0; e < NE; ++e) if (lg[e] > l0) { l0 = lg[e]; i0 = e; }
        float l1 = -1e30f; int i1 = 0;
        for (int e = 0; e < NE; ++e) if (e != i0 && lg[e] > l1) { l1 = lg[e]; i1 = e; }
        float rr = expf(l1 - l0);
        wbuf[t * 2 + 0] = 1.f / (1.f + rr);
        wbuf[t * 2 + 1] = rr / (1.f + rr);
        int s0 = atomicAdd(&cnt[i0], 1); elist[i0 * S + s0] = t * 2;
        int s1 = atomicAdd(&cnt[i1], 1); elist[i1 * S + s1] = t * 2 + 1;
    }
}

// ---------------------------------------------------------------- launch
extern "C" void kernel_launch(void* const* d_in, const int* in_sizes, int n_in,
                              void* d_out, int out_size, void* d_ws, size_t ws_size,
                              hipStream_t stream)
{
    const float* hidden = (const float*)d_in[0];
    const float* ln1 = (const float*)d_in[1];
    const float* ln2 = (const float*)d_in[2];
    const float* qn  = (const float*)d_in[3];
    const float* kn  = (const float*)d_in[4];
    const float* Wq  = (const float*)d_in[5];
    const float* Wk  = (const float*)d_in[6];
    const float* Wv  = (const float*)d_in[7];
    const float* Wo  = (const float*)d_in[8];
    const float* gw  = (const float*)d_in[9];
    const float* Wg  = (const float*)d_in[10];
    const float* Wu  = (const float*)d_in[11];
    const float* Wd  = (const float*)d_in[12];
    const int*   pos = (const int*)d_in[13];

    float* ws    = (float*)d_ws;
    float* h1    = ws;                    // 2M floats; overlays qbh/kbh/vbt bf16
    float* qkvb  = h1 + 2097152;          // S*3072 = 3.15M floats
    float* attn  = qkvb + 3145728;        // 2M; overlays abuf bf16
    float* hattn = attn + 2097152;        // 2M
    float* h2    = hattn + 2097152;       // 2M
    float* h2bf  = h2 + 2097152;          // 1M floats as bf16 (S*D ushort)
    float* wbuf  = h2bf + 1048576;        // 2048
    int*   cnt   = (int*)(wbuf + 2048);   // 16
    int*   elist = cnt + 16;              // 16*1024

    unsigned short* qbh = (unsigned short*)h1;                 // S*D bf16
    unsigned short* kbh = (unsigned short*)(h1 + 1048576);     // S*512 bf16
    unsigned short* vbt = (unsigned short*)(h1 + 1310720);     // 512*S bf16
    unsigned short* abuf = (unsigned short*)attn;              // 2048*NI bf16
    unsigned short* h2b  = (unsigned short*)h2bf;              // S*D bf16
    float* out   = (float*)d_out;

    hipMemsetAsync(cnt, 0, NE * sizeof(int), stream);

    rmsnorm_kernel<<<S, 256, 0, stream>>>(hidden, ln1, h1, nullptr);
    qkv_gemm_kernel<<<dim3(48, 16), 256, 0, stream>>>(h1, Wq, Wk, Wv, qkvb);
    // h1 dead; bf16 overlays
    qkrope_bf16_kernel<<<dim3(S, NH + NKV), 64, 0, stream>>>(qkvb, qn, kn, pos, qbh, kbh);
    vtrans_kernel<<<dim3(S / 64, HD / 64, NKV), 256, 0, stream>>>(qkvb, vbt);
    flash_attn_mfma_kernel<<<dim3(S / 64, NH), 256, 0, stream>>>(qbh, kbh, vbt, attn);
    // O projection + residual; also writes out (= hattn) for MoE atomic accumulation
    mfma_gemm_kernel<<<dim3(32, 16), 256, 0, stream>>>(attn, D, Wo, D, hattn, D, hidden, out, S, 2048, D);
    rmsnorm_kernel<<<S, 256, 0, stream>>>(hattn, ln2, h2, h2b);
    gate_kernel<<<S, 256, 0, stream>>>(h2, gw, wbuf, cnt, elist);
    // attn buffer dead; abuf overlays
    moe_mlp_kernel<<<dim3(NI / 16, 16, NE), 256, 0, stream>>>(h2b, Wg, Wu, cnt, elist, abuf);
    moe_down_kernel<<<dim3(D / 16, 16, NE), 256, 0, stream>>>(abuf, Wd, cnt, elist, wbuf, out);
}

// Round 7
// 336.840 us; speedup vs baseline: 5.1264x; 1.0161x over previous
//
#include <hip/hip_runtime.h>
#include <hip/hip_bf16.h>
#include <math.h>

#define D 2048
#define NH 16
#define NKV 4
#define HD 128
#define NE 16
#define NI 768
#define S 1024
#define EPS 1e-6f

typedef __attribute__((ext_vector_type(8))) short bf16x8;
typedef __attribute__((ext_vector_type(4))) float f32x4;

__device__ __forceinline__ float wave_reduce_sum64(float v) {
    for (int off = 32; off; off >>= 1) v += __shfl_xor(v, off, 64);
    return v;
}

__device__ __forceinline__ unsigned short f2bf(float f) {
    unsigned int x = __float_as_uint(f);
    x += 0x7FFFu + ((x >> 16) & 1u);   // round-to-nearest-even
    return (unsigned short)(x >> 16);
}

__device__ __forceinline__ bf16x8 pack8(const float4 a, const float4 b) {
    bf16x8 r;
    r[0] = (short)f2bf(a.x); r[1] = (short)f2bf(a.y);
    r[2] = (short)f2bf(a.z); r[3] = (short)f2bf(a.w);
    r[4] = (short)f2bf(b.x); r[5] = (short)f2bf(b.y);
    r[6] = (short)f2bf(b.z); r[7] = (short)f2bf(b.w);
    return r;
}

// ---------------------------------------------------------------- RMSNorm over D (+ optional bf16 copy)
__global__ void rmsnorm_kernel(const float* __restrict__ x, const float* __restrict__ w,
                               float* __restrict__ y, unsigned short* __restrict__ yb) {
    int t = blockIdx.x;
    const float* xr = x + (size_t)t * D;
    float* yr = y + (size_t)t * D;
    float v[8];
    float ss = 0.f;
#pragma unroll
    for (int m = 0; m < 8; ++m) {
        v[m] = xr[threadIdx.x + 256 * m];
        ss += v[m] * v[m];
    }
    ss = wave_reduce_sum64(ss);
    __shared__ float wsum[4];
    if ((threadIdx.x & 63) == 0) wsum[threadIdx.x >> 6] = ss;
    __syncthreads();
    float tot = wsum[0] + wsum[1] + wsum[2] + wsum[3];
    float r = rsqrtf(tot / (float)D + EPS);
#pragma unroll
    for (int m = 0; m < 8; ++m) {
        int d = threadIdx.x + 256 * m;
        float val = v[m] * r * w[d];
        yr[d] = val;
        if (yb) yb[(size_t)t * D + d] = f2bf(val);
    }
}

// ---------------------------------------------------------------- dense MFMA GEMM (LDS dbuf, 1 barrier/k-step)
// C = A@W^T (+R); optional duplicate write to C2. BM=BN=64, BK=64, K % 128 == 0.
__global__ __launch_bounds__(256) void mfma_gemm_kernel(
    const float* __restrict__ A, int lda,
    const float* __restrict__ W, int ldw,
    float* __restrict__ C, int ldc,
    const float* __restrict__ R, float* __restrict__ C2,
    int M, int N, int K)
{
    int m0 = blockIdx.y * 64;
    int n0 = blockIdx.x * 64;

    __shared__ unsigned short As[2][64 * 64];
    __shared__ unsigned short Bs[2][64 * 64];

    int tid = threadIdx.x;
    int srow = tid >> 2;
    int scol = (tid & 3) * 16;

    const float* ap = A + (size_t)(m0 + srow) * lda + scol;
    const float* wp = W + (size_t)(n0 + srow) * ldw + scol;

    int wlo[2];
#pragma unroll
    for (int u = 0; u < 2; ++u) {
        int g = (tid & 3) * 2 + u;
        wlo[u] = srow * 64 + (g ^ (srow & 7)) * 8;
    }

    int wid = tid >> 6, lane = tid & 63;
    int wm = wid >> 1, wn = wid & 1;
    int l16 = lane & 15, lhi = lane >> 4;

    int ra[2][2], rb[2][2];
#pragma unroll
    for (int f = 0; f < 2; ++f) {
        int rowa = wm * 32 + f * 16 + l16;
        int rowb = wn * 32 + f * 16 + l16;
#pragma unroll
        for (int kh = 0; kh < 2; ++kh) {
            ra[f][kh] = rowa * 64 + (((kh * 4 + lhi) ^ (rowa & 7))) * 8;
            rb[f][kh] = rowb * 64 + (((kh * 4 + lhi) ^ (rowb & 7))) * 8;
        }
    }

    f32x4 acc[2][2] = {};
    float4 avA[4], wvA[4], avB[4], wvB[4];

    auto ldt = [&](float4* av, float4* wv, int k0) {
#pragma unroll
        for (int u = 0; u < 4; ++u) {
            av[u] = *(const float4*)(ap + k0 + u * 4);
            wv[u] = *(const float4*)(wp + k0 + u * 4);
        }
    };
    auto stage = [&](const float4* av, const float4* wv, int b) {
        bf16x8 pa0 = pack8(av[0], av[1]);
        bf16x8 pa1 = pack8(av[2], av[3]);
        bf16x8 pw0 = pack8(wv[0], wv[1]);
        bf16x8 pw1 = pack8(wv[2], wv[3]);
        *(bf16x8*)(&As[b][wlo[0]]) = pa0;
        *(bf16x8*)(&As[b][wlo[1]]) = pa1;
        *(bf16x8*)(&Bs[b][wlo[0]]) = pw0;
        *(bf16x8*)(&Bs[b][wlo[1]]) = pw1;
    };
    auto domfma = [&](int b) {
#pragma unroll
        for (int kh = 0; kh < 2; ++kh) {
            bf16x8 af0 = *(const bf16x8*)(&As[b][ra[0][kh]]);
            bf16x8 af1 = *(const bf16x8*)(&As[b][ra[1][kh]]);
            bf16x8 bf0 = *(const bf16x8*)(&Bs[b][rb[0][kh]]);
            bf16x8 bf1 = *(const bf16x8*)(&Bs[b][rb[1][kh]]);
            acc[0][0] = __builtin_amdgcn_mfma_f32_16x16x32_bf16(af0, bf0, acc[0][0], 0, 0, 0);
            acc[0][1] = __builtin_amdgcn_mfma_f32_16x16x32_bf16(af0, bf1, acc[0][1], 0, 0, 0);
            acc[1][0] = __builtin_amdgcn_mfma_f32_16x16x32_bf16(af1, bf0, acc[1][0], 0, 0, 0);
            acc[1][1] = __builtin_amdgcn_mfma_f32_16x16x32_bf16(af1, bf1, acc[1][1], 0, 0, 0);
        }
    };

    ldt(avA, wvA, 0);
    for (int k0 = 0; k0 < K; k0 += 128) {
        ldt(avB, wvB, k0 + 64);
        stage(avA, wvA, 0);
        __syncthreads();
        domfma(0);
        if (k0 + 128 < K) ldt(avA, wvA, k0 + 128);
        stage(avB, wvB, 1);
        __syncthreads();
        domfma(1);
    }

#pragma unroll
    for (int mi = 0; mi < 2; ++mi) {
#pragma unroll
        for (int r = 0; r < 4; ++r) {
            int grow = m0 + wm * 32 + mi * 16 + lhi * 4 + r;
#pragma unroll
            for (int ni = 0; ni < 2; ++ni) {
                int gcol = n0 + wn * 32 + ni * 16 + l16;
                float v = acc[mi][ni][r];
                if (R) v += R[(size_t)grow * ldc + gcol];
                C[(size_t)grow * ldc + gcol] = v;
                if (C2) C2[(size_t)grow * ldc + gcol] = v;
            }
        }
    }
}

// ---------------------------------------------------------------- fused QKV GEMM (LDS dbuf)
// N = 3072: cols 0..2047 = Wq, 2048..2559 = Wk, 2560..3071 = Wv. C ldc = 3072.
__global__ __launch_bounds__(256) void qkv_gemm_kernel(
    const float* __restrict__ A,
    const float* __restrict__ Wq, const float* __restrict__ Wk, const float* __restrict__ Wv,
    float* __restrict__ C)
{
    int m0 = blockIdx.y * 64;
    int n0 = blockIdx.x * 64;

    const float* W;
    int wr0;
    if (n0 < 2048)      { W = Wq; wr0 = n0; }
    else if (n0 < 2560) { W = Wk; wr0 = n0 - 2048; }
    else                { W = Wv; wr0 = n0 - 2560; }

    __shared__ unsigned short As[2][64 * 64];
    __shared__ unsigned short Bs[2][64 * 64];

    int tid = threadIdx.x;
    int srow = tid >> 2;
    int scol = (tid & 3) * 16;

    const float* ap = A + (size_t)(m0 + srow) * D + scol;
    const float* wp = W + (size_t)(wr0 + srow) * D + scol;

    int wlo[2];
#pragma unroll
    for (int u = 0; u < 2; ++u) {
        int g = (tid & 3) * 2 + u;
        wlo[u] = srow * 64 + (g ^ (srow & 7)) * 8;
    }

    int wid = tid >> 6, lane = tid & 63;
    int wm = wid >> 1, wn = wid & 1;
    int l16 = lane & 15, lhi = lane >> 4;

    int ra[2][2], rb[2][2];
#pragma unroll
    for (int f = 0; f < 2; ++f) {
        int rowa = wm * 32 + f * 16 + l16;
        int rowb = wn * 32 + f * 16 + l16;
#pragma unroll
        for (int kh = 0; kh < 2; ++kh) {
            ra[f][kh] = rowa * 64 + (((kh * 4 + lhi) ^ (rowa & 7))) * 8;
            rb[f][kh] = rowb * 64 + (((kh * 4 + lhi) ^ (rowb & 7))) * 8;
        }
    }

    f32x4 acc[2][2] = {};
    float4 avA[4], wvA[4], avB[4], wvB[4];

    auto ldt = [&](float4* av, float4* wv, int k0) {
#pragma unroll
        for (int u = 0; u < 4; ++u) {
            av[u] = *(const float4*)(ap + k0 + u * 4);
            wv[u] = *(const float4*)(wp + k0 + u * 4);
        }
    };
    auto stage = [&](const float4* av, const float4* wv, int b) {
        bf16x8 pa0 = pack8(av[0], av[1]);
        bf16x8 pa1 = pack8(av[2], av[3]);
        bf16x8 pw0 = pack8(wv[0], wv[1]);
        bf16x8 pw1 = pack8(wv[2], wv[3]);
        *(bf16x8*)(&As[b][wlo[0]]) = pa0;
        *(bf16x8*)(&As[b][wlo[1]]) = pa1;
        *(bf16x8*)(&Bs[b][wlo[0]]) = pw0;
        *(bf16x8*)(&Bs[b][wlo[1]]) = pw1;
    };
    auto domfma = [&](int b) {
#pragma unroll
        for (int kh = 0; kh < 2; ++kh) {
            bf16x8 af0 = *(const bf16x8*)(&As[b][ra[0][kh]]);
            bf16x8 af1 = *(const bf16x8*)(&As[b][ra[1][kh]]);
            bf16x8 bf0 = *(const bf16x8*)(&Bs[b][rb[0][kh]]);
            bf16x8 bf1 = *(const bf16x8*)(&Bs[b][rb[1][kh]]);
            acc[0][0] = __builtin_amdgcn_mfma_f32_16x16x32_bf16(af0, bf0, acc[0][0], 0, 0, 0);
            acc[0][1] = __builtin_amdgcn_mfma_f32_16x16x32_bf16(af0, bf1, acc[0][1], 0, 0, 0);
            acc[1][0] = __builtin_amdgcn_mfma_f32_16x16x32_bf16(af1, bf0, acc[1][0], 0, 0, 0);
            acc[1][1] = __builtin_amdgcn_mfma_f32_16x16x32_bf16(af1, bf1, acc[1][1], 0, 0, 0);
        }
    };

    ldt(avA, wvA, 0);
    for (int k0 = 0; k0 < D; k0 += 128) {
        ldt(avB, wvB, k0 + 64);
        stage(avA, wvA, 0);
        __syncthreads();
        domfma(0);
        if (k0 + 128 < D) ldt(avA, wvA, k0 + 128);
        stage(avB, wvB, 1);
        __syncthreads();
        domfma(1);
    }

#pragma unroll
    for (int mi = 0; mi < 2; ++mi) {
#pragma unroll
        for (int r = 0; r < 4; ++r) {
            int grow = m0 + wm * 32 + mi * 16 + lhi * 4 + r;
#pragma unroll
            for (int ni = 0; ni < 2; ++ni) {
                int gcol = n0 + wn * 32 + ni * 16 + l16;
                C[(size_t)grow * 3072 + gcol] = acc[mi][ni][r];
            }
        }
    }
}

// ---------------------------------------------------------------- fused MoE up+gate (gathered, LDS dbuf)
// BM=64, BN=16, BK=64. grid (NI/16, 16, NE). A = h2b (bf16). abuf[slot][i] = silu(g)*u bf16.
__global__ __launch_bounds__(256) void moe_mlp_kernel(
    const unsigned short* __restrict__ h2b,
    const float* __restrict__ Wg, const float* __restrict__ Wu,
    const int* __restrict__ cnt, const int* __restrict__ elist,
    unsigned short* __restrict__ abuf)
{
    int e = blockIdx.z;
    int me = cnt[e];
    int m0 = blockIdx.y * 64;
    if (m0 >= me) return;
    int n0 = blockIdx.x * 16;

    __shared__ unsigned short As[2][64 * 64];
    __shared__ unsigned short Gs[2][16 * 64];
    __shared__ unsigned short Us[2][16 * 64];
    __shared__ int ridx[64];

    int tid = threadIdx.x;
    const int* idx = elist + e * S;
    if (tid < 64) ridx[tid] = (m0 + tid < me) ? idx[m0 + tid] : -1;
    __syncthreads();

    int arow_i = tid >> 2;
    int acolg = (tid & 3) * 16;
    int rva = ridx[arow_i];
    const unsigned short* arow = (rva >= 0) ? (h2b + (size_t)(rva >> 1) * D + acolg) : nullptr;
    int wa[2];
#pragma unroll
    for (int u = 0; u < 2; ++u) {
        int g = (tid & 3) * 2 + u;
        wa[u] = arow_i * 64 + (g ^ (arow_i & 7)) * 8;
    }

    int tl = tid & 127;
    int bwrow = tl >> 3;
    int bg8 = tl & 7;
    const float* bp = ((tid < 128) ? Wg : Wu) + ((size_t)e * NI + n0 + bwrow) * D + bg8 * 8;
    int wbo = bwrow * 64 + (bg8 ^ (bwrow & 7)) * 8;
    bool isG = tid < 128;

    int wid = tid >> 6, lane = tid & 63;
    int l16 = lane & 15, lhi = lane >> 4;

    int raoff[2], rboff[2];
    {
        int rowa = wid * 16 + l16;
#pragma unroll
        for (int kh = 0; kh < 2; ++kh) {
            raoff[kh] = rowa * 64 + (((kh * 4 + lhi) ^ (rowa & 7))) * 8;
            rboff[kh] = l16 * 64 + (((kh * 4 + lhi) ^ (l16 & 7))) * 8;
        }
    }

    f32x4 accg = {}, accu = {};
    bf16x8 avA[2], avB[2];
    float4 bvA[2], bvB[2];

    auto ldt = [&](bf16x8* av, float4* bv, int k0) {
        if (arow) {
            av[0] = *(const bf16x8*)(arow + k0);
            av[1] = *(const bf16x8*)(arow + k0 + 8);
        } else {
            bf16x8 z = {};
            av[0] = z; av[1] = z;
        }
        bv[0] = *(const float4*)(bp + k0);
        bv[1] = *(const float4*)(bp + k0 + 4);
    };
    auto stage = [&](const bf16x8* av, const float4* bv, int b) {
        bf16x8 pb = pack8(bv[0], bv[1]);
        *(bf16x8*)(&As[b][wa[0]]) = av[0];
        *(bf16x8*)(&As[b][wa[1]]) = av[1];
        if (isG) *(bf16x8*)(&Gs[b][wbo]) = pb;
        else     *(bf16x8*)(&Us[b][wbo]) = pb;
    };
    auto domfma = [&](int b) {
#pragma unroll
        for (int kh = 0; kh < 2; ++kh) {
            bf16x8 a = *(const bf16x8*)(&As[b][raoff[kh]]);
            bf16x8 bgf = *(const bf16x8*)(&Gs[b][rboff[kh]]);
            bf16x8 buf = *(const bf16x8*)(&Us[b][rboff[kh]]);
            accg = __builtin_amdgcn_mfma_f32_16x16x32_bf16(a, bgf, accg, 0, 0, 0);
            accu = __builtin_amdgcn_mfma_f32_16x16x32_bf16(a, buf, accu, 0, 0, 0);
        }
    };

    ldt(avA, bvA, 0);
    for (int k0 = 0; k0 < D; k0 += 128) {
        ldt(avB, bvB, k0 + 64);
        stage(avA, bvA, 0);
        __syncthreads();
        domfma(0);
        if (k0 + 128 < D) ldt(avA, bvA, k0 + 128);
        stage(avB, bvB, 1);
        __syncthreads();
        domfma(1);
    }

#pragma unroll
    for (int r = 0; r < 4; ++r) {
        int lrow = wid * 16 + lhi * 4 + r;
        int rv = ridx[lrow];
        if (rv < 0) continue;
        float g = accg[r];
        float u = accu[r];
        float a = g / (1.f + __expf(-g)) * u;
        abuf[(size_t)rv * NI + n0 + l16] = f2bf(a);
    }
}

// ---------------------------------------------------------------- MoE down proj + combine (LDS dbuf)
// BM=64, BN=16. grid (D/16, 16, NE). out += wbuf[slot] * (abuf@Wd^T) via atomics.
__global__ __launch_bounds__(256) void moe_down_kernel(
    const unsigned short* __restrict__ abuf, const float* __restrict__ Wd,
    const int* __restrict__ cnt, const int* __restrict__ elist,
    const float* __restrict__ wbuf, float* __restrict__ out)
{
    int e = blockIdx.z;
    int me = cnt[e];
    int m0 = blockIdx.y * 64;
    if (m0 >= me) return;
    int n0 = blockIdx.x * 16;

    __shared__ unsigned short As[2][64 * 64];
    __shared__ unsigned short Bs[2][16 * 64];
    __shared__ int ridx[64];

    int tid = threadIdx.x;
    const int* idx = elist + e * S;
    if (tid < 64) ridx[tid] = (m0 + tid < me) ? idx[m0 + tid] : -1;
    __syncthreads();

    int arow_i = tid >> 2;
    int acolg = (tid & 3) * 16;
    int rva = ridx[arow_i];
    const unsigned short* arow = (rva >= 0) ? (abuf + (size_t)rva * NI + acolg) : nullptr;
    int wa[2];
#pragma unroll
    for (int u = 0; u < 2; ++u) {
        int g = (tid & 3) * 2 + u;
        wa[u] = arow_i * 64 + (g ^ (arow_i & 7)) * 8;
    }

    int tl = tid & 127;
    int bwrow = tl >> 3;
    int bg8 = tl & 7;
    const float* bp = Wd + ((size_t)e * D + n0 + bwrow) * NI + bg8 * 8;
    int wbo = bwrow * 64 + (bg8 ^ (bwrow & 7)) * 8;
    bool doB = tid < 128;

    int wid = tid >> 6, lane = tid & 63;
    int l16 = lane & 15, lhi = lane >> 4;

    int raoff[2], rboff[2];
    {
        int rowa = wid * 16 + l16;
#pragma unroll
        for (int kh = 0; kh < 2; ++kh) {
            raoff[kh] = rowa * 64 + (((kh * 4 + lhi) ^ (rowa & 7))) * 8;
            rboff[kh] = l16 * 64 + (((kh * 4 + lhi) ^ (l16 & 7))) * 8;
        }
    }

    f32x4 acc = {};
    bf16x8 avA[2], avB[2];
    float4 bvA[2], bvB[2];

    auto ldt = [&](bf16x8* av, float4* bv, int k0) {
        if (arow) {
            av[0] = *(const bf16x8*)(arow + k0);
            av[1] = *(const bf16x8*)(arow + k0 + 8);
        } else {
            bf16x8 z = {};
            av[0] = z; av[1] = z;
        }
        if (doB) {
            bv[0] = *(const float4*)(bp + k0);
            bv[1] = *(const float4*)(bp + k0 + 4);
        }
    };
    auto stage = [&](const bf16x8* av, const float4* bv, int b) {
        *(bf16x8*)(&As[b][wa[0]]) = av[0];
        *(bf16x8*)(&As[b][wa[1]]) = av[1];
        if (doB) {
            bf16x8 pb = pack8(bv[0], bv[1]);
            *(bf16x8*)(&Bs[b][wbo]) = pb;
        }
    };
    auto domfma = [&](int b) {
#pragma unroll
        for (int kh = 0; kh < 2; ++kh) {
            bf16x8 a = *(const bf16x8*)(&As[b][raoff[kh]]);
            bf16x8 bb = *(const bf16x8*)(&Bs[b][rboff[kh]]);
            acc = __builtin_amdgcn_mfma_f32_16x16x32_bf16(a, bb, acc, 0, 0, 0);
        }
    };

    ldt(avA, bvA, 0);
    for (int k0 = 0; k0 < NI; k0 += 128) {
        ldt(avB, bvB, k0 + 64);
        stage(avA, bvA, 0);
        __syncthreads();
        domfma(0);
        if (k0 + 128 < NI) ldt(avA, bvA, k0 + 128);
        stage(avB, bvB, 1);
        __syncthreads();
        domfma(1);
    }

#pragma unroll
    for (int r = 0; r < 4; ++r) {
        int lrow = wid * 16 + lhi * 4 + r;
        int rv = ridx[lrow];
        if (rv < 0) continue;
        float w = wbuf[rv];
        atomicAdd(out + (size_t)(rv >> 1) * D + n0 + l16, w * acc[r]);
    }
}

// ---------------------------------------------------------------- q/k RMSNorm + RoPE -> bf16
__global__ void qkrope_bf16_kernel(const float* __restrict__ qkvb,
                                   const float* __restrict__ qn_w, const float* __restrict__ kn_w,
                                   const int* __restrict__ pos_ids,
                                   unsigned short* __restrict__ qbh, unsigned short* __restrict__ kbh)
{
    int t = blockIdx.x;
    int h = blockIdx.y;
    int d = threadIdx.x;
    const float* base;
    const float* w;
    unsigned short* ob;
    float scale;
    if (h < NH) {
        base = qkvb + (size_t)t * 3072 + h * HD; w = qn_w;
        ob = qbh + (size_t)t * D + h * HD; scale = 0.08838834764831845f;
    } else {
        base = qkvb + (size_t)t * 3072 + 2048 + (h - NH) * HD; w = kn_w;
        ob = kbh + (size_t)t * (NKV * HD) + (h - NH) * HD; scale = 1.0f;
    }
    float x1 = base[d], x2 = base[d + 64];
    float ss = wave_reduce_sum64(x1 * x1 + x2 * x2);
    float r = rsqrtf(ss / (float)HD + EPS);
    float n1 = x1 * r * w[d];
    float n2 = x2 * r * w[d + 64];
    float pos = (float)pos_ids[t];
    float freq = powf(1000000.0f, -(float)d * (1.0f / 64.0f));
    float ang = pos * freq;
    float c, s;
    sincosf(ang, &s, &c);
    ob[d]      = f2bf((n1 * c - n2 * s) * scale);
    ob[d + 64] = f2bf((n2 * c + n1 * s) * scale);
}

// ---------------------------------------------------------------- V -> bf16 V^T [KV][HD][S]
__global__ void vtrans_kernel(const float* __restrict__ qkvb, unsigned short* __restrict__ vbt)
{
    __shared__ unsigned short tile[64][65];
    int s0 = blockIdx.x * 64, d0 = blockIdx.y * 64, kvh = blockIdx.z;
    int tid = threadIdx.x;
    {
        int i = tid >> 2;
        int j4 = (tid & 3) * 16;
        const float* src = qkvb + (size_t)(s0 + i) * 3072 + 2560 + kvh * HD + d0 + j4;
#pragma unroll
        for (int u = 0; u < 4; ++u) {
            float4 f = *(const float4*)(src + u * 4);
            tile[i][j4 + u * 4 + 0] = f2bf(f.x);
            tile[i][j4 + u * 4 + 1] = f2bf(f.y);
            tile[i][j4 + u * 4 + 2] = f2bf(f.z);
            tile[i][j4 + u * 4 + 3] = f2bf(f.w);
        }
    }
    __syncthreads();
    {
        int j = tid >> 2;
        int i4 = (tid & 3) * 16;
        bf16x8 o0, o1;
#pragma unroll
        for (int u = 0; u < 8; ++u) {
            o0[u] = (short)tile[i4 + u][j];
            o1[u] = (short)tile[i4 + 8 + u][j];
        }
        unsigned short* dst = vbt + ((size_t)kvh * HD + d0 + j) * S + s0 + i4;
        *(bf16x8*)(dst) = o0;
        *(bf16x8*)(dst + 8) = o1;
    }
}

// ---------------------------------------------------------------- MFMA flash attention
__global__ __launch_bounds__(256) void flash_attn_mfma_kernel(
    const unsigned short* __restrict__ qbh, const unsigned short* __restrict__ kbh,
    const unsigned short* __restrict__ vbt, float* __restrict__ o)
{
    int qt = blockIdx.x;
    int h  = blockIdx.y;
    int kvh = h >> 2;

    __shared__ unsigned short Qs[64 * 128];
    __shared__ unsigned short Ks[64 * 128];
    __shared__ unsigned short Vs[128 * 64];
    __shared__ unsigned short Ps[4][16 * 72];

    int tid = threadIdx.x;
    int wid = tid >> 6, lane = tid & 63;
    int l16 = lane & 15, lhi = lane >> 4;

    {
        int r = tid >> 2;
        int gb = (tid & 3) * 4;
        const unsigned short* src = qbh + (size_t)(qt * 64 + r) * D + h * HD;
#pragma unroll
        for (int u = 0; u < 4; ++u) {
            int g = gb + u;
            bf16x8 val = *(const bf16x8*)(src + g * 8);
            *(bf16x8*)(Qs + r * 128 + (g ^ (r & 7)) * 8) = val;
        }
    }

    int qrow = wid * 16 + l16;
    int qoff[4];
#pragma unroll
    for (int kh = 0; kh < 4; ++kh)
        qoff[kh] = qrow * 128 + (((kh * 4 + lhi) ^ (qrow & 7))) * 8;

    float mreg[4], lreg[4];
#pragma unroll
    for (int r = 0; r < 4; ++r) { mreg[r] = -3.0e38f; lreg[r] = 0.f; }
    f32x4 oacc[8] = {};

    for (int kt = 0; kt < S / 64; ++kt) {
        __syncthreads();
        {
            int r = tid >> 2;
            int gb = (tid & 3) * 4;
            const unsigned short* src = kbh + (size_t)(kt * 64 + r) * (NKV * HD) + kvh * HD;
#pragma unroll
            for (int u = 0; u < 4; ++u) {
                int g = gb + u;
                bf16x8 val = *(const bf16x8*)(src + g * 8);
                *(bf16x8*)(Ks + r * 128 + (g ^ (r & 7)) * 8) = val;
            }
        }
        {
            int r = tid >> 1;
            int gb = (tid & 1) * 4;
            const unsigned short* src = vbt + ((size_t)kvh * HD + r) * S + kt * 64;
#pragma unroll
            for (int u = 0; u < 4; ++u) {
                int g = gb + u;
                bf16x8 val = *(const bf16x8*)(src + g * 8);
                *(bf16x8*)(Vs + r * 64 + (g ^ (r & 7)) * 8) = val;
            }
        }
        __syncthreads();

        bf16x8 qa[4];
#pragma unroll
        for (int kh = 0; kh < 4; ++kh) qa[kh] = *(const bf16x8*)(Qs + qoff[kh]);
        f32x4 sc[4] = {};
#pragma unroll
        for (int nf = 0; nf < 4; ++nf) {
            int krow = nf * 16 + l16;
#pragma unroll
            for (int kh = 0; kh < 4; ++kh) {
                bf16x8 kf = *(const bf16x8*)(Ks + krow * 128 + (((kh * 4 + lhi) ^ (krow & 7))) * 8);
                sc[nf] = __builtin_amdgcn_mfma_f32_16x16x32_bf16(qa[kh], kf, sc[nf], 0, 0, 0);
            }
        }

        float corr[4];
#pragma unroll
        for (int r = 0; r < 4; ++r) {
            float tmax = fmaxf(fmaxf(sc[0][r], sc[1][r]), fmaxf(sc[2][r], sc[3][r]));
            tmax = fmaxf(tmax, __shfl_xor(tmax, 1, 64));
            tmax = fmaxf(tmax, __shfl_xor(tmax, 2, 64));
            tmax = fmaxf(tmax, __shfl_xor(tmax, 4, 64));
            tmax = fmaxf(tmax, __shfl_xor(tmax, 8, 64));
            float mn = fmaxf(mreg[r], tmax);
            corr[r] = __expf(mreg[r] - mn);
            mreg[r] = mn;
            float psum = 0.f;
#pragma unroll
            for (int nf = 0; nf < 4; ++nf) {
                float p = __expf(sc[nf][r] - mn);
                sc[nf][r] = p;
                psum += p;
            }
            psum += __shfl_xor(psum, 1, 64);
            psum += __shfl_xor(psum, 2, 64);
            psum += __shfl_xor(psum, 4, 64);
            psum += __shfl_xor(psum, 8, 64);
            lreg[r] = lreg[r] * corr[r] + psum;
        }
#pragma unroll
        for (int fb = 0; fb < 8; ++fb)
#pragma unroll
            for (int r = 0; r < 4; ++r) oacc[fb][r] *= corr[r];

#pragma unroll
        for (int nf = 0; nf < 4; ++nf)
#pragma unroll
            for (int r = 0; r < 4; ++r)
                Ps[wid][(lhi * 4 + r) * 72 + nf * 16 + l16] = f2bf(sc[nf][r]);

        bf16x8 pa[2];
#pragma unroll
        for (int k2 = 0; k2 < 2; ++k2)
            pa[k2] = *(const bf16x8*)(&Ps[wid][l16 * 72 + k2 * 32 + lhi * 8]);

#pragma unroll
        for (int fb = 0; fb < 8; ++fb) {
            int vrow = fb * 16 + l16;
#pragma unroll
            for (int k2 = 0; k2 < 2; ++k2) {
                bf16x8 vf = *(const bf16x8*)(Vs + vrow * 64 + (((k2 * 4 + lhi) ^ (vrow & 7))) * 8);
                oacc[fb] = __builtin_amdgcn_mfma_f32_16x16x32_bf16(pa[k2], vf, oacc[fb], 0, 0, 0);
            }
        }
    }

    float linv[4];
#pragma unroll
    for (int r = 0; r < 4; ++r) linv[r] = 1.f / lreg[r];
#pragma unroll
    for (int fb = 0; fb < 8; ++fb) {
#pragma unroll
        for (int r = 0; r < 4; ++r) {
            int row = qt * 64 + wid * 16 + lhi * 4 + r;
            o[(size_t)row * D + h * HD + fb * 16 + l16] = oacc[fb][r] * linv[r];
        }
    }
}

// ---------------------------------------------------------------- MoE gate + expert lists
__global__ void gate_kernel(const float* __restrict__ x, const float* __restrict__ gw,
                            float* __restrict__ wbuf, int* __restrict__ cnt, int* __restrict__ elist)
{
    int t = blockIdx.x;
    int g = threadIdx.x >> 4, j = threadIdx.x & 15;
    const float* xr = x + (size_t)t * D;
    const float* gr = gw + (size_t)g * D;
    float p = 0.f;
    for (int m = 0; m < D / 16; ++m) p += xr[j + 16 * m] * gr[j + 16 * m];
    for (int off = 8; off; off >>= 1) p += __shfl_down(p, off, 64);
    __shared__ float lg[NE];
    if (j == 0) lg[g] = p;
    __syncthreads();
    if (threadIdx.x == 0) {
        float l0 = -1e30f; int i0 = 0;
        for (int e = 0; e < NE; ++e) if (lg[e] > l0) { l0 = lg[e]; i0 = e; }
        float l1 = -1e30f; int i1 = 0;
        for (int e = 0; e < NE; ++e) if (e != i0 && lg[e] > l1) { l1 = lg[e]; i1 = e; }
        float rr = expf(l1 - l0);
        wbuf[t * 2 + 0] = 1.f / (1.f + rr);
        wbuf[t * 2 + 1] = rr / (1.f + rr);
        int s0 = atomicAdd(&cnt[i0], 1); elist[i0 * S + s0] = t * 2;
        int s1 = atomicAdd(&cnt[i1], 1); elist[i1 * S + s1] = t * 2 + 1;
    }
}

// ---------------------------------------------------------------- launch
extern "C" void kernel_launch(void* const* d_in, const int* in_sizes, int n_in,
                              void* d_out, int out_size, void* d_ws, size_t ws_size,
                              hipStream_t stream)
{
    const float* hidden = (const float*)d_in[0];
    const float* ln1 = (const float*)d_in[1];
    const float* ln2 = (const float*)d_in[2];
    const float* qn  = (const float*)d_in[3];
    const float* kn  = (const float*)d_in[4];
    const float* Wq  = (const float*)d_in[5];
    const float* Wk  = (const float*)d_in[6];
    const float* Wv  = (const float*)d_in[7];
    const float* Wo  = (const float*)d_in[8];
    const float* gw  = (const float*)d_in[9];
    const float* Wg  = (const float*)d_in[10];
    const float* Wu  = (const float*)d_in[11];
    const float* Wd  = (const float*)d_in[12];
    const int*   pos = (const int*)d_in[13];

    float* ws    = (float*)d_ws;
    float* h1    = ws;                    // 2M floats; overlays qbh/kbh/vbt bf16
    float* qkvb  = h1 + 2097152;          // S*3072 = 3.15M floats
    float* attn  = qkvb + 3145728;        // 2M; overlays abuf bf16
    float* hattn = attn + 2097152;        // 2M
    float* h2    = hattn + 2097152;       // 2M
    float* h2bf  = h2 + 2097152;          // 1M floats as bf16 (S*D ushort)
    float* wbuf  = h2bf + 1048576;        // 2048
    int*   cnt   = (int*)(wbuf + 2048);   // 16
    int*   elist = cnt + 16;              // 16*1024

    unsigned short* qbh = (unsigned short*)h1;                 // S*D bf16
    unsigned short* kbh = (unsigned short*)(h1 + 1048576);     // S*512 bf16
    unsigned short* vbt = (unsigned short*)(h1 + 1310720);     // 512*S bf16
    unsigned short* abuf = (unsigned short*)attn;              // 2048*NI bf16
    unsigned short* h2b  = (unsigned short*)h2bf;              // S*D bf16
    float* out   = (float*)d_out;

    hipMemsetAsync(cnt, 0, NE * sizeof(int), stream);

    rmsnorm_kernel<<<S, 256, 0, stream>>>(hidden, ln1, h1, nullptr);
    qkv_gemm_kernel<<<dim3(48, 16), 256, 0, stream>>>(h1, Wq, Wk, Wv, qkvb);
    // h1 dead; bf16 overlays
    qkrope_bf16_kernel<<<dim3(S, NH + NKV), 64, 0, stream>>>(qkvb, qn, kn, pos, qbh, kbh);
    vtrans_kernel<<<dim3(S / 64, HD / 64, NKV), 256, 0, stream>>>(qkvb, vbt);
    flash_attn_mfma_kernel<<<dim3(S / 64, NH), 256, 0, stream>>>(qbh, kbh, vbt, attn);
    // O projection + residual; also writes out (= hattn) for MoE atomic accumulation
    mfma_gemm_kernel<<<dim3(32, 16), 256, 0, stream>>>(attn, D, Wo, D, hattn, D, hidden, out, S, 2048, D);
    rmsnorm_kernel<<<S, 256, 0, stream>>>(hattn, ln2, h2, h2b);
    gate_kernel<<<S, 256, 0, stream>>>(h2, gw, wbuf, cnt, elist);
    // attn buffer dead; abuf overlays
    moe_mlp_kernel<<<dim3(NI / 16, 16, NE), 256, 0, stream>>>(h2b, Wg, Wu, cnt, elist, abuf);
    moe_down_kernel<<<dim3(D / 16, 16, NE), 256, 0, stream>>>(abuf, Wd, cnt, elist, wbuf, out);
}